// Round 1
// baseline (1686.767 us; speedup 1.0000x reference)
//
#include <hip/hip_runtime.h>

constexpr int N    = 8000;
constexpr int E    = 128000;
constexpr int G    = 4;
constexpr int C    = 64;
constexpr int NLM  = 16;
constexpr int NEL  = 10;
constexpr int NGR  = N / G;          // 2000
constexpr int NC   = N * C;          // 512000
constexpr int NK   = 342;            // Ewald vectors
constexpr float RMAX = 5.0f;

__device__ __forceinline__ int lmap_rt(int l) { return (l >= 1) + (l >= 4) + (l >= 9); }
__device__ __forceinline__ float silu(float x) { return x / (1.f + __expf(-x)); }

// ---------------- init: elem, e0/charge/dipole ----------------
__global__ __launch_bounds__(256) void k_init(const float* __restrict__ na,
    const float* __restrict__ q, const float* __restrict__ pos,
    const int* __restrict__ batch, const float* __restrict__ aE,
    int* __restrict__ elem, float* __restrict__ acc)
{
    __shared__ float s[G * 5];
    if (threadIdx.x < G * 5) s[threadIdx.x] = 0.f;
    __syncthreads();
    const int n = blockIdx.x * 256 + threadIdx.x;
    if (n < N) {
        int el = 0; float best = na[n * NEL];
        #pragma unroll
        for (int j = 1; j < NEL; ++j) { float v = na[n * NEL + j]; if (v > best) { best = v; el = j; } }
        elem[n] = el;
        const int g = batch[n];
        const float qn = q[n];
        atomicAdd(&s[g * 5 + 0], aE[el]);
        atomicAdd(&s[g * 5 + 1], qn);
        atomicAdd(&s[g * 5 + 2], qn * pos[n * 3 + 0]);
        atomicAdd(&s[g * 5 + 3], qn * pos[n * 3 + 1]);
        atomicAdd(&s[g * 5 + 4], qn * pos[n * 3 + 2]);
    }
    __syncthreads();
    if (threadIdx.x < G * 5) atomicAdd(&acc[threadIdx.x], s[threadIdx.x]);
}

__global__ __launch_bounds__(256) void k_feat0(const int* __restrict__ elem,
    const float* __restrict__ embW, float* __restrict__ F)
{
    const int i = blockIdx.x * 256 + threadIdx.x;
    if (i < NC) F[i] = embW[elem[i >> 6] * 64 + (i & 63)];
}

__global__ __launch_bounds__(256) void k_pre(const float* __restrict__ q,
    const float* __restrict__ qc, float* __restrict__ F)
{
    const int i = blockIdx.x * 256 + threadIdx.x;
    if (i < NC) F[i] += q[i >> 6] * qc[i & 63];
}

// ---------------- element bucketing ----------------
__global__ __launch_bounds__(256) void k_hist(const int* __restrict__ elem, int* __restrict__ counts)
{
    const int n = blockIdx.x * 256 + threadIdx.x;
    if (n < N) atomicAdd(&counts[elem[n]], 1);
}
__global__ void k_offs(const int* __restrict__ counts, int* __restrict__ offs)
{
    if (threadIdx.x == 0 && blockIdx.x == 0) {
        int o = 0;
        for (int j = 0; j < NEL; ++j) { offs[j] = o; o += (counts[j] + 63) & ~63; }
        offs[NEL] = o;
    }
}
__global__ __launch_bounds__(256) void k_scatter(const int* __restrict__ elem,
    const int* __restrict__ offs, int* __restrict__ cursor, int* __restrict__ perm)
{
    const int n = blockIdx.x * 256 + threadIdx.x;
    if (n < N) {
        const int el = elem[n];
        const int p = atomicAdd(&cursor[el], 1);
        perm[offs[el] + p] = n;
    }
}

// ---------------- per-l GEMM: Out[l][n][d] = sum_c X[l][n][c] * W[lmap(l)][c][d] ----------------
__global__ __launch_bounds__(256) void k_lgemm(const float* __restrict__ X,
    const float* __restrict__ Wb, float* __restrict__ Out)
{
    __shared__ float Ws[4096];
    __shared__ float Xs[64 * 65];
    const int l  = blockIdx.y;
    const int nb = blockIdx.x << 6;
    const float* W = Wb + lmap_rt(l) * 4096;
    for (int i = threadIdx.x; i < 4096; i += 256) Ws[i] = W[i];
    const float* Xp = X + (size_t)l * NC + (size_t)nb * 64;
    for (int i = threadIdx.x; i < 4096; i += 256) Xs[(i >> 6) * 65 + (i & 63)] = Xp[i];
    __syncthreads();
    const int tc = threadIdx.x & 15;
    const int tr = threadIdx.x >> 4;
    float4 acc[4];
    #pragma unroll
    for (int j = 0; j < 4; ++j) acc[j] = make_float4(0.f, 0.f, 0.f, 0.f);
    #pragma unroll 8
    for (int c = 0; c < 64; ++c) {
        const float4 w = *(const float4*)&Ws[(c << 6) + (tc << 2)];
        #pragma unroll
        for (int j = 0; j < 4; ++j) {
            const float x = Xs[((tr << 2) + j) * 65 + c];
            acc[j].x += x * w.x; acc[j].y += x * w.y; acc[j].z += x * w.z; acc[j].w += x * w.w;
        }
    }
    float* Op = Out + (size_t)l * NC + (size_t)nb * 64;
    #pragma unroll
    for (int j = 0; j < 4; ++j)
        *(float4*)&Op[((tr << 2) + j) * 64 + (tc << 2)] = acc[j];
}

// ---------------- sc GEMM over element buckets ----------------
__global__ __launch_bounds__(256) void k_sc(const float* __restrict__ F,
    const float* __restrict__ Wsc, const int* __restrict__ perm,
    const int* __restrict__ elem, float* __restrict__ Out)
{
    __shared__ float Ws[4096];
    __shared__ float Xs[64 * 65];
    __shared__ int rows[64];
    const int l  = blockIdx.y;
    const int tb = blockIdx.x << 6;
    if (threadIdx.x < 64) rows[threadIdx.x] = perm[tb + threadIdx.x];
    __syncthreads();
    if (rows[0] < 0) return;
    const float* W = Wsc + elem[rows[0]] * 4096;
    for (int i = threadIdx.x; i < 4096; i += 256) Ws[i] = W[i];
    for (int i = threadIdx.x; i < 4096; i += 256) {
        const int rr = i >> 6, cc = i & 63;
        const int n = rows[rr];
        Xs[rr * 65 + cc] = (n >= 0) ? F[(size_t)l * NC + (size_t)n * 64 + cc] : 0.f;
    }
    __syncthreads();
    const int tc = threadIdx.x & 15;
    const int tr = threadIdx.x >> 4;
    float4 acc[4];
    #pragma unroll
    for (int j = 0; j < 4; ++j) acc[j] = make_float4(0.f, 0.f, 0.f, 0.f);
    #pragma unroll 8
    for (int c = 0; c < 64; ++c) {
        const float4 w = *(const float4*)&Ws[(c << 6) + (tc << 2)];
        #pragma unroll
        for (int j = 0; j < 4; ++j) {
            const float x = Xs[((tr << 2) + j) * 65 + c];
            acc[j].x += x * w.x; acc[j].y += x * w.y; acc[j].z += x * w.z; acc[j].w += x * w.w;
        }
    }
    #pragma unroll
    for (int j = 0; j < 4; ++j) {
        const int n = rows[(tr << 2) + j];
        if (n >= 0) *(float4*)&Out[(size_t)l * NC + (size_t)n * 64 + (tc << 2)] = acc[j];
    }
}

// ---------------- radial MLP (h1..h3), wave per edge ----------------
__global__ __launch_bounds__(512) void k_radial(const float* __restrict__ pos,
    const float* __restrict__ shifts, const int* __restrict__ ei,
    const float* __restrict__ W1, const float* __restrict__ W2,
    const float* __restrict__ W3, float* __restrict__ h3buf)
{
    __shared__ float W1s[512], W2s[4096], W3s[4096];
    for (int i = threadIdx.x; i < 512; i += 512) W1s[i] = W1[i];
    for (int i = threadIdx.x; i < 4096; i += 512) { W2s[i] = W2[i]; W3s[i] = W3[i]; }
    __syncthreads();
    const int lane = threadIdx.x & 63;
    const int w0i  = blockIdx.x * 8 + (threadIdx.x >> 6);
    const int nw   = gridDim.x * 8;
    for (int e = w0i; e < E; e += nw) {
        const int s  = ei[e], rv = ei[E + e];
        const float dx = pos[rv * 3 + 0] - pos[s * 3 + 0] + shifts[e * 3 + 0];
        const float dy = pos[rv * 3 + 1] - pos[s * 3 + 1] + shifts[e * 3 + 1];
        const float dz = pos[rv * 3 + 2] - pos[s * 3 + 2] + shifts[e * 3 + 2];
        const float r = sqrtf(dx * dx + dy * dy + dz * dz);
        if (r >= RMAX) continue;
        const float u  = r * 0.2f;
        const float u2 = u * u, u5 = u2 * u2 * u;
        const float fc = 1.f - 21.f * u5 + 35.f * u5 * u - 15.f * u5 * u2;
        const float pref = 0.63245553f * fc / (r + 1e-9f);
        const float piu = 3.14159265358979f * u;
        float h1 = 0.f;
        #pragma unroll
        for (int b = 0; b < 8; ++b)
            h1 += __sinf((float)(b + 1) * piu) * pref * W1s[b * 64 + lane];
        h1 = silu(h1);
        float h2 = 0.f;
        #pragma unroll
        for (int k = 0; k < 64; ++k) h2 += __shfl(h1, k, 64) * W2s[k * 64 + lane];
        h2 = silu(h2);
        float h3 = 0.f;
        #pragma unroll
        for (int k = 0; k < 64; ++k) h3 += __shfl(h2, k, 64) * W3s[k * 64 + lane];
        h3 = silu(h3);
        h3buf[(size_t)e * 64 + lane] = h3;
    }
}

// ---------------- edge message: W4, Y, s_e, scatter ----------------
__global__ __launch_bounds__(512) void k_edge(const float* __restrict__ pos,
    const float* __restrict__ shifts, const int* __restrict__ ei,
    const float* __restrict__ H, const float* __restrict__ h3buf,
    const float* __restrict__ W4, float* __restrict__ Aacc)
{
    __shared__ float W4s[16384];
    for (int i = threadIdx.x; i < 16384; i += 512) W4s[i] = W4[i];
    __syncthreads();
    const int lane = threadIdx.x & 63;
    const int w0i  = blockIdx.x * 8 + (threadIdx.x >> 6);
    const int nw   = gridDim.x * 8;
    for (int e = w0i; e < E; e += nw) {
        const int s  = ei[e], rv = ei[E + e];
        const float dx = pos[rv * 3 + 0] - pos[s * 3 + 0] + shifts[e * 3 + 0];
        const float dy = pos[rv * 3 + 1] - pos[s * 3 + 1] + shifts[e * 3 + 1];
        const float dz = pos[rv * 3 + 2] - pos[s * 3 + 2] + shifts[e * 3 + 2];
        const float r = sqrtf(dx * dx + dy * dy + dz * dz);
        if (r >= RMAX) continue;
        const float inv = 1.f / (r + 1e-9f);
        const float x = dx * inv, y = dy * inv, z = dz * inv;
        const float xx = x * x, yy = y * y, zz = z * z;
        float Y[16];
        Y[0] = 1.f;
        Y[1] = 1.7320508f * x;  Y[2] = 1.7320508f * y;  Y[3] = 1.7320508f * z;
        Y[4] = 3.8729833f * x * y;  Y[5] = 3.8729833f * y * z;
        Y[6] = 0.5f * 2.2360680f * (3.f * zz - 1.f);
        Y[7] = 3.8729833f * x * z;  Y[8] = 0.5f * 3.8729833f * (xx - yy);
        Y[9]  = 2.0916500f * y * (3.f * xx - yy);
        Y[10] = 10.2469508f * x * y * z;
        Y[11] = 1.6201852f * y * (5.f * zz - 1.f);
        Y[12] = 0.5f * 2.6457513f * z * (5.f * zz - 3.f);
        Y[13] = 1.6201852f * x * (5.f * zz - 1.f);
        Y[14] = 0.5f * 10.2469508f * z * (xx - yy);
        Y[15] = 2.0916500f * x * (xx - 3.f * yy);
        // s_e = sum_l h[sender][lane][l] * Y[l], fold /AVG_NEIGH
        float se = 0.f;
        const float* Hp = H + (size_t)s * 64 + lane;
        #pragma unroll
        for (int l = 0; l < 16; ++l) se += Hp[(size_t)l * NC] * Y[l];
        se *= 0.0625f;
        // w[lane][0..3] = sum_k h3[k] * W4[k][lane*4 + l']
        const float v = h3buf[(size_t)e * 64 + lane];
        float wa = 0.f, wb = 0.f, wc = 0.f, wd = 0.f;
        #pragma unroll
        for (int k = 0; k < 64; ++k) {
            const float hk = __shfl(v, k, 64);
            const float4 q4 = *(const float4*)&W4s[(k << 8) + (lane << 2)];
            wa += hk * q4.x; wb += hk * q4.y; wc += hk * q4.z; wd += hk * q4.w;
        }
        const float wl[4] = { wa * se, wb * se, wc * se, wd * se };
        float* Ap = Aacc + (size_t)rv * 64 + lane;
        #pragma unroll
        for (int l = 0; l < 16; ++l) {
            constexpr int LM[16] = {0,1,1,1,2,2,2,2,2,3,3,3,3,3,3,3};
            atomicAdd(&Ap[(size_t)l * NC], wl[LM[l]] * Y[l]);
        }
    }
}

// ---------------- s1[n][c] = sum_l A'[l][n][c]^2 ----------------
__global__ __launch_bounds__(256) void k_s1(const float* __restrict__ H, float* __restrict__ s1)
{
    const int i = blockIdx.x * 256 + threadIdx.x;
    if (i < NC) {
        float s = 0.f;
        #pragma unroll
        for (int l = 0; l < 16; ++l) { const float a = H[(size_t)l * NC + i]; s += a * a; }
        s1[i] = s;
    }
}

// ---------------- out = sum_p (A'*s1^p)@Wp_p + sc -> F ----------------
__global__ __launch_bounds__(256) void k_out(const float* __restrict__ Ap,
    const float* __restrict__ s1, const float* __restrict__ Wp3,
    const float* __restrict__ sc, float* __restrict__ F)
{
    __shared__ float As[64 * 65];
    __shared__ float Ss[64 * 65];
    __shared__ float Ws[4096];
    const int l  = blockIdx.y;
    const int nb = blockIdx.x << 6;
    const float* Xp = Ap + (size_t)l * NC + (size_t)nb * 64;
    for (int i = threadIdx.x; i < 4096; i += 256) {
        As[(i >> 6) * 65 + (i & 63)] = Xp[i];
        Ss[(i >> 6) * 65 + (i & 63)] = s1[nb * 64 + i];
    }
    const int tc = threadIdx.x & 15;
    const int tr = threadIdx.x >> 4;
    float4 acc[4];
    #pragma unroll
    for (int j = 0; j < 4; ++j) acc[j] = make_float4(0.f, 0.f, 0.f, 0.f);
    #pragma unroll
    for (int p = 0; p < 3; ++p) {
        __syncthreads();
        for (int i = threadIdx.x; i < 4096; i += 256) Ws[i] = Wp3[p * 4096 + i];
        __syncthreads();
        #pragma unroll 4
        for (int c = 0; c < 64; ++c) {
            const float4 w = *(const float4*)&Ws[(c << 6) + (tc << 2)];
            #pragma unroll
            for (int j = 0; j < 4; ++j) {
                const int row = (tr << 2) + j;
                float a = As[row * 65 + c];
                if (p == 1) a *= Ss[row * 65 + c];
                else if (p == 2) { const float s = Ss[row * 65 + c]; a *= s * s; }
                acc[j].x += a * w.x; acc[j].y += a * w.y; acc[j].z += a * w.z; acc[j].w += a * w.w;
            }
        }
    }
    #pragma unroll
    for (int j = 0; j < 4; ++j) {
        const int row = (tr << 2) + j;
        const size_t idx = (size_t)l * NC + (size_t)(nb + row) * 64 + (tc << 2);
        const float4 sv = *(const float4*)&sc[idx];
        float4 o;
        o.x = acc[j].x + sv.x; o.y = acc[j].y + sv.y; o.z = acc[j].z + sv.z; o.w = acc[j].w + sv.w;
        *(float4*)&F[idx] = o;
    }
}

// ---------------- readout ----------------
__global__ __launch_bounds__(256) void k_read(const float* __restrict__ F,
    const float* __restrict__ q, const int* __restrict__ batch,
    const float* __restrict__ Wr0, const float* __restrict__ Wa,
    const float* __restrict__ Wb, const float* __restrict__ Wq,
    float* __restrict__ acc, int last)
{
    __shared__ float sred[G];
    if (threadIdx.x < G) sred[threadIdx.x] = 0.f;
    __syncthreads();
    const int n = blockIdx.x * 256 + threadIdx.x;
    if (n < N) {
        float a16[16];
        #pragma unroll
        for (int j = 0; j < 16; ++j) a16[j] = 0.f;
        float ar = 0.f, aq = 0.f;
        const float* f = F + (size_t)n * 64;
        for (int c = 0; c < 64; ++c) {
            const float fv = f[c];
            aq += fv * Wq[c];
            if (last) {
                #pragma unroll
                for (int j = 0; j < 16; ++j) a16[j] += fv * Wa[c * 16 + j];
            } else ar += fv * Wr0[c];
        }
        float en;
        if (last) {
            en = 0.f;
            #pragma unroll
            for (int j = 0; j < 16; ++j) en += silu(a16[j]) * Wb[j];
        } else en = ar;
        en += q[n] * aq;
        atomicAdd(&sred[batch[n]], en);
    }
    __syncthreads();
    if (threadIdx.x < G) atomicAdd(&acc[threadIdx.x * 5], sred[threadIdx.x]);
}

// ---------------- Ewald ----------------
__global__ __launch_bounds__(256) void k_kvec(const float* __restrict__ rcell,
    float* __restrict__ kvec, float* __restrict__ k2)
{
    const int idx = blockIdx.x * 256 + threadIdx.x;
    if (idx >= G * NK) return;
    const int g = idx / NK, k = idx % NK;
    const int kk = k + (k >= 171 ? 1 : 0);
    const int a = kk / 49 - 3, b = (kk / 7) % 7 - 3, c = kk % 7 - 3;
    const float* rc = rcell + g * 9;
    float s = 0.f;
    #pragma unroll
    for (int i = 0; i < 3; ++i) {
        const float kv = 6.283185307f * ((float)a * rc[0 + i] + (float)b * rc[3 + i] + (float)c * rc[6 + i]);
        kvec[idx * 3 + i] = kv;
        s += kv * kv;
    }
    k2[idx] = s;
}

__global__ __launch_bounds__(256) void k_phase(const float* __restrict__ pos,
    const float* __restrict__ q, const float* __restrict__ kvec,
    float* __restrict__ Sr, float* __restrict__ Si)
{
    __shared__ float kvs[38 * 3];
    __shared__ float srs[38], sis[38];
    const int g = blockIdx.z, kc = blockIdx.x, ncb = blockIdx.y;
    const int kbase = kc * 38;
    if (threadIdx.x < 38 * 3) kvs[threadIdx.x] = kvec[((size_t)g * NK + kbase) * 3 + threadIdx.x];
    if (threadIdx.x < 38) { srs[threadIdx.x] = 0.f; sis[threadIdx.x] = 0.f; }
    __syncthreads();
    const int t = threadIdx.x;
    float px = 0.f, py = 0.f, pz = 0.f, qn = 0.f;
    if (t < 250) {
        const int n = g * NGR + ncb * 250 + t;
        px = pos[n * 3]; py = pos[n * 3 + 1]; pz = pos[n * 3 + 2]; qn = q[n];
    }
    const int lane = t & 63;
    for (int j = 0; j < 38; ++j) {
        const float ph = px * kvs[j * 3] + py * kvs[j * 3 + 1] + pz * kvs[j * 3 + 2];
        float sv, cv;
        __sincosf(ph, &sv, &cv);
        float vr = qn * cv, vi = qn * sv;
        #pragma unroll
        for (int o = 32; o > 0; o >>= 1) { vr += __shfl_down(vr, o, 64); vi += __shfl_down(vi, o, 64); }
        if (lane == 0) { atomicAdd(&srs[j], vr); atomicAdd(&sis[j], vi); }
    }
    __syncthreads();
    if (t < 38) {
        atomicAdd(&Sr[g * NK + kbase + t], srs[t]);
        atomicAdd(&Si[g * NK + kbase + t], sis[t]);
    }
}

__global__ __launch_bounds__(512) void k_final(const float* __restrict__ k2,
    const float* __restrict__ Sr, const float* __restrict__ Si,
    const float* __restrict__ vol, const float* __restrict__ acc,
    float* __restrict__ out)
{
    __shared__ float red[512];
    const int g = blockIdx.x, t = threadIdx.x;
    float v = 0.f;
    if (t < NK) {
        const float kk = k2[g * NK + t];
        const float sr = Sr[g * NK + t], si = Si[g * NK + t];
        v = __expf(-0.5f * kk) * (sr * sr + si * si) / kk;
    }
    red[t] = v;
    __syncthreads();
    for (int s2 = 256; s2 > 0; s2 >>= 1) {
        if (t < s2) red[t] += red[t + s2];
        __syncthreads();
    }
    if (t == 0) {
        const float Ees = 6.283185307f / vol[g] * red[0];
        out[g]     = acc[g * 5 + 0] + Ees;
        out[4 + g] = acc[g * 5 + 1];
        out[8 + g * 3 + 0] = acc[g * 5 + 2];
        out[8 + g * 3 + 1] = acc[g * 5 + 3];
        out[8 + g * 3 + 2] = acc[g * 5 + 4];
    }
}

extern "C" void kernel_launch(void* const* d_in, const int* in_sizes, int n_in,
                              void* d_out, int out_size, void* d_ws, size_t ws_size,
                              hipStream_t stream)
{
    const float* na    = (const float*)d_in[0];
    const float* pos   = (const float*)d_in[1];
    const float* shif  = (const float*)d_in[2];
    const float* q     = (const float*)d_in[3];
    const float* rcell = (const float*)d_in[5];
    const float* vol   = (const float*)d_in[6];
    const int*   ei    = (const int*)d_in[7];
    const int*   batch = (const int*)d_in[8];
    const float* embW  = (const float*)d_in[9];
    const float* qcoef = (const float*)d_in[10];
    const float* rW1   = (const float*)d_in[11];
    const float* rW2   = (const float*)d_in[12];
    const float* rW3   = (const float*)d_in[13];
    const float* rW4   = (const float*)d_in[14];
    const float* lup   = (const float*)d_in[15];
    const float* lout  = (const float*)d_in[16];
    const float* Wsc   = (const float*)d_in[17];
    const float* Wp    = (const float*)d_in[18];
    const float* Wr0   = (const float*)d_in[19];
    const float* Wa    = (const float*)d_in[20];
    const float* Wb    = (const float*)d_in[21];
    const float* Wq    = (const float*)d_in[22];
    const float* aE    = (const float*)d_in[23];
    float* out = (float*)d_out;

    float* wsf  = (float*)d_ws;
    float* F    = wsf;                  // [16][N][64]
    float* H    = F    + 8192000;       // [16][N][64]
    float* Aacc = H    + 8192000;       // [16][N][64]
    float* h3   = Aacc + 8192000;       // [E][64]
    float* s1   = h3   + 8192000;       // [N][64]
    float* kvec = s1   + 512000;        // [G*342][3]
    float* k2   = kvec + 4104;          // [G*342]
    float* Sr   = k2   + 1368;
    float* Si   = Sr   + 1368;
    float* acc  = Si   + 1368;          // [G][5]
    int*   elem = (int*)(acc + 32);     // [N]
    int*   perm = elem + 8000;          // [8640]
    int*   counts = perm + 8640;        // [16]
    int*   cursor = counts + 16;        // [16]
    int*   offs   = cursor + 16;        // [16]

    hipMemsetAsync(F, 0, 8192000 * sizeof(float), stream);
    hipMemsetAsync(Sr, 0, (1368 * 2 + 32) * sizeof(float), stream);
    hipMemsetAsync(perm, 0xFF, 8640 * sizeof(int), stream);
    hipMemsetAsync(counts, 0, 32 * sizeof(int), stream);

    k_init<<<32, 256, 0, stream>>>(na, q, pos, batch, aE, elem, acc);
    k_feat0<<<2000, 256, 0, stream>>>(elem, embW, F);
    k_hist<<<32, 256, 0, stream>>>(elem, counts);
    k_offs<<<1, 64, 0, stream>>>(counts, offs);
    k_scatter<<<32, 256, 0, stream>>>(elem, offs, cursor, perm);
    k_kvec<<<6, 256, 0, stream>>>(rcell, kvec, k2);
    k_phase<<<dim3(9, 8, G), 256, 0, stream>>>(pos, q, kvec, Sr, Si);

    for (int t = 0; t < 2; ++t) {
        hipMemsetAsync(Aacc, 0, 8192000 * sizeof(float), stream);
        k_pre<<<2000, 256, 0, stream>>>(q, qcoef + t * 64, F);
        k_lgemm<<<dim3(125, 16), 256, 0, stream>>>(F, lup + t * 4 * 4096, H);
        k_radial<<<512, 512, 0, stream>>>(pos, shif, ei, rW1 + t * 512, rW2 + t * 4096, rW3 + t * 4096, h3);
        k_edge<<<256, 512, 0, stream>>>(pos, shif, ei, H, h3, rW4 + t * 16384, Aacc);
        k_lgemm<<<dim3(125, 16), 256, 0, stream>>>(Aacc, lout + t * 4 * 4096, H);
        k_s1<<<2000, 256, 0, stream>>>(H, s1);
        k_sc<<<dim3(135, 16), 256, 0, stream>>>(F, Wsc + t * NEL * 4096, perm, elem, Aacc);
        k_out<<<dim3(125, 16), 256, 0, stream>>>(H, s1, Wp + t * 3 * 4096, Aacc, F);
        k_read<<<32, 256, 0, stream>>>(F, q, batch, Wr0, Wa, Wb, Wq + t * 64, acc, t == 1);
    }
    k_final<<<G, 512, 0, stream>>>(k2, Sr, Si, vol, acc, out);
}

// Round 2
// 1436.920 us; speedup vs baseline: 1.1739x; 1.1739x over previous
//
#include <hip/hip_runtime.h>

constexpr int N    = 8000;
constexpr int E    = 128000;
constexpr int G    = 4;
constexpr int C    = 64;
constexpr int NLM  = 16;
constexpr int NEL  = 10;
constexpr int NGR  = N / G;          // 2000
constexpr int NC   = N * C;          // 512000
constexpr int NK   = 342;            // Ewald vectors
constexpr float RMAX = 5.0f;

__device__ __forceinline__ int lmap_rt(int l) { return (l >= 1) + (l >= 4) + (l >= 9); }
__device__ __forceinline__ float silu(float x) { return x / (1.f + __expf(-x)); }

// ---------------- init: elem, e0/charge/dipole ----------------
__global__ __launch_bounds__(256) void k_init(const float* __restrict__ na,
    const float* __restrict__ q, const float* __restrict__ pos,
    const int* __restrict__ batch, const float* __restrict__ aE,
    int* __restrict__ elem, float* __restrict__ acc)
{
    __shared__ float s[G * 5];
    if (threadIdx.x < G * 5) s[threadIdx.x] = 0.f;
    __syncthreads();
    const int n = blockIdx.x * 256 + threadIdx.x;
    if (n < N) {
        int el = 0; float best = na[n * NEL];
        #pragma unroll
        for (int j = 1; j < NEL; ++j) { float v = na[n * NEL + j]; if (v > best) { best = v; el = j; } }
        elem[n] = el;
        const int g = batch[n];
        const float qn = q[n];
        atomicAdd(&s[g * 5 + 0], aE[el]);
        atomicAdd(&s[g * 5 + 1], qn);
        atomicAdd(&s[g * 5 + 2], qn * pos[n * 3 + 0]);
        atomicAdd(&s[g * 5 + 3], qn * pos[n * 3 + 1]);
        atomicAdd(&s[g * 5 + 4], qn * pos[n * 3 + 2]);
    }
    __syncthreads();
    if (threadIdx.x < G * 5) atomicAdd(&acc[threadIdx.x], s[threadIdx.x]);
}

__global__ __launch_bounds__(256) void k_feat0(const int* __restrict__ elem,
    const float* __restrict__ embW, float* __restrict__ F)
{
    const int i = blockIdx.x * 256 + threadIdx.x;
    if (i < NC) F[i] = embW[elem[i >> 6] * 64 + (i & 63)];
}

__global__ __launch_bounds__(256) void k_pre(const float* __restrict__ q,
    const float* __restrict__ qc, float* __restrict__ F)
{
    const int i = blockIdx.x * 256 + threadIdx.x;
    if (i < NC) F[i] += q[i >> 6] * qc[i & 63];
}

// ---------------- element bucketing ----------------
__global__ __launch_bounds__(256) void k_hist(const int* __restrict__ elem, int* __restrict__ counts)
{
    const int n = blockIdx.x * 256 + threadIdx.x;
    if (n < N) atomicAdd(&counts[elem[n]], 1);
}
__global__ void k_offs(const int* __restrict__ counts, int* __restrict__ offs)
{
    if (threadIdx.x == 0 && blockIdx.x == 0) {
        int o = 0;
        for (int j = 0; j < NEL; ++j) { offs[j] = o; o += (counts[j] + 63) & ~63; }
        offs[NEL] = o;
    }
}
__global__ __launch_bounds__(256) void k_scatter(const int* __restrict__ elem,
    const int* __restrict__ offs, int* __restrict__ cursor, int* __restrict__ perm)
{
    const int n = blockIdx.x * 256 + threadIdx.x;
    if (n < N) {
        const int el = elem[n];
        const int p = atomicAdd(&cursor[el], 1);
        perm[offs[el] + p] = n;
    }
}

// ---------------- receiver CSR build ----------------
__global__ __launch_bounds__(256) void k_gcnt(const int* __restrict__ ei, int* __restrict__ cnt)
{
    const int e = blockIdx.x * 256 + threadIdx.x;
    if (e < E) atomicAdd(&cnt[ei[E + e]], 1);
}
__global__ __launch_bounds__(1024) void k_goff(const int* __restrict__ cnt, int* __restrict__ roff)
{
    __shared__ int part[1024];
    const int t = threadIdx.x;
    const int base = t * 8;
    int loc[8];
    int s = 0;
    #pragma unroll
    for (int i = 0; i < 8; ++i) { loc[i] = s; s += (base + i < N) ? cnt[base + i] : 0; }
    part[t] = s;
    __syncthreads();
    for (int d = 1; d < 1024; d <<= 1) {
        const int v = (t >= d) ? part[t - d] : 0;
        __syncthreads();
        part[t] += v;
        __syncthreads();
    }
    const int excl = (t == 0) ? 0 : part[t - 1];
    #pragma unroll
    for (int i = 0; i < 8; ++i) if (base + i < N) roff[base + i] = excl + loc[i];
    if (t == 0) roff[N] = E;
}
__global__ __launch_bounds__(256) void k_gscat(const int* __restrict__ ei,
    const int* __restrict__ roff, int* __restrict__ cur, int* __restrict__ elist)
{
    const int e = blockIdx.x * 256 + threadIdx.x;
    if (e < E) {
        const int rv = ei[E + e];
        const int p = atomicAdd(&cur[rv], 1);
        elist[roff[rv] + p] = e;
    }
}

// ---------------- per-l GEMM: Out[l][n][d] = sum_c X[l][n][c] * W[lmap(l)][c][d] ----------------
__global__ __launch_bounds__(256) void k_lgemm(const float* __restrict__ X,
    const float* __restrict__ Wb, float* __restrict__ Out)
{
    __shared__ float Ws[4096];
    __shared__ float Xs[64 * 65];
    const int l  = blockIdx.y;
    const int nb = blockIdx.x << 6;
    const float* W = Wb + lmap_rt(l) * 4096;
    for (int i = threadIdx.x; i < 4096; i += 256) Ws[i] = W[i];
    const float* Xp = X + (size_t)l * NC + (size_t)nb * 64;
    for (int i = threadIdx.x; i < 4096; i += 256) Xs[(i >> 6) * 65 + (i & 63)] = Xp[i];
    __syncthreads();
    const int tc = threadIdx.x & 15;
    const int tr = threadIdx.x >> 4;
    float4 acc[4];
    #pragma unroll
    for (int j = 0; j < 4; ++j) acc[j] = make_float4(0.f, 0.f, 0.f, 0.f);
    #pragma unroll 8
    for (int c = 0; c < 64; ++c) {
        const float4 w = *(const float4*)&Ws[(c << 6) + (tc << 2)];
        #pragma unroll
        for (int j = 0; j < 4; ++j) {
            const float x = Xs[((tr << 2) + j) * 65 + c];
            acc[j].x += x * w.x; acc[j].y += x * w.y; acc[j].z += x * w.z; acc[j].w += x * w.w;
        }
    }
    float* Op = Out + (size_t)l * NC + (size_t)nb * 64;
    #pragma unroll
    for (int j = 0; j < 4; ++j)
        *(float4*)&Op[((tr << 2) + j) * 64 + (tc << 2)] = acc[j];
}

// ---------------- sc GEMM over element buckets ----------------
__global__ __launch_bounds__(256) void k_sc(const float* __restrict__ F,
    const float* __restrict__ Wsc, const int* __restrict__ perm,
    const int* __restrict__ elem, float* __restrict__ Out)
{
    __shared__ float Ws[4096];
    __shared__ float Xs[64 * 65];
    __shared__ int rows[64];
    const int l  = blockIdx.y;
    const int tb = blockIdx.x << 6;
    if (threadIdx.x < 64) rows[threadIdx.x] = perm[tb + threadIdx.x];
    __syncthreads();
    if (rows[0] < 0) return;
    const float* W = Wsc + elem[rows[0]] * 4096;
    for (int i = threadIdx.x; i < 4096; i += 256) Ws[i] = W[i];
    for (int i = threadIdx.x; i < 4096; i += 256) {
        const int rr = i >> 6, cc = i & 63;
        const int n = rows[rr];
        Xs[rr * 65 + cc] = (n >= 0) ? F[(size_t)l * NC + (size_t)n * 64 + cc] : 0.f;
    }
    __syncthreads();
    const int tc = threadIdx.x & 15;
    const int tr = threadIdx.x >> 4;
    float4 acc[4];
    #pragma unroll
    for (int j = 0; j < 4; ++j) acc[j] = make_float4(0.f, 0.f, 0.f, 0.f);
    #pragma unroll 8
    for (int c = 0; c < 64; ++c) {
        const float4 w = *(const float4*)&Ws[(c << 6) + (tc << 2)];
        #pragma unroll
        for (int j = 0; j < 4; ++j) {
            const float x = Xs[((tr << 2) + j) * 65 + c];
            acc[j].x += x * w.x; acc[j].y += x * w.y; acc[j].z += x * w.z; acc[j].w += x * w.w;
        }
    }
    #pragma unroll
    for (int j = 0; j < 4; ++j) {
        const int n = rows[(tr << 2) + j];
        if (n >= 0) *(float4*)&Out[(size_t)l * NC + (size_t)n * 64 + (tc << 2)] = acc[j];
    }
}

// ---------------- radial MLP (h1..h3), wave per edge ----------------
__global__ __launch_bounds__(512) void k_radial(const float* __restrict__ pos,
    const float* __restrict__ shifts, const int* __restrict__ ei,
    const float* __restrict__ W1, const float* __restrict__ W2,
    const float* __restrict__ W3, float* __restrict__ h3buf)
{
    __shared__ float W1s[512], W2s[4096], W3s[4096];
    for (int i = threadIdx.x; i < 512; i += 512) W1s[i] = W1[i];
    for (int i = threadIdx.x; i < 4096; i += 512) { W2s[i] = W2[i]; W3s[i] = W3[i]; }
    __syncthreads();
    const int lane = threadIdx.x & 63;
    const int w0i  = blockIdx.x * 8 + (threadIdx.x >> 6);
    const int nw   = gridDim.x * 8;
    for (int e = w0i; e < E; e += nw) {
        const int s  = ei[e], rv = ei[E + e];
        const float dx = pos[rv * 3 + 0] - pos[s * 3 + 0] + shifts[e * 3 + 0];
        const float dy = pos[rv * 3 + 1] - pos[s * 3 + 1] + shifts[e * 3 + 1];
        const float dz = pos[rv * 3 + 2] - pos[s * 3 + 2] + shifts[e * 3 + 2];
        const float r = sqrtf(dx * dx + dy * dy + dz * dz);
        if (r >= RMAX) continue;
        const float u  = r * 0.2f;
        const float u2 = u * u, u5 = u2 * u2 * u;
        const float fc = 1.f - 21.f * u5 + 35.f * u5 * u - 15.f * u5 * u2;
        const float pref = 0.63245553f * fc / (r + 1e-9f);
        const float piu = 3.14159265358979f * u;
        float h1 = 0.f;
        #pragma unroll
        for (int b = 0; b < 8; ++b)
            h1 += __sinf((float)(b + 1) * piu) * pref * W1s[b * 64 + lane];
        h1 = silu(h1);
        float h2 = 0.f;
        #pragma unroll
        for (int k = 0; k < 64; ++k) h2 += __shfl(h1, k, 64) * W2s[k * 64 + lane];
        h2 = silu(h2);
        float h3 = 0.f;
        #pragma unroll
        for (int k = 0; k < 64; ++k) h3 += __shfl(h2, k, 64) * W3s[k * 64 + lane];
        h3 = silu(h3);
        h3buf[(size_t)e * 64 + lane] = h3;
    }
}

// ---------------- fused gather: per-receiver wave, no atomics ----------------
__global__ __launch_bounds__(512) void k_gather(const float* __restrict__ pos,
    const float* __restrict__ shifts, const int* __restrict__ ei,
    const float* __restrict__ H, const float* __restrict__ h3buf,
    const float* __restrict__ W4, const int* __restrict__ roff,
    const int* __restrict__ elist, float* __restrict__ A)
{
    __shared__ float W4s[16384];
    for (int i = threadIdx.x; i < 16384; i += 512) W4s[i] = W4[i];
    __syncthreads();
    const int lane = threadIdx.x & 63;
    const int n = blockIdx.x * 8 + (threadIdx.x >> 6);
    float acc[16];
    #pragma unroll
    for (int l = 0; l < 16; ++l) acc[l] = 0.f;
    const int j0 = roff[n], j1 = roff[n + 1];
    const float p0x = pos[n * 3], p0y = pos[n * 3 + 1], p0z = pos[n * 3 + 2];
    for (int j = j0; j < j1; ++j) {
        const int e = elist[j];
        const int s = ei[e];
        const float dx = p0x - pos[s * 3 + 0] + shifts[e * 3 + 0];
        const float dy = p0y - pos[s * 3 + 1] + shifts[e * 3 + 1];
        const float dz = p0z - pos[s * 3 + 2] + shifts[e * 3 + 2];
        const float r = sqrtf(dx * dx + dy * dy + dz * dz);
        if (r >= RMAX) continue;
        const float inv = 1.f / (r + 1e-9f);
        const float x = dx * inv, y = dy * inv, z = dz * inv;
        const float xx = x * x, yy = y * y, zz = z * z;
        float Y[16];
        Y[0] = 1.f;
        Y[1] = 1.7320508f * x;  Y[2] = 1.7320508f * y;  Y[3] = 1.7320508f * z;
        Y[4] = 3.8729833f * x * y;  Y[5] = 3.8729833f * y * z;
        Y[6] = 0.5f * 2.2360680f * (3.f * zz - 1.f);
        Y[7] = 3.8729833f * x * z;  Y[8] = 0.5f * 3.8729833f * (xx - yy);
        Y[9]  = 2.0916500f * y * (3.f * xx - yy);
        Y[10] = 10.2469508f * x * y * z;
        Y[11] = 1.6201852f * y * (5.f * zz - 1.f);
        Y[12] = 0.5f * 2.6457513f * z * (5.f * zz - 3.f);
        Y[13] = 1.6201852f * x * (5.f * zz - 1.f);
        Y[14] = 0.5f * 10.2469508f * z * (xx - yy);
        Y[15] = 2.0916500f * x * (xx - 3.f * yy);
        // s_e (sender features), fold /AVG_NEIGH
        float se = 0.f;
        const float* Hp = H + (size_t)s * 64 + lane;
        #pragma unroll
        for (int l = 0; l < 16; ++l) se += Hp[(size_t)l * NC] * Y[l];
        se *= 0.0625f;
        // w[lane][0..3] via W4 shuffle-GEMM
        const float v = h3buf[(size_t)e * 64 + lane];
        float wa = 0.f, wb = 0.f, wc = 0.f, wd = 0.f;
        #pragma unroll
        for (int k = 0; k < 64; ++k) {
            const float hk = __shfl(v, k, 64);
            const float4 q4 = *(const float4*)&W4s[(k << 8) + (lane << 2)];
            wa += hk * q4.x; wb += hk * q4.y; wc += hk * q4.z; wd += hk * q4.w;
        }
        const float wl[4] = { wa * se, wb * se, wc * se, wd * se };
        #pragma unroll
        for (int l = 0; l < 16; ++l) {
            constexpr int LM[16] = {0,1,1,1,2,2,2,2,2,3,3,3,3,3,3,3};
            acc[l] += wl[LM[l]] * Y[l];
        }
    }
    float* Ap = A + (size_t)n * 64 + lane;
    #pragma unroll
    for (int l = 0; l < 16; ++l) Ap[(size_t)l * NC] = acc[l];
}

// ---------------- s1[n][c] = sum_l A'[l][n][c]^2 ----------------
__global__ __launch_bounds__(256) void k_s1(const float* __restrict__ H, float* __restrict__ s1)
{
    const int i = blockIdx.x * 256 + threadIdx.x;
    if (i < NC) {
        float s = 0.f;
        #pragma unroll
        for (int l = 0; l < 16; ++l) { const float a = H[(size_t)l * NC + i]; s += a * a; }
        s1[i] = s;
    }
}

// ---------------- out = sum_p (A'*s1^p)@Wp_p + sc -> F ----------------
__global__ __launch_bounds__(256) void k_out(const float* __restrict__ Ap,
    const float* __restrict__ s1, const float* __restrict__ Wp3,
    const float* __restrict__ sc, float* __restrict__ F)
{
    __shared__ float As[64 * 65];
    __shared__ float Ss[64 * 65];
    __shared__ float Ws[4096];
    const int l  = blockIdx.y;
    const int nb = blockIdx.x << 6;
    const float* Xp = Ap + (size_t)l * NC + (size_t)nb * 64;
    for (int i = threadIdx.x; i < 4096; i += 256) {
        As[(i >> 6) * 65 + (i & 63)] = Xp[i];
        Ss[(i >> 6) * 65 + (i & 63)] = s1[nb * 64 + i];
    }
    const int tc = threadIdx.x & 15;
    const int tr = threadIdx.x >> 4;
    float4 acc[4];
    #pragma unroll
    for (int j = 0; j < 4; ++j) acc[j] = make_float4(0.f, 0.f, 0.f, 0.f);
    #pragma unroll
    for (int p = 0; p < 3; ++p) {
        __syncthreads();
        for (int i = threadIdx.x; i < 4096; i += 256) Ws[i] = Wp3[p * 4096 + i];
        __syncthreads();
        #pragma unroll 4
        for (int c = 0; c < 64; ++c) {
            const float4 w = *(const float4*)&Ws[(c << 6) + (tc << 2)];
            #pragma unroll
            for (int j = 0; j < 4; ++j) {
                const int row = (tr << 2) + j;
                float a = As[row * 65 + c];
                if (p == 1) a *= Ss[row * 65 + c];
                else if (p == 2) { const float s = Ss[row * 65 + c]; a *= s * s; }
                acc[j].x += a * w.x; acc[j].y += a * w.y; acc[j].z += a * w.z; acc[j].w += a * w.w;
            }
        }
    }
    #pragma unroll
    for (int j = 0; j < 4; ++j) {
        const int row = (tr << 2) + j;
        const size_t idx = (size_t)l * NC + (size_t)(nb + row) * 64 + (tc << 2);
        const float4 sv = *(const float4*)&sc[idx];
        float4 o;
        o.x = acc[j].x + sv.x; o.y = acc[j].y + sv.y; o.z = acc[j].z + sv.z; o.w = acc[j].w + sv.w;
        *(float4*)&F[idx] = o;
    }
}

// ---------------- readout ----------------
__global__ __launch_bounds__(256) void k_read(const float* __restrict__ F,
    const float* __restrict__ q, const int* __restrict__ batch,
    const float* __restrict__ Wr0, const float* __restrict__ Wa,
    const float* __restrict__ Wb, const float* __restrict__ Wq,
    float* __restrict__ acc, int last)
{
    __shared__ float sred[G];
    if (threadIdx.x < G) sred[threadIdx.x] = 0.f;
    __syncthreads();
    const int n = blockIdx.x * 256 + threadIdx.x;
    if (n < N) {
        float a16[16];
        #pragma unroll
        for (int j = 0; j < 16; ++j) a16[j] = 0.f;
        float ar = 0.f, aq = 0.f;
        const float* f = F + (size_t)n * 64;
        for (int c = 0; c < 64; ++c) {
            const float fv = f[c];
            aq += fv * Wq[c];
            if (last) {
                #pragma unroll
                for (int j = 0; j < 16; ++j) a16[j] += fv * Wa[c * 16 + j];
            } else ar += fv * Wr0[c];
        }
        float en;
        if (last) {
            en = 0.f;
            #pragma unroll
            for (int j = 0; j < 16; ++j) en += silu(a16[j]) * Wb[j];
        } else en = ar;
        en += q[n] * aq;
        atomicAdd(&sred[batch[n]], en);
    }
    __syncthreads();
    if (threadIdx.x < G) atomicAdd(&acc[threadIdx.x * 5], sred[threadIdx.x]);
}

// ---------------- Ewald ----------------
__global__ __launch_bounds__(256) void k_kvec(const float* __restrict__ rcell,
    float* __restrict__ kvec, float* __restrict__ k2)
{
    const int idx = blockIdx.x * 256 + threadIdx.x;
    if (idx >= G * NK) return;
    const int g = idx / NK, k = idx % NK;
    const int kk = k + (k >= 171 ? 1 : 0);
    const int a = kk / 49 - 3, b = (kk / 7) % 7 - 3, c = kk % 7 - 3;
    const float* rc = rcell + g * 9;
    float s = 0.f;
    #pragma unroll
    for (int i = 0; i < 3; ++i) {
        const float kv = 6.283185307f * ((float)a * rc[0 + i] + (float)b * rc[3 + i] + (float)c * rc[6 + i]);
        kvec[idx * 3 + i] = kv;
        s += kv * kv;
    }
    k2[idx] = s;
}

__global__ __launch_bounds__(256) void k_phase(const float* __restrict__ pos,
    const float* __restrict__ q, const float* __restrict__ kvec,
    float* __restrict__ Sr, float* __restrict__ Si)
{
    __shared__ float kvs[38 * 3];
    __shared__ float srs[38], sis[38];
    const int g = blockIdx.z, kc = blockIdx.x, ncb = blockIdx.y;
    const int kbase = kc * 38;
    if (threadIdx.x < 38 * 3) kvs[threadIdx.x] = kvec[((size_t)g * NK + kbase) * 3 + threadIdx.x];
    if (threadIdx.x < 38) { srs[threadIdx.x] = 0.f; sis[threadIdx.x] = 0.f; }
    __syncthreads();
    const int t = threadIdx.x;
    float px = 0.f, py = 0.f, pz = 0.f, qn = 0.f;
    if (t < 250) {
        const int n = g * NGR + ncb * 250 + t;
        px = pos[n * 3]; py = pos[n * 3 + 1]; pz = pos[n * 3 + 2]; qn = q[n];
    }
    const int lane = t & 63;
    for (int j = 0; j < 38; ++j) {
        const float ph = px * kvs[j * 3] + py * kvs[j * 3 + 1] + pz * kvs[j * 3 + 2];
        float sv, cv;
        __sincosf(ph, &sv, &cv);
        float vr = qn * cv, vi = qn * sv;
        #pragma unroll
        for (int o = 32; o > 0; o >>= 1) { vr += __shfl_down(vr, o, 64); vi += __shfl_down(vi, o, 64); }
        if (lane == 0) { atomicAdd(&srs[j], vr); atomicAdd(&sis[j], vi); }
    }
    __syncthreads();
    if (t < 38) {
        atomicAdd(&Sr[g * NK + kbase + t], srs[t]);
        atomicAdd(&Si[g * NK + kbase + t], sis[t]);
    }
}

__global__ __launch_bounds__(512) void k_final(const float* __restrict__ k2,
    const float* __restrict__ Sr, const float* __restrict__ Si,
    const float* __restrict__ vol, const float* __restrict__ acc,
    float* __restrict__ out)
{
    __shared__ float red[512];
    const int g = blockIdx.x, t = threadIdx.x;
    float v = 0.f;
    if (t < NK) {
        const float kk = k2[g * NK + t];
        const float sr = Sr[g * NK + t], si = Si[g * NK + t];
        v = __expf(-0.5f * kk) * (sr * sr + si * si) / kk;
    }
    red[t] = v;
    __syncthreads();
    for (int s2 = 256; s2 > 0; s2 >>= 1) {
        if (t < s2) red[t] += red[t + s2];
        __syncthreads();
    }
    if (t == 0) {
        const float Ees = 6.283185307f / vol[g] * red[0];
        out[g]     = acc[g * 5 + 0] + Ees;
        out[4 + g] = acc[g * 5 + 1];
        out[8 + g * 3 + 0] = acc[g * 5 + 2];
        out[8 + g * 3 + 1] = acc[g * 5 + 3];
        out[8 + g * 3 + 2] = acc[g * 5 + 4];
    }
}

extern "C" void kernel_launch(void* const* d_in, const int* in_sizes, int n_in,
                              void* d_out, int out_size, void* d_ws, size_t ws_size,
                              hipStream_t stream)
{
    const float* na    = (const float*)d_in[0];
    const float* pos   = (const float*)d_in[1];
    const float* shif  = (const float*)d_in[2];
    const float* q     = (const float*)d_in[3];
    const float* rcell = (const float*)d_in[5];
    const float* vol   = (const float*)d_in[6];
    const int*   ei    = (const int*)d_in[7];
    const int*   batch = (const int*)d_in[8];
    const float* embW  = (const float*)d_in[9];
    const float* qcoef = (const float*)d_in[10];
    const float* rW1   = (const float*)d_in[11];
    const float* rW2   = (const float*)d_in[12];
    const float* rW3   = (const float*)d_in[13];
    const float* rW4   = (const float*)d_in[14];
    const float* lup   = (const float*)d_in[15];
    const float* lout  = (const float*)d_in[16];
    const float* Wsc   = (const float*)d_in[17];
    const float* Wp    = (const float*)d_in[18];
    const float* Wr0   = (const float*)d_in[19];
    const float* Wa    = (const float*)d_in[20];
    const float* Wb    = (const float*)d_in[21];
    const float* Wq    = (const float*)d_in[22];
    const float* aE    = (const float*)d_in[23];
    float* out = (float*)d_out;

    float* wsf  = (float*)d_ws;
    float* F    = wsf;                  // [16][N][64]
    float* H    = F    + 8192000;       // [16][N][64]
    float* Asc  = H    + 8192000;       // [16][N][64]  (A result, then sc buffer)
    float* h3   = Asc  + 8192000;       // [E][64]
    float* s1   = h3   + 8192000;       // [N][64]
    float* kvec = s1   + 512000;        // [G*342][3]
    float* k2   = kvec + 4104;          // [G*342]
    float* Sr   = k2   + 1368;
    float* Si   = Sr   + 1368;
    float* acc  = Si   + 1368;          // [G][5]
    int*   elem = (int*)(acc + 32);     // [N]
    int*   perm = elem + 8000;          // [8640]
    int*   counts = perm + 8640;        // [16]
    int*   cursor = counts + 16;        // [16]
    int*   offs   = cursor + 16;        // [16+...]
    int*   roff   = offs + 16;          // [N+1]
    int*   cnt    = roff + 8001;        // [N]
    int*   cur    = cnt + 8000;         // [N]
    int*   elist  = cur + 8000;         // [E]

    hipMemsetAsync(F, 0, 8192000 * sizeof(float), stream);
    hipMemsetAsync(Sr, 0, (1368 * 2 + 32) * sizeof(float), stream);
    hipMemsetAsync(perm, 0xFF, 8640 * sizeof(int), stream);
    hipMemsetAsync(counts, 0, 32 * sizeof(int), stream);
    hipMemsetAsync(cnt, 0, 16000 * sizeof(int), stream);

    k_init<<<32, 256, 0, stream>>>(na, q, pos, batch, aE, elem, acc);
    k_feat0<<<2000, 256, 0, stream>>>(elem, embW, F);
    k_hist<<<32, 256, 0, stream>>>(elem, counts);
    k_offs<<<1, 64, 0, stream>>>(counts, offs);
    k_scatter<<<32, 256, 0, stream>>>(elem, offs, cursor, perm);
    k_gcnt<<<500, 256, 0, stream>>>(ei, cnt);
    k_goff<<<1, 1024, 0, stream>>>(cnt, roff);
    k_gscat<<<500, 256, 0, stream>>>(ei, roff, cur, elist);
    k_kvec<<<6, 256, 0, stream>>>(rcell, kvec, k2);
    k_phase<<<dim3(9, 8, G), 256, 0, stream>>>(pos, q, kvec, Sr, Si);

    for (int t = 0; t < 2; ++t) {
        k_pre<<<2000, 256, 0, stream>>>(q, qcoef + t * 64, F);
        k_lgemm<<<dim3(125, 16), 256, 0, stream>>>(F, lup + t * 4 * 4096, H);
        k_radial<<<1024, 512, 0, stream>>>(pos, shif, ei, rW1 + t * 512, rW2 + t * 4096, rW3 + t * 4096, h3);
        k_gather<<<1000, 512, 0, stream>>>(pos, shif, ei, H, h3, rW4 + t * 16384, roff, elist, Asc);
        k_lgemm<<<dim3(125, 16), 256, 0, stream>>>(Asc, lout + t * 4 * 4096, H);
        k_s1<<<2000, 256, 0, stream>>>(H, s1);
        k_sc<<<dim3(135, 16), 256, 0, stream>>>(F, Wsc + t * NEL * 4096, perm, elem, Asc);
        k_out<<<dim3(125, 16), 256, 0, stream>>>(H, s1, Wp + t * 3 * 4096, Asc, F);
        k_read<<<32, 256, 0, stream>>>(F, q, batch, Wr0, Wa, Wb, Wq + t * 64, acc, t == 1);
    }
    k_final<<<G, 512, 0, stream>>>(k2, Sr, Si, vol, acc, out);
}

// Round 3
// 1411.163 us; speedup vs baseline: 1.1953x; 1.0183x over previous
//
#include <hip/hip_runtime.h>

constexpr int N    = 8000;
constexpr int E    = 128000;
constexpr int G    = 4;
constexpr int C    = 64;
constexpr int NLM  = 16;
constexpr int NEL  = 10;
constexpr int NGR  = N / G;          // 2000
constexpr int NC   = N * C;          // 512000
constexpr int NK   = 342;            // Ewald vectors
constexpr float RMAX = 5.0f;
constexpr int NRCH  = 1600;          // receivers per chunk (5 chunks)
constexpr int TILES = 460;           // 460*64=29440 covers chunk edges (mean 25600, sigma~143)

__device__ __forceinline__ int lmap_rt(int l) { return (l >= 1) + (l >= 4) + (l >= 9); }
__device__ __forceinline__ float silu(float x) { return x / (1.f + __expf(-x)); }

// ---------------- init: elem, e0/charge/dipole ----------------
__global__ __launch_bounds__(256) void k_init(const float* __restrict__ na,
    const float* __restrict__ q, const float* __restrict__ pos,
    const int* __restrict__ batch, const float* __restrict__ aE,
    int* __restrict__ elem, float* __restrict__ acc)
{
    __shared__ float s[G * 5];
    if (threadIdx.x < G * 5) s[threadIdx.x] = 0.f;
    __syncthreads();
    const int n = blockIdx.x * 256 + threadIdx.x;
    if (n < N) {
        int el = 0; float best = na[n * NEL];
        #pragma unroll
        for (int j = 1; j < NEL; ++j) { float v = na[n * NEL + j]; if (v > best) { best = v; el = j; } }
        elem[n] = el;
        const int g = batch[n];
        const float qn = q[n];
        atomicAdd(&s[g * 5 + 0], aE[el]);
        atomicAdd(&s[g * 5 + 1], qn);
        atomicAdd(&s[g * 5 + 2], qn * pos[n * 3 + 0]);
        atomicAdd(&s[g * 5 + 3], qn * pos[n * 3 + 1]);
        atomicAdd(&s[g * 5 + 4], qn * pos[n * 3 + 2]);
    }
    __syncthreads();
    if (threadIdx.x < G * 5) atomicAdd(&acc[threadIdx.x], s[threadIdx.x]);
}

__global__ __launch_bounds__(256) void k_feat0(const int* __restrict__ elem,
    const float* __restrict__ embW, float* __restrict__ F)
{
    const int i = blockIdx.x * 256 + threadIdx.x;
    if (i < NC) F[i] = embW[elem[i >> 6] * 64 + (i & 63)];
}

__global__ __launch_bounds__(256) void k_pre(const float* __restrict__ q,
    const float* __restrict__ qc, float* __restrict__ F)
{
    const int i = blockIdx.x * 256 + threadIdx.x;
    if (i < NC) F[i] += q[i >> 6] * qc[i & 63];
}

// ---------------- element bucketing ----------------
__global__ __launch_bounds__(256) void k_hist(const int* __restrict__ elem, int* __restrict__ counts)
{
    const int n = blockIdx.x * 256 + threadIdx.x;
    if (n < N) atomicAdd(&counts[elem[n]], 1);
}
__global__ void k_offs(const int* __restrict__ counts, int* __restrict__ offs)
{
    if (threadIdx.x == 0 && blockIdx.x == 0) {
        int o = 0;
        for (int j = 0; j < NEL; ++j) { offs[j] = o; o += (counts[j] + 63) & ~63; }
        offs[NEL] = o;
    }
}
__global__ __launch_bounds__(256) void k_scatter(const int* __restrict__ elem,
    const int* __restrict__ offs, int* __restrict__ cursor, int* __restrict__ perm)
{
    const int n = blockIdx.x * 256 + threadIdx.x;
    if (n < N) {
        const int el = elem[n];
        const int p = atomicAdd(&cursor[el], 1);
        perm[offs[el] + p] = n;
    }
}

// ---------------- receiver CSR build ----------------
__global__ __launch_bounds__(256) void k_gcnt(const int* __restrict__ ei, int* __restrict__ cnt)
{
    const int e = blockIdx.x * 256 + threadIdx.x;
    if (e < E) atomicAdd(&cnt[ei[E + e]], 1);
}
__global__ __launch_bounds__(1024) void k_goff(const int* __restrict__ cnt, int* __restrict__ roff)
{
    __shared__ int part[1024];
    const int t = threadIdx.x;
    const int base = t * 8;
    int loc[8];
    int s = 0;
    #pragma unroll
    for (int i = 0; i < 8; ++i) { loc[i] = s; s += (base + i < N) ? cnt[base + i] : 0; }
    part[t] = s;
    __syncthreads();
    for (int d = 1; d < 1024; d <<= 1) {
        const int v = (t >= d) ? part[t - d] : 0;
        __syncthreads();
        part[t] += v;
        __syncthreads();
    }
    const int excl = (t == 0) ? 0 : part[t - 1];
    #pragma unroll
    for (int i = 0; i < 8; ++i) if (base + i < N) roff[base + i] = excl + loc[i];
    if (t == 0) roff[N] = E;
}
__global__ __launch_bounds__(256) void k_gscat(const int* __restrict__ ei,
    const int* __restrict__ roff, int* __restrict__ cur, int* __restrict__ elist)
{
    const int e = blockIdx.x * 256 + threadIdx.x;
    if (e < E) {
        const int rv = ei[E + e];
        const int p = atomicAdd(&cur[rv], 1);
        elist[roff[rv] + p] = e;
    }
}

// ---------------- per-l GEMM: Out[l][n][d] = sum_c X[l][n][c] * W[lmap(l)][c][d] ----------------
__global__ __launch_bounds__(256) void k_lgemm(const float* __restrict__ X,
    const float* __restrict__ Wb, float* __restrict__ Out)
{
    __shared__ float Ws[4096];
    __shared__ float Xs[64 * 65];
    const int l  = blockIdx.y;
    const int nb = blockIdx.x << 6;
    const float* W = Wb + lmap_rt(l) * 4096;
    for (int i = threadIdx.x; i < 4096; i += 256) Ws[i] = W[i];
    const float* Xp = X + (size_t)l * NC + (size_t)nb * 64;
    for (int i = threadIdx.x; i < 4096; i += 256) Xs[(i >> 6) * 65 + (i & 63)] = Xp[i];
    __syncthreads();
    const int tc = threadIdx.x & 15;
    const int tr = threadIdx.x >> 4;
    float4 acc[4];
    #pragma unroll
    for (int j = 0; j < 4; ++j) acc[j] = make_float4(0.f, 0.f, 0.f, 0.f);
    #pragma unroll 8
    for (int c = 0; c < 64; ++c) {
        const float4 w = *(const float4*)&Ws[(c << 6) + (tc << 2)];
        #pragma unroll
        for (int j = 0; j < 4; ++j) {
            const float x = Xs[((tr << 2) + j) * 65 + c];
            acc[j].x += x * w.x; acc[j].y += x * w.y; acc[j].z += x * w.z; acc[j].w += x * w.w;
        }
    }
    float* Op = Out + (size_t)l * NC + (size_t)nb * 64;
    #pragma unroll
    for (int j = 0; j < 4; ++j)
        *(float4*)&Op[((tr << 2) + j) * 64 + (tc << 2)] = acc[j];
}

// ---------------- sc GEMM over element buckets ----------------
__global__ __launch_bounds__(256) void k_sc(const float* __restrict__ F,
    const float* __restrict__ Wsc, const int* __restrict__ perm,
    const int* __restrict__ elem, float* __restrict__ Out)
{
    __shared__ float Ws[4096];
    __shared__ float Xs[64 * 65];
    __shared__ int rows[64];
    const int l  = blockIdx.y;
    const int tb = blockIdx.x << 6;
    if (threadIdx.x < 64) rows[threadIdx.x] = perm[tb + threadIdx.x];
    __syncthreads();
    if (rows[0] < 0) return;
    const float* W = Wsc + elem[rows[0]] * 4096;
    for (int i = threadIdx.x; i < 4096; i += 256) Ws[i] = W[i];
    for (int i = threadIdx.x; i < 4096; i += 256) {
        const int rr = i >> 6, cc = i & 63;
        const int n = rows[rr];
        Xs[rr * 65 + cc] = (n >= 0) ? F[(size_t)l * NC + (size_t)n * 64 + cc] : 0.f;
    }
    __syncthreads();
    const int tc = threadIdx.x & 15;
    const int tr = threadIdx.x >> 4;
    float4 acc[4];
    #pragma unroll
    for (int j = 0; j < 4; ++j) acc[j] = make_float4(0.f, 0.f, 0.f, 0.f);
    #pragma unroll 8
    for (int c = 0; c < 64; ++c) {
        const float4 w = *(const float4*)&Ws[(c << 6) + (tc << 2)];
        #pragma unroll
        for (int j = 0; j < 4; ++j) {
            const float x = Xs[((tr << 2) + j) * 65 + c];
            acc[j].x += x * w.x; acc[j].y += x * w.y; acc[j].z += x * w.z; acc[j].w += x * w.w;
        }
    }
    #pragma unroll
    for (int j = 0; j < 4; ++j) {
        const int n = rows[(tr << 2) + j];
        if (n >= 0) *(float4*)&Out[(size_t)l * NC + (size_t)n * 64 + (tc << 2)] = acc[j];
    }
}

// ---------------- edge GEMM pipeline: rb -> h1 -> h2 -> h3 -> w ----------------
__global__ __launch_bounds__(256) void k_wgemm(const float* __restrict__ pos,
    const float* __restrict__ shifts, const int* __restrict__ ei,
    const float* __restrict__ W1, const float* __restrict__ W2,
    const float* __restrict__ W3, const float* __restrict__ W4,
    const int* __restrict__ roff, const int* __restrict__ elist,
    int r0, float* __restrict__ wout)
{
    __shared__ float rb[64 * 9];
    __shared__ float hA[64 * 65];
    __shared__ float hB[64 * 65];
    __shared__ float Ws[4096];
    __shared__ int jb[2];
    const int t = threadIdx.x;
    if (t < 2) jb[t] = roff[r0 + t * NRCH];
    __syncthreads();
    const int j0   = jb[0] + (blockIdx.x << 6);
    const int jend = jb[1];
    if (j0 >= jend) return;
    // geometry -> rb (edges j0..j0+63)
    if (t < 64) {
        float rbv[8];
        const int j = j0 + t;
        if (j < jend) {
            const int e = elist[j];
            const int s = ei[e], rv = ei[E + e];
            const float dx = pos[rv * 3 + 0] - pos[s * 3 + 0] + shifts[e * 3 + 0];
            const float dy = pos[rv * 3 + 1] - pos[s * 3 + 1] + shifts[e * 3 + 1];
            const float dz = pos[rv * 3 + 2] - pos[s * 3 + 2] + shifts[e * 3 + 2];
            const float r = sqrtf(dx * dx + dy * dy + dz * dz);
            const float u  = r * 0.2f;
            const float u2 = u * u, u5 = u2 * u2 * u;
            const float fc = 1.f - 21.f * u5 + 35.f * u5 * u - 15.f * u5 * u2;
            float pref = 0.63245553f * fc / (r + 1e-9f);
            if (u >= 1.f) pref = 0.f;
            const float piu = 3.14159265358979f * u;
            #pragma unroll
            for (int b = 0; b < 8; ++b) rbv[b] = __sinf((float)(b + 1) * piu) * pref;
        } else {
            #pragma unroll
            for (int b = 0; b < 8; ++b) rbv[b] = 0.f;
        }
        #pragma unroll
        for (int b = 0; b < 8; ++b) rb[t * 9 + b] = rbv[b];
    }
    for (int i = t; i < 512; i += 256) Ws[i] = W1[i];
    __syncthreads();
    const int tr = t >> 4, tc = t & 15;
    // stage 1: h1 = silu(rb @ W1)   (64x8 @ 8x64)
    {
        float4 a[4];
        #pragma unroll
        for (int j = 0; j < 4; ++j) a[j] = make_float4(0.f, 0.f, 0.f, 0.f);
        #pragma unroll
        for (int k = 0; k < 8; ++k) {
            const float4 w = *(const float4*)&Ws[(k << 6) + (tc << 2)];
            #pragma unroll
            for (int j = 0; j < 4; ++j) {
                const float x = rb[((tr << 2) + j) * 9 + k];
                a[j].x += x * w.x; a[j].y += x * w.y; a[j].z += x * w.z; a[j].w += x * w.w;
            }
        }
        #pragma unroll
        for (int j = 0; j < 4; ++j) {
            float* o = &hA[((tr << 2) + j) * 65 + (tc << 2)];
            o[0] = silu(a[j].x); o[1] = silu(a[j].y); o[2] = silu(a[j].z); o[3] = silu(a[j].w);
        }
    }
    __syncthreads();
    // stage 2: h2 = silu(h1 @ W2)
    for (int i = t; i < 4096; i += 256) Ws[i] = W2[i];
    __syncthreads();
    {
        float4 a[4];
        #pragma unroll
        for (int j = 0; j < 4; ++j) a[j] = make_float4(0.f, 0.f, 0.f, 0.f);
        #pragma unroll 8
        for (int k = 0; k < 64; ++k) {
            const float4 w = *(const float4*)&Ws[(k << 6) + (tc << 2)];
            #pragma unroll
            for (int j = 0; j < 4; ++j) {
                const float x = hA[((tr << 2) + j) * 65 + k];
                a[j].x += x * w.x; a[j].y += x * w.y; a[j].z += x * w.z; a[j].w += x * w.w;
            }
        }
        #pragma unroll
        for (int j = 0; j < 4; ++j) {
            float* o = &hB[((tr << 2) + j) * 65 + (tc << 2)];
            o[0] = silu(a[j].x); o[1] = silu(a[j].y); o[2] = silu(a[j].z); o[3] = silu(a[j].w);
        }
    }
    __syncthreads();
    // stage 3: h3 = silu(h2 @ W3)
    for (int i = t; i < 4096; i += 256) Ws[i] = W3[i];
    __syncthreads();
    {
        float4 a[4];
        #pragma unroll
        for (int j = 0; j < 4; ++j) a[j] = make_float4(0.f, 0.f, 0.f, 0.f);
        #pragma unroll 8
        for (int k = 0; k < 64; ++k) {
            const float4 w = *(const float4*)&Ws[(k << 6) + (tc << 2)];
            #pragma unroll
            for (int j = 0; j < 4; ++j) {
                const float x = hB[((tr << 2) + j) * 65 + k];
                a[j].x += x * w.x; a[j].y += x * w.y; a[j].z += x * w.z; a[j].w += x * w.w;
            }
        }
        #pragma unroll
        for (int j = 0; j < 4; ++j) {
            float* o = &hA[((tr << 2) + j) * 65 + (tc << 2)];
            o[0] = silu(a[j].x); o[1] = silu(a[j].y); o[2] = silu(a[j].z); o[3] = silu(a[j].w);
        }
    }
    __syncthreads();
    // stage 4: w = h3 @ W4 (64x64 @ 64x256), 4 column chunks of 64
    const int p0 = blockIdx.x << 6;
    for (int cc = 0; cc < 4; ++cc) {
        for (int i = t; i < 4096; i += 256) Ws[i] = W4[(i >> 6) * 256 + (cc << 6) + (i & 63)];
        __syncthreads();
        float4 a[4];
        #pragma unroll
        for (int j = 0; j < 4; ++j) a[j] = make_float4(0.f, 0.f, 0.f, 0.f);
        #pragma unroll 8
        for (int k = 0; k < 64; ++k) {
            const float4 w = *(const float4*)&Ws[(k << 6) + (tc << 2)];
            #pragma unroll
            for (int j = 0; j < 4; ++j) {
                const float x = hA[((tr << 2) + j) * 65 + k];
                a[j].x += x * w.x; a[j].y += x * w.y; a[j].z += x * w.z; a[j].w += x * w.w;
            }
        }
        #pragma unroll
        for (int j = 0; j < 4; ++j) {
            const int p = p0 + (tr << 2) + j;
            *(float4*)&wout[(size_t)p * 256 + (cc << 6) + (tc << 2)] = a[j];
        }
        __syncthreads();
    }
}

// ---------------- aggregate: wave per receiver, reads precomputed w ----------------
__global__ __launch_bounds__(256) void k_agg(const float* __restrict__ pos,
    const float* __restrict__ shifts, const int* __restrict__ ei,
    const float* __restrict__ H, const float* __restrict__ wbuf,
    const int* __restrict__ roff, const int* __restrict__ elist,
    int r0, float* __restrict__ A)
{
    const int lane = threadIdx.x & 63;
    const int n = r0 + (blockIdx.x << 2) + (threadIdx.x >> 6);
    const int jbase = roff[r0];
    const int ja = roff[n], jb2 = roff[n + 1];
    float acc[16];
    #pragma unroll
    for (int l = 0; l < 16; ++l) acc[l] = 0.f;
    const float p0x = pos[n * 3], p0y = pos[n * 3 + 1], p0z = pos[n * 3 + 2];
    constexpr int LM[16] = {0,1,1,1,2,2,2,2,2,3,3,3,3,3,3,3};
    for (int j = ja; j < jb2; ++j) {
        const int e = elist[j];
        const int s = ei[e];
        const float dx = p0x - pos[s * 3 + 0] + shifts[e * 3 + 0];
        const float dy = p0y - pos[s * 3 + 1] + shifts[e * 3 + 1];
        const float dz = p0z - pos[s * 3 + 2] + shifts[e * 3 + 2];
        const float r = sqrtf(dx * dx + dy * dy + dz * dz);
        if (r >= RMAX) continue;
        const float inv = 1.f / (r + 1e-9f);
        const float x = dx * inv, y = dy * inv, z = dz * inv;
        const float xx = x * x, yy = y * y, zz = z * z;
        float Y[16];
        Y[0] = 1.f;
        Y[1] = 1.7320508f * x;  Y[2] = 1.7320508f * y;  Y[3] = 1.7320508f * z;
        Y[4] = 3.8729833f * x * y;  Y[5] = 3.8729833f * y * z;
        Y[6] = 0.5f * 2.2360680f * (3.f * zz - 1.f);
        Y[7] = 3.8729833f * x * z;  Y[8] = 0.5f * 3.8729833f * (xx - yy);
        Y[9]  = 2.0916500f * y * (3.f * xx - yy);
        Y[10] = 10.2469508f * x * y * z;
        Y[11] = 1.6201852f * y * (5.f * zz - 1.f);
        Y[12] = 0.5f * 2.6457513f * z * (5.f * zz - 3.f);
        Y[13] = 1.6201852f * x * (5.f * zz - 1.f);
        Y[14] = 0.5f * 10.2469508f * z * (xx - yy);
        Y[15] = 2.0916500f * x * (xx - 3.f * yy);
        float se = 0.f;
        const float* Hp = H + (size_t)s * 64 + lane;
        #pragma unroll
        for (int l = 0; l < 16; ++l) se += Hp[(size_t)l * NC] * Y[l];
        se *= 0.0625f;
        const float4 w4 = *(const float4*)&wbuf[(size_t)(j - jbase) * 256 + (lane << 2)];
        const float wl[4] = { w4.x * se, w4.y * se, w4.z * se, w4.w * se };
        #pragma unroll
        for (int l = 0; l < 16; ++l) acc[l] += wl[LM[l]] * Y[l];
    }
    float* Ap = A + (size_t)n * 64 + lane;
    #pragma unroll
    for (int l = 0; l < 16; ++l) Ap[(size_t)l * NC] = acc[l];
}

// ---------------- s1[n][c] = sum_l A'[l][n][c]^2 ----------------
__global__ __launch_bounds__(256) void k_s1(const float* __restrict__ H, float* __restrict__ s1)
{
    const int i = blockIdx.x * 256 + threadIdx.x;
    if (i < NC) {
        float s = 0.f;
        #pragma unroll
        for (int l = 0; l < 16; ++l) { const float a = H[(size_t)l * NC + i]; s += a * a; }
        s1[i] = s;
    }
}

// ---------------- out = sum_p (A'*s1^p)@Wp_p + sc -> F ----------------
__global__ __launch_bounds__(256) void k_out(const float* __restrict__ Ap,
    const float* __restrict__ s1, const float* __restrict__ Wp3,
    const float* __restrict__ sc, float* __restrict__ F)
{
    __shared__ float As[64 * 65];
    __shared__ float Ss[64 * 65];
    __shared__ float Ws[4096];
    const int l  = blockIdx.y;
    const int nb = blockIdx.x << 6;
    const float* Xp = Ap + (size_t)l * NC + (size_t)nb * 64;
    for (int i = threadIdx.x; i < 4096; i += 256) {
        As[(i >> 6) * 65 + (i & 63)] = Xp[i];
        Ss[(i >> 6) * 65 + (i & 63)] = s1[nb * 64 + i];
    }
    const int tc = threadIdx.x & 15;
    const int tr = threadIdx.x >> 4;
    float4 acc[4];
    #pragma unroll
    for (int j = 0; j < 4; ++j) acc[j] = make_float4(0.f, 0.f, 0.f, 0.f);
    #pragma unroll
    for (int p = 0; p < 3; ++p) {
        __syncthreads();
        for (int i = threadIdx.x; i < 4096; i += 256) Ws[i] = Wp3[p * 4096 + i];
        __syncthreads();
        #pragma unroll 4
        for (int c = 0; c < 64; ++c) {
            const float4 w = *(const float4*)&Ws[(c << 6) + (tc << 2)];
            #pragma unroll
            for (int j = 0; j < 4; ++j) {
                const int row = (tr << 2) + j;
                float a = As[row * 65 + c];
                if (p == 1) a *= Ss[row * 65 + c];
                else if (p == 2) { const float s = Ss[row * 65 + c]; a *= s * s; }
                acc[j].x += a * w.x; acc[j].y += a * w.y; acc[j].z += a * w.z; acc[j].w += a * w.w;
            }
        }
    }
    #pragma unroll
    for (int j = 0; j < 4; ++j) {
        const int row = (tr << 2) + j;
        const size_t idx = (size_t)l * NC + (size_t)(nb + row) * 64 + (tc << 2);
        const float4 sv = *(const float4*)&sc[idx];
        float4 o;
        o.x = acc[j].x + sv.x; o.y = acc[j].y + sv.y; o.z = acc[j].z + sv.z; o.w = acc[j].w + sv.w;
        *(float4*)&F[idx] = o;
    }
}

// ---------------- readout ----------------
__global__ __launch_bounds__(256) void k_read(const float* __restrict__ F,
    const float* __restrict__ q, const int* __restrict__ batch,
    const float* __restrict__ Wr0, const float* __restrict__ Wa,
    const float* __restrict__ Wb, const float* __restrict__ Wq,
    float* __restrict__ acc, int last)
{
    __shared__ float sred[G];
    if (threadIdx.x < G) sred[threadIdx.x] = 0.f;
    __syncthreads();
    const int n = blockIdx.x * 256 + threadIdx.x;
    if (n < N) {
        float a16[16];
        #pragma unroll
        for (int j = 0; j < 16; ++j) a16[j] = 0.f;
        float ar = 0.f, aq = 0.f;
        const float* f = F + (size_t)n * 64;
        for (int c = 0; c < 64; ++c) {
            const float fv = f[c];
            aq += fv * Wq[c];
            if (last) {
                #pragma unroll
                for (int j = 0; j < 16; ++j) a16[j] += fv * Wa[c * 16 + j];
            } else ar += fv * Wr0[c];
        }
        float en;
        if (last) {
            en = 0.f;
            #pragma unroll
            for (int j = 0; j < 16; ++j) en += silu(a16[j]) * Wb[j];
        } else en = ar;
        en += q[n] * aq;
        atomicAdd(&sred[batch[n]], en);
    }
    __syncthreads();
    if (threadIdx.x < G) atomicAdd(&acc[threadIdx.x * 5], sred[threadIdx.x]);
}

// ---------------- Ewald ----------------
__global__ __launch_bounds__(256) void k_kvec(const float* __restrict__ rcell,
    float* __restrict__ kvec, float* __restrict__ k2)
{
    const int idx = blockIdx.x * 256 + threadIdx.x;
    if (idx >= G * NK) return;
    const int g = idx / NK, k = idx % NK;
    const int kk = k + (k >= 171 ? 1 : 0);
    const int a = kk / 49 - 3, b = (kk / 7) % 7 - 3, c = kk % 7 - 3;
    const float* rc = rcell + g * 9;
    float s = 0.f;
    #pragma unroll
    for (int i = 0; i < 3; ++i) {
        const float kv = 6.283185307f * ((float)a * rc[0 + i] + (float)b * rc[3 + i] + (float)c * rc[6 + i]);
        kvec[idx * 3 + i] = kv;
        s += kv * kv;
    }
    k2[idx] = s;
}

__global__ __launch_bounds__(256) void k_phase(const float* __restrict__ pos,
    const float* __restrict__ q, const float* __restrict__ kvec,
    float* __restrict__ Sr, float* __restrict__ Si)
{
    __shared__ float kvs[38 * 3];
    __shared__ float srs[38], sis[38];
    const int g = blockIdx.z, kc = blockIdx.x, ncb = blockIdx.y;
    const int kbase = kc * 38;
    if (threadIdx.x < 38 * 3) kvs[threadIdx.x] = kvec[((size_t)g * NK + kbase) * 3 + threadIdx.x];
    if (threadIdx.x < 38) { srs[threadIdx.x] = 0.f; sis[threadIdx.x] = 0.f; }
    __syncthreads();
    const int t = threadIdx.x;
    float px = 0.f, py = 0.f, pz = 0.f, qn = 0.f;
    if (t < 250) {
        const int n = g * NGR + ncb * 250 + t;
        px = pos[n * 3]; py = pos[n * 3 + 1]; pz = pos[n * 3 + 2]; qn = q[n];
    }
    const int lane = t & 63;
    for (int j = 0; j < 38; ++j) {
        const float ph = px * kvs[j * 3] + py * kvs[j * 3 + 1] + pz * kvs[j * 3 + 2];
        float sv, cv;
        __sincosf(ph, &sv, &cv);
        float vr = qn * cv, vi = qn * sv;
        #pragma unroll
        for (int o = 32; o > 0; o >>= 1) { vr += __shfl_down(vr, o, 64); vi += __shfl_down(vi, o, 64); }
        if (lane == 0) { atomicAdd(&srs[j], vr); atomicAdd(&sis[j], vi); }
    }
    __syncthreads();
    if (t < 38) {
        atomicAdd(&Sr[g * NK + kbase + t], srs[t]);
        atomicAdd(&Si[g * NK + kbase + t], sis[t]);
    }
}

__global__ __launch_bounds__(512) void k_final(const float* __restrict__ k2,
    const float* __restrict__ Sr, const float* __restrict__ Si,
    const float* __restrict__ vol, const float* __restrict__ acc,
    float* __restrict__ out)
{
    __shared__ float red[512];
    const int g = blockIdx.x, t = threadIdx.x;
    float v = 0.f;
    if (t < NK) {
        const float kk = k2[g * NK + t];
        const float sr = Sr[g * NK + t], si = Si[g * NK + t];
        v = __expf(-0.5f * kk) * (sr * sr + si * si) / kk;
    }
    red[t] = v;
    __syncthreads();
    for (int s2 = 256; s2 > 0; s2 >>= 1) {
        if (t < s2) red[t] += red[t + s2];
        __syncthreads();
    }
    if (t == 0) {
        const float Ees = 6.283185307f / vol[g] * red[0];
        out[g]     = acc[g * 5 + 0] + Ees;
        out[4 + g] = acc[g * 5 + 1];
        out[8 + g * 3 + 0] = acc[g * 5 + 2];
        out[8 + g * 3 + 1] = acc[g * 5 + 3];
        out[8 + g * 3 + 2] = acc[g * 5 + 4];
    }
}

extern "C" void kernel_launch(void* const* d_in, const int* in_sizes, int n_in,
                              void* d_out, int out_size, void* d_ws, size_t ws_size,
                              hipStream_t stream)
{
    const float* na    = (const float*)d_in[0];
    const float* pos   = (const float*)d_in[1];
    const float* shif  = (const float*)d_in[2];
    const float* q     = (const float*)d_in[3];
    const float* rcell = (const float*)d_in[5];
    const float* vol   = (const float*)d_in[6];
    const int*   ei    = (const int*)d_in[7];
    const int*   batch = (const int*)d_in[8];
    const float* embW  = (const float*)d_in[9];
    const float* qcoef = (const float*)d_in[10];
    const float* rW1   = (const float*)d_in[11];
    const float* rW2   = (const float*)d_in[12];
    const float* rW3   = (const float*)d_in[13];
    const float* rW4   = (const float*)d_in[14];
    const float* lup   = (const float*)d_in[15];
    const float* lout  = (const float*)d_in[16];
    const float* Wsc   = (const float*)d_in[17];
    const float* Wp    = (const float*)d_in[18];
    const float* Wr0   = (const float*)d_in[19];
    const float* Wa    = (const float*)d_in[20];
    const float* Wb    = (const float*)d_in[21];
    const float* Wq    = (const float*)d_in[22];
    const float* aE    = (const float*)d_in[23];
    float* out = (float*)d_out;

    float* wsf  = (float*)d_ws;
    float* F    = wsf;                  // [16][N][64]
    float* H    = F    + 8192000;       // [16][N][64]
    float* Asc  = H    + 8192000;       // [16][N][64]  (A result, then sc buffer)
    float* wbuf = Asc  + 8192000;       // [32000][256] w chunk (position-indexed)
    float* s1   = wbuf + 8192000;       // [N][64]
    float* kvec = s1   + 512000;        // [G*342][3]
    float* k2   = kvec + 4104;          // [G*342]
    float* Sr   = k2   + 1368;
    float* Si   = Sr   + 1368;
    float* acc  = Si   + 1368;          // [G][5]
    int*   elem = (int*)(acc + 32);     // [N]
    int*   perm = elem + 8000;          // [8640]
    int*   counts = perm + 8640;        // [16]
    int*   cursor = counts + 16;        // [16]
    int*   offs   = cursor + 16;        // [16+...]
    int*   roff   = offs + 16;          // [N+1]
    int*   cnt    = roff + 8001;        // [N]
    int*   cur    = cnt + 8000;         // [N]
    int*   elist  = cur + 8000;         // [E]

    hipMemsetAsync(F, 0, 8192000 * sizeof(float), stream);
    hipMemsetAsync(Sr, 0, (1368 * 2 + 32) * sizeof(float), stream);
    hipMemsetAsync(perm, 0xFF, 8640 * sizeof(int), stream);
    hipMemsetAsync(counts, 0, 32 * sizeof(int), stream);
    hipMemsetAsync(cnt, 0, 16000 * sizeof(int), stream);

    k_init<<<32, 256, 0, stream>>>(na, q, pos, batch, aE, elem, acc);
    k_feat0<<<2000, 256, 0, stream>>>(elem, embW, F);
    k_hist<<<32, 256, 0, stream>>>(elem, counts);
    k_offs<<<1, 64, 0, stream>>>(counts, offs);
    k_scatter<<<32, 256, 0, stream>>>(elem, offs, cursor, perm);
    k_gcnt<<<500, 256, 0, stream>>>(ei, cnt);
    k_goff<<<1, 1024, 0, stream>>>(cnt, roff);
    k_gscat<<<500, 256, 0, stream>>>(ei, roff, cur, elist);
    k_kvec<<<6, 256, 0, stream>>>(rcell, kvec, k2);
    k_phase<<<dim3(9, 8, G), 256, 0, stream>>>(pos, q, kvec, Sr, Si);

    for (int t = 0; t < 2; ++t) {
        k_pre<<<2000, 256, 0, stream>>>(q, qcoef + t * 64, F);
        k_lgemm<<<dim3(125, 16), 256, 0, stream>>>(F, lup + t * 4 * 4096, H);
        for (int ch = 0; ch < 5; ++ch) {
            k_wgemm<<<TILES, 256, 0, stream>>>(pos, shif, ei,
                rW1 + t * 512, rW2 + t * 4096, rW3 + t * 4096, rW4 + t * 16384,
                roff, elist, ch * NRCH, wbuf);
            k_agg<<<NRCH / 4, 256, 0, stream>>>(pos, shif, ei, H, wbuf,
                roff, elist, ch * NRCH, Asc);
        }
        k_lgemm<<<dim3(125, 16), 256, 0, stream>>>(Asc, lout + t * 4 * 4096, H);
        k_s1<<<2000, 256, 0, stream>>>(H, s1);
        k_sc<<<dim3(135, 16), 256, 0, stream>>>(F, Wsc + t * NEL * 4096, perm, elem, Asc);
        k_out<<<dim3(125, 16), 256, 0, stream>>>(H, s1, Wp + t * 3 * 4096, Asc, F);
        k_read<<<32, 256, 0, stream>>>(F, q, batch, Wr0, Wa, Wb, Wq + t * 64, acc, t == 1);
    }
    k_final<<<G, 512, 0, stream>>>(k2, Sr, Si, vol, acc, out);
}

// Round 4
// 979.851 us; speedup vs baseline: 1.7215x; 1.4402x over previous
//
#include <hip/hip_runtime.h>
#include <hip/hip_bf16.h>

constexpr int N    = 8000;
constexpr int E    = 128000;
constexpr int G    = 4;
constexpr int NEL  = 10;
constexpr int NGR  = N / G;          // 2000
constexpr int NC   = N * 64;         // 512000
constexpr int NK   = 342;            // Ewald vectors
constexpr float RMAX = 5.0f;

__device__ __forceinline__ int lmap_rt(int l) { return (l >= 1) + (l >= 4) + (l >= 9); }
__device__ __forceinline__ float silu(float x) { return x / (1.f + __expf(-x)); }
__device__ __forceinline__ float bf2f(unsigned short u) { return __uint_as_float(((unsigned)u) << 16); }
__device__ __forceinline__ unsigned short f2bf(float f) {
    __hip_bfloat16 h = __float2bfloat16(f);
    return *(unsigned short*)&h;
}

// ---------------- init: elem, e0/charge/dipole ----------------
__global__ __launch_bounds__(256) void k_init(const float* __restrict__ na,
    const float* __restrict__ q, const float* __restrict__ pos,
    const int* __restrict__ batch, const float* __restrict__ aE,
    int* __restrict__ elem, float* __restrict__ acc)
{
    __shared__ float s[G * 5];
    if (threadIdx.x < G * 5) s[threadIdx.x] = 0.f;
    __syncthreads();
    const int n = blockIdx.x * 256 + threadIdx.x;
    if (n < N) {
        int el = 0; float best = na[n * NEL];
        #pragma unroll
        for (int j = 1; j < NEL; ++j) { float v = na[n * NEL + j]; if (v > best) { best = v; el = j; } }
        elem[n] = el;
        const int g = batch[n];
        const float qn = q[n];
        atomicAdd(&s[g * 5 + 0], aE[el]);
        atomicAdd(&s[g * 5 + 1], qn);
        atomicAdd(&s[g * 5 + 2], qn * pos[n * 3 + 0]);
        atomicAdd(&s[g * 5 + 3], qn * pos[n * 3 + 1]);
        atomicAdd(&s[g * 5 + 4], qn * pos[n * 3 + 2]);
    }
    __syncthreads();
    if (threadIdx.x < G * 5) atomicAdd(&acc[threadIdx.x], s[threadIdx.x]);
}

__global__ __launch_bounds__(256) void k_feat0(const int* __restrict__ elem,
    const float* __restrict__ embW, float* __restrict__ F)
{
    const int i = blockIdx.x * 256 + threadIdx.x;
    if (i < NC) F[i] = embW[elem[i >> 6] * 64 + (i & 63)];
}

__global__ __launch_bounds__(256) void k_pre(const float* __restrict__ q,
    const float* __restrict__ qc, float* __restrict__ F)
{
    const int i = blockIdx.x * 256 + threadIdx.x;
    if (i < NC) F[i] += q[i >> 6] * qc[i & 63];
}

// ---------------- element bucketing ----------------
__global__ __launch_bounds__(256) void k_hist(const int* __restrict__ elem, int* __restrict__ counts)
{
    const int n = blockIdx.x * 256 + threadIdx.x;
    if (n < N) atomicAdd(&counts[elem[n]], 1);
}
__global__ void k_offs(const int* __restrict__ counts, int* __restrict__ offs)
{
    if (threadIdx.x == 0 && blockIdx.x == 0) {
        int o = 0;
        for (int j = 0; j < NEL; ++j) { offs[j] = o; o += (counts[j] + 63) & ~63; }
        offs[NEL] = o;
    }
}
__global__ __launch_bounds__(256) void k_scatter(const int* __restrict__ elem,
    const int* __restrict__ offs, int* __restrict__ cursor, int* __restrict__ perm)
{
    const int n = blockIdx.x * 256 + threadIdx.x;
    if (n < N) {
        const int el = elem[n];
        const int p = atomicAdd(&cursor[el], 1);
        perm[offs[el] + p] = n;
    }
}

// ---------------- receiver CSR build ----------------
__global__ __launch_bounds__(256) void k_gcnt(const int* __restrict__ ei, int* __restrict__ cnt)
{
    const int e = blockIdx.x * 256 + threadIdx.x;
    if (e < E) atomicAdd(&cnt[ei[E + e]], 1);
}
__global__ __launch_bounds__(1024) void k_goff(const int* __restrict__ cnt, int* __restrict__ roff)
{
    __shared__ int part[1024];
    const int t = threadIdx.x;
    const int base = t * 8;
    int loc[8];
    int s = 0;
    #pragma unroll
    for (int i = 0; i < 8; ++i) { loc[i] = s; s += (base + i < N) ? cnt[base + i] : 0; }
    part[t] = s;
    __syncthreads();
    for (int d = 1; d < 1024; d <<= 1) {
        const int v = (t >= d) ? part[t - d] : 0;
        __syncthreads();
        part[t] += v;
        __syncthreads();
    }
    const int excl = (t == 0) ? 0 : part[t - 1];
    #pragma unroll
    for (int i = 0; i < 8; ++i) if (base + i < N) roff[base + i] = excl + loc[i];
    if (t == 0) roff[N] = E;
}
__global__ __launch_bounds__(256) void k_gscat(const int* __restrict__ ei,
    const int* __restrict__ roff, int* __restrict__ cur, int* __restrict__ elist)
{
    const int e = blockIdx.x * 256 + threadIdx.x;
    if (e < E) {
        const int rv = ei[E + e];
        const int p = atomicAdd(&cur[rv], 1);
        elist[roff[rv] + p] = e;
    }
}

// =========== GEMM inner loop macro: Xs[64][64], Ws[64][64], 4x4 per thread ===========
// per 4k: 4 b128 x-reads (broadcast across tc) + 4 b128 w-reads -> VALU-bound

// ---------------- lin_up GEMM -> bf16 node-major Hb[n][l][64] ----------------
__global__ __launch_bounds__(256) void k_lgemm_hb(const float* __restrict__ X,
    const float* __restrict__ Wb, unsigned short* __restrict__ Hb)
{
    __shared__ float Ws[4096];
    __shared__ float Xs[4096];
    const int l  = blockIdx.y;
    const int nb = blockIdx.x << 6;
    const float* W = Wb + lmap_rt(l) * 4096;
    for (int i = threadIdx.x; i < 4096; i += 256) Ws[i] = W[i];
    const float* Xp = X + (size_t)l * NC + (size_t)nb * 64;
    for (int i = threadIdx.x; i < 4096; i += 256) Xs[i] = Xp[i];
    __syncthreads();
    const int tc = threadIdx.x & 15;
    const int tr = threadIdx.x >> 4;
    float4 acc[4];
    #pragma unroll
    for (int j = 0; j < 4; ++j) acc[j] = make_float4(0.f, 0.f, 0.f, 0.f);
    #pragma unroll 2
    for (int k0 = 0; k0 < 64; k0 += 4) {
        float4 xq[4];
        #pragma unroll
        for (int j = 0; j < 4; ++j) xq[j] = *(const float4*)&Xs[(((tr << 2) + j) << 6) + k0];
        #pragma unroll
        for (int i = 0; i < 4; ++i) {
            const float4 w = *(const float4*)&Ws[((k0 + i) << 6) + (tc << 2)];
            #pragma unroll
            for (int j = 0; j < 4; ++j) {
                const float x = ((const float*)&xq[j])[i];
                acc[j].x += x * w.x; acc[j].y += x * w.y; acc[j].z += x * w.z; acc[j].w += x * w.w;
            }
        }
    }
    #pragma unroll
    for (int j = 0; j < 4; ++j) {
        const int n = nb + (tr << 2) + j;
        ushort4 o;
        o.x = f2bf(acc[j].x); o.y = f2bf(acc[j].y); o.z = f2bf(acc[j].z); o.w = f2bf(acc[j].w);
        *(ushort4*)&Hb[(size_t)n * 1024 + (l << 6) + (tc << 2)] = o;
    }
}

// ---------------- lin_out GEMM -> fp32 l-major ----------------
__global__ __launch_bounds__(256) void k_lgemm(const float* __restrict__ X,
    const float* __restrict__ Wb, float* __restrict__ Out)
{
    __shared__ float Ws[4096];
    __shared__ float Xs[4096];
    const int l  = blockIdx.y;
    const int nb = blockIdx.x << 6;
    const float* W = Wb + lmap_rt(l) * 4096;
    for (int i = threadIdx.x; i < 4096; i += 256) Ws[i] = W[i];
    const float* Xp = X + (size_t)l * NC + (size_t)nb * 64;
    for (int i = threadIdx.x; i < 4096; i += 256) Xs[i] = Xp[i];
    __syncthreads();
    const int tc = threadIdx.x & 15;
    const int tr = threadIdx.x >> 4;
    float4 acc[4];
    #pragma unroll
    for (int j = 0; j < 4; ++j) acc[j] = make_float4(0.f, 0.f, 0.f, 0.f);
    #pragma unroll 2
    for (int k0 = 0; k0 < 64; k0 += 4) {
        float4 xq[4];
        #pragma unroll
        for (int j = 0; j < 4; ++j) xq[j] = *(const float4*)&Xs[(((tr << 2) + j) << 6) + k0];
        #pragma unroll
        for (int i = 0; i < 4; ++i) {
            const float4 w = *(const float4*)&Ws[((k0 + i) << 6) + (tc << 2)];
            #pragma unroll
            for (int j = 0; j < 4; ++j) {
                const float x = ((const float*)&xq[j])[i];
                acc[j].x += x * w.x; acc[j].y += x * w.y; acc[j].z += x * w.z; acc[j].w += x * w.w;
            }
        }
    }
    float* Op = Out + (size_t)l * NC + (size_t)nb * 64;
    #pragma unroll
    for (int j = 0; j < 4; ++j)
        *(float4*)&Op[(((tr << 2) + j) << 6) + (tc << 2)] = acc[j];
}

// ---------------- sc GEMM over element buckets ----------------
__global__ __launch_bounds__(256) void k_sc(const float* __restrict__ F,
    const float* __restrict__ Wsc, const int* __restrict__ perm,
    const int* __restrict__ elem, float* __restrict__ Out)
{
    __shared__ float Ws[4096];
    __shared__ float Xs[4096];
    __shared__ int rows[64];
    const int l  = blockIdx.y;
    const int tb = blockIdx.x << 6;
    if (threadIdx.x < 64) rows[threadIdx.x] = perm[tb + threadIdx.x];
    __syncthreads();
    if (rows[0] < 0) return;
    const float* W = Wsc + elem[rows[0]] * 4096;
    for (int i = threadIdx.x; i < 4096; i += 256) Ws[i] = W[i];
    for (int i = threadIdx.x; i < 4096; i += 256) {
        const int rr = i >> 6, cc = i & 63;
        const int n = rows[rr];
        Xs[i] = (n >= 0) ? F[(size_t)l * NC + (size_t)n * 64 + cc] : 0.f;
    }
    __syncthreads();
    const int tc = threadIdx.x & 15;
    const int tr = threadIdx.x >> 4;
    float4 acc[4];
    #pragma unroll
    for (int j = 0; j < 4; ++j) acc[j] = make_float4(0.f, 0.f, 0.f, 0.f);
    #pragma unroll 2
    for (int k0 = 0; k0 < 64; k0 += 4) {
        float4 xq[4];
        #pragma unroll
        for (int j = 0; j < 4; ++j) xq[j] = *(const float4*)&Xs[(((tr << 2) + j) << 6) + k0];
        #pragma unroll
        for (int i = 0; i < 4; ++i) {
            const float4 w = *(const float4*)&Ws[((k0 + i) << 6) + (tc << 2)];
            #pragma unroll
            for (int j = 0; j < 4; ++j) {
                const float x = ((const float*)&xq[j])[i];
                acc[j].x += x * w.x; acc[j].y += x * w.y; acc[j].z += x * w.z; acc[j].w += x * w.w;
            }
        }
    }
    #pragma unroll
    for (int j = 0; j < 4; ++j) {
        const int n = rows[(tr << 2) + j];
        if (n >= 0) *(float4*)&Out[(size_t)l * NC + (size_t)n * 64 + (tc << 2)] = acc[j];
    }
}

// ---------------- edge GEMM pipeline: rb -> h1 -> h2 -> h3 -> w(bf16) ----------------
__global__ __launch_bounds__(256) void k_wgemm(const float* __restrict__ pos,
    const float* __restrict__ shifts, const int* __restrict__ ei,
    const float* __restrict__ W1, const float* __restrict__ W2,
    const float* __restrict__ W3, const float* __restrict__ W4,
    const int* __restrict__ elist, unsigned short* __restrict__ wout)
{
    __shared__ float rb[64 * 8];
    __shared__ float hA[4096];
    __shared__ float hB[4096];
    __shared__ float Ws[4096];
    const int t = threadIdx.x;
    const int j0 = blockIdx.x << 6;
    // geometry -> rb (edges j0..j0+63); E is a multiple of 64, no bounds
    if (t < 64) {
        const int e = elist[j0 + t];
        const int s = ei[e], rv = ei[E + e];
        const float dx = pos[rv * 3 + 0] - pos[s * 3 + 0] + shifts[e * 3 + 0];
        const float dy = pos[rv * 3 + 1] - pos[s * 3 + 1] + shifts[e * 3 + 1];
        const float dz = pos[rv * 3 + 2] - pos[s * 3 + 2] + shifts[e * 3 + 2];
        const float r = sqrtf(dx * dx + dy * dy + dz * dz);
        const float u  = r * 0.2f;
        const float u2 = u * u, u5 = u2 * u2 * u;
        const float fc = 1.f - 21.f * u5 + 35.f * u5 * u - 15.f * u5 * u2;
        float pref = 0.63245553f * fc / (r + 1e-9f);
        if (u >= 1.f) pref = 0.f;
        const float piu = 3.14159265358979f * u;
        #pragma unroll
        for (int b = 0; b < 8; ++b) rb[t * 8 + b] = __sinf((float)(b + 1) * piu) * pref;
    }
    for (int i = t; i < 512; i += 256) Ws[i] = W1[i];
    __syncthreads();
    const int tr = t >> 4, tc = t & 15;
    // stage 1: h1 = silu(rb @ W1)   (64x8 @ 8x64)
    {
        float4 a[4];
        #pragma unroll
        for (int j = 0; j < 4; ++j) a[j] = make_float4(0.f, 0.f, 0.f, 0.f);
        #pragma unroll
        for (int k0 = 0; k0 < 8; k0 += 4) {
            float4 xq[4];
            #pragma unroll
            for (int j = 0; j < 4; ++j) xq[j] = *(const float4*)&rb[(((tr << 2) + j) << 3) + k0];
            #pragma unroll
            for (int i = 0; i < 4; ++i) {
                const float4 w = *(const float4*)&Ws[((k0 + i) << 6) + (tc << 2)];
                #pragma unroll
                for (int j = 0; j < 4; ++j) {
                    const float x = ((const float*)&xq[j])[i];
                    a[j].x += x * w.x; a[j].y += x * w.y; a[j].z += x * w.z; a[j].w += x * w.w;
                }
            }
        }
        #pragma unroll
        for (int j = 0; j < 4; ++j) {
            float* o = &hA[(((tr << 2) + j) << 6) + (tc << 2)];
            o[0] = silu(a[j].x); o[1] = silu(a[j].y); o[2] = silu(a[j].z); o[3] = silu(a[j].w);
        }
    }
    __syncthreads();
    // stage 2: h2 = silu(h1 @ W2)
    for (int i = t; i < 4096; i += 256) Ws[i] = W2[i];
    __syncthreads();
    {
        float4 a[4];
        #pragma unroll
        for (int j = 0; j < 4; ++j) a[j] = make_float4(0.f, 0.f, 0.f, 0.f);
        #pragma unroll 2
        for (int k0 = 0; k0 < 64; k0 += 4) {
            float4 xq[4];
            #pragma unroll
            for (int j = 0; j < 4; ++j) xq[j] = *(const float4*)&hA[(((tr << 2) + j) << 6) + k0];
            #pragma unroll
            for (int i = 0; i < 4; ++i) {
                const float4 w = *(const float4*)&Ws[((k0 + i) << 6) + (tc << 2)];
                #pragma unroll
                for (int j = 0; j < 4; ++j) {
                    const float x = ((const float*)&xq[j])[i];
                    a[j].x += x * w.x; a[j].y += x * w.y; a[j].z += x * w.z; a[j].w += x * w.w;
                }
            }
        }
        #pragma unroll
        for (int j = 0; j < 4; ++j) {
            float* o = &hB[(((tr << 2) + j) << 6) + (tc << 2)];
            o[0] = silu(a[j].x); o[1] = silu(a[j].y); o[2] = silu(a[j].z); o[3] = silu(a[j].w);
        }
    }
    __syncthreads();
    // stage 3: h3 = silu(h2 @ W3)
    for (int i = t; i < 4096; i += 256) Ws[i] = W3[i];
    __syncthreads();
    {
        float4 a[4];
        #pragma unroll
        for (int j = 0; j < 4; ++j) a[j] = make_float4(0.f, 0.f, 0.f, 0.f);
        #pragma unroll 2
        for (int k0 = 0; k0 < 64; k0 += 4) {
            float4 xq[4];
            #pragma unroll
            for (int j = 0; j < 4; ++j) xq[j] = *(const float4*)&hB[(((tr << 2) + j) << 6) + k0];
            #pragma unroll
            for (int i = 0; i < 4; ++i) {
                const float4 w = *(const float4*)&Ws[((k0 + i) << 6) + (tc << 2)];
                #pragma unroll
                for (int j = 0; j < 4; ++j) {
                    const float x = ((const float*)&xq[j])[i];
                    a[j].x += x * w.x; a[j].y += x * w.y; a[j].z += x * w.z; a[j].w += x * w.w;
                }
            }
        }
        #pragma unroll
        for (int j = 0; j < 4; ++j) {
            float* o = &hA[(((tr << 2) + j) << 6) + (tc << 2)];
            o[0] = silu(a[j].x); o[1] = silu(a[j].y); o[2] = silu(a[j].z); o[3] = silu(a[j].w);
        }
    }
    __syncthreads();
    // stage 4: w = h3 @ W4 (64x64 @ 64x256), 4 column chunks of 64 -> bf16 out
    for (int cc = 0; cc < 4; ++cc) {
        for (int i = t; i < 4096; i += 256) Ws[i] = W4[(i >> 6) * 256 + (cc << 6) + (i & 63)];
        __syncthreads();
        float4 a[4];
        #pragma unroll
        for (int j = 0; j < 4; ++j) a[j] = make_float4(0.f, 0.f, 0.f, 0.f);
        #pragma unroll 2
        for (int k0 = 0; k0 < 64; k0 += 4) {
            float4 xq[4];
            #pragma unroll
            for (int j = 0; j < 4; ++j) xq[j] = *(const float4*)&hA[(((tr << 2) + j) << 6) + k0];
            #pragma unroll
            for (int i = 0; i < 4; ++i) {
                const float4 w = *(const float4*)&Ws[((k0 + i) << 6) + (tc << 2)];
                #pragma unroll
                for (int j = 0; j < 4; ++j) {
                    const float x = ((const float*)&xq[j])[i];
                    a[j].x += x * w.x; a[j].y += x * w.y; a[j].z += x * w.z; a[j].w += x * w.w;
                }
            }
        }
        #pragma unroll
        for (int j = 0; j < 4; ++j) {
            const int p = j0 + (tr << 2) + j;
            ushort4 o;
            o.x = f2bf(a[j].x); o.y = f2bf(a[j].y); o.z = f2bf(a[j].z); o.w = f2bf(a[j].w);
            *(ushort4*)&wout[(size_t)p * 256 + (cc << 6) + (tc << 2)] = o;
        }
        __syncthreads();
    }
}

// ---------------- aggregate: wave per receiver, bf16 w + bf16 Hb ----------------
__global__ __launch_bounds__(256) void k_agg(const float* __restrict__ pos,
    const float* __restrict__ shifts, const int* __restrict__ ei,
    const unsigned short* __restrict__ Hb, const unsigned short* __restrict__ wb,
    const int* __restrict__ roff, const int* __restrict__ elist,
    float* __restrict__ A)
{
    const int lane = threadIdx.x & 63;
    const int n = (blockIdx.x << 2) + (threadIdx.x >> 6);
    const int ja = roff[n], jb2 = roff[n + 1];
    float acc[16];
    #pragma unroll
    for (int l = 0; l < 16; ++l) acc[l] = 0.f;
    const float p0x = pos[n * 3], p0y = pos[n * 3 + 1], p0z = pos[n * 3 + 2];
    constexpr int LM[16] = {0,1,1,1,2,2,2,2,2,3,3,3,3,3,3,3};
    for (int j = ja; j < jb2; ++j) {
        const int e = elist[j];
        const int s = ei[e];
        const float dx = p0x - pos[s * 3 + 0] + shifts[e * 3 + 0];
        const float dy = p0y - pos[s * 3 + 1] + shifts[e * 3 + 1];
        const float dz = p0z - pos[s * 3 + 2] + shifts[e * 3 + 2];
        const float r = sqrtf(dx * dx + dy * dy + dz * dz);
        if (r >= RMAX) continue;
        const float inv = 1.f / (r + 1e-9f);
        const float x = dx * inv, y = dy * inv, z = dz * inv;
        const float xx = x * x, yy = y * y, zz = z * z;
        float Y[16];
        Y[0] = 1.f;
        Y[1] = 1.7320508f * x;  Y[2] = 1.7320508f * y;  Y[3] = 1.7320508f * z;
        Y[4] = 3.8729833f * x * y;  Y[5] = 3.8729833f * y * z;
        Y[6] = 0.5f * 2.2360680f * (3.f * zz - 1.f);
        Y[7] = 3.8729833f * x * z;  Y[8] = 0.5f * 3.8729833f * (xx - yy);
        Y[9]  = 2.0916500f * y * (3.f * xx - yy);
        Y[10] = 10.2469508f * x * y * z;
        Y[11] = 1.6201852f * y * (5.f * zz - 1.f);
        Y[12] = 0.5f * 2.6457513f * z * (5.f * zz - 3.f);
        Y[13] = 1.6201852f * x * (5.f * zz - 1.f);
        Y[14] = 0.5f * 10.2469508f * z * (xx - yy);
        Y[15] = 2.0916500f * x * (xx - 3.f * yy);
        float se = 0.f;
        const unsigned short* Hp = Hb + (size_t)s * 1024 + lane;
        #pragma unroll
        for (int l = 0; l < 16; ++l) se += bf2f(Hp[l << 6]) * Y[l];
        se *= 0.0625f;
        const ushort4 wq = *(const ushort4*)&wb[(size_t)j * 256 + (lane << 2)];
        const float wl[4] = { bf2f(wq.x) * se, bf2f(wq.y) * se, bf2f(wq.z) * se, bf2f(wq.w) * se };
        #pragma unroll
        for (int l = 0; l < 16; ++l) acc[l] += wl[LM[l]] * Y[l];
    }
    float* Ap = A + (size_t)n * 64 + lane;
    #pragma unroll
    for (int l = 0; l < 16; ++l) Ap[(size_t)l * NC] = acc[l];
}

// ---------------- s1[n][c] = sum_l H2[l][n][c]^2 ----------------
__global__ __launch_bounds__(256) void k_s1(const float* __restrict__ H, float* __restrict__ s1)
{
    const int i = blockIdx.x * 256 + threadIdx.x;
    if (i < NC) {
        float s = 0.f;
        #pragma unroll
        for (int l = 0; l < 16; ++l) { const float a = H[(size_t)l * NC + i]; s += a * a; }
        s1[i] = s;
    }
}

// ---------------- out = sum_p (A'*s1^p)@Wp_p + sc -> F ----------------
__global__ __launch_bounds__(256) void k_out(const float* __restrict__ Ap,
    const float* __restrict__ s1, const float* __restrict__ Wp3,
    const float* __restrict__ sc, float* __restrict__ F)
{
    __shared__ float Xs[4096];
    __shared__ float Ws[4096];
    const int l  = blockIdx.y;
    const int nb = blockIdx.x << 6;
    const int tc = threadIdx.x & 15;
    const int tr = threadIdx.x >> 4;
    const float* Xp = Ap + (size_t)l * NC + (size_t)nb * 64;
    float4 acc[4];
    #pragma unroll
    for (int j = 0; j < 4; ++j) acc[j] = make_float4(0.f, 0.f, 0.f, 0.f);
    for (int p = 0; p < 3; ++p) {
        for (int i = threadIdx.x; i < 4096; i += 256) {
            Ws[i] = Wp3[p * 4096 + i];
            float a = Xp[i];
            if (p) {
                const float s = s1[nb * 64 + i];
                a *= (p == 1) ? s : s * s;
            }
            Xs[i] = a;
        }
        __syncthreads();
        #pragma unroll 2
        for (int k0 = 0; k0 < 64; k0 += 4) {
            float4 xq[4];
            #pragma unroll
            for (int j = 0; j < 4; ++j) xq[j] = *(const float4*)&Xs[(((tr << 2) + j) << 6) + k0];
            #pragma unroll
            for (int i = 0; i < 4; ++i) {
                const float4 w = *(const float4*)&Ws[((k0 + i) << 6) + (tc << 2)];
                #pragma unroll
                for (int j = 0; j < 4; ++j) {
                    const float x = ((const float*)&xq[j])[i];
                    acc[j].x += x * w.x; acc[j].y += x * w.y; acc[j].z += x * w.z; acc[j].w += x * w.w;
                }
            }
        }
        __syncthreads();
    }
    #pragma unroll
    for (int j = 0; j < 4; ++j) {
        const int row = (tr << 2) + j;
        const size_t idx = (size_t)l * NC + (size_t)(nb + row) * 64 + (tc << 2);
        const float4 sv = *(const float4*)&sc[idx];
        float4 o;
        o.x = acc[j].x + sv.x; o.y = acc[j].y + sv.y; o.z = acc[j].z + sv.z; o.w = acc[j].w + sv.w;
        *(float4*)&F[idx] = o;
    }
}

// ---------------- readout ----------------
__global__ __launch_bounds__(256) void k_read(const float* __restrict__ F,
    const float* __restrict__ q, const int* __restrict__ batch,
    const float* __restrict__ Wr0, const float* __restrict__ Wa,
    const float* __restrict__ Wb, const float* __restrict__ Wq,
    float* __restrict__ acc, int last)
{
    __shared__ float sred[G];
    if (threadIdx.x < G) sred[threadIdx.x] = 0.f;
    __syncthreads();
    const int n = blockIdx.x * 256 + threadIdx.x;
    if (n < N) {
        float a16[16];
        #pragma unroll
        for (int j = 0; j < 16; ++j) a16[j] = 0.f;
        float ar = 0.f, aq = 0.f;
        const float* f = F + (size_t)n * 64;
        for (int c = 0; c < 64; ++c) {
            const float fv = f[c];
            aq += fv * Wq[c];
            if (last) {
                #pragma unroll
                for (int j = 0; j < 16; ++j) a16[j] += fv * Wa[c * 16 + j];
            } else ar += fv * Wr0[c];
        }
        float en;
        if (last) {
            en = 0.f;
            #pragma unroll
            for (int j = 0; j < 16; ++j) en += silu(a16[j]) * Wb[j];
        } else en = ar;
        en += q[n] * aq;
        atomicAdd(&sred[batch[n]], en);
    }
    __syncthreads();
    if (threadIdx.x < G) atomicAdd(&acc[threadIdx.x * 5], sred[threadIdx.x]);
}

// ---------------- Ewald ----------------
__global__ __launch_bounds__(256) void k_kvec(const float* __restrict__ rcell,
    float* __restrict__ kvec, float* __restrict__ k2)
{
    const int idx = blockIdx.x * 256 + threadIdx.x;
    if (idx >= G * NK) return;
    const int g = idx / NK, k = idx % NK;
    const int kk = k + (k >= 171 ? 1 : 0);
    const int a = kk / 49 - 3, b = (kk / 7) % 7 - 3, c = kk % 7 - 3;
    const float* rc = rcell + g * 9;
    float s = 0.f;
    #pragma unroll
    for (int i = 0; i < 3; ++i) {
        const float kv = 6.283185307f * ((float)a * rc[0 + i] + (float)b * rc[3 + i] + (float)c * rc[6 + i]);
        kvec[idx * 3 + i] = kv;
        s += kv * kv;
    }
    k2[idx] = s;
}

__global__ __launch_bounds__(256) void k_phase(const float* __restrict__ pos,
    const float* __restrict__ q, const float* __restrict__ kvec,
    float* __restrict__ Sr, float* __restrict__ Si)
{
    __shared__ float kvs[38 * 3];
    __shared__ float srs[38], sis[38];
    const int g = blockIdx.z, kc = blockIdx.x, ncb = blockIdx.y;
    const int kbase = kc * 38;
    if (threadIdx.x < 38 * 3) kvs[threadIdx.x] = kvec[((size_t)g * NK + kbase) * 3 + threadIdx.x];
    if (threadIdx.x < 38) { srs[threadIdx.x] = 0.f; sis[threadIdx.x] = 0.f; }
    __syncthreads();
    const int t = threadIdx.x;
    float px = 0.f, py = 0.f, pz = 0.f, qn = 0.f;
    if (t < 250) {
        const int n = g * NGR + ncb * 250 + t;
        px = pos[n * 3]; py = pos[n * 3 + 1]; pz = pos[n * 3 + 2]; qn = q[n];
    }
    const int lane = t & 63;
    for (int j = 0; j < 38; ++j) {
        const float ph = px * kvs[j * 3] + py * kvs[j * 3 + 1] + pz * kvs[j * 3 + 2];
        float sv, cv;
        __sincosf(ph, &sv, &cv);
        float vr = qn * cv, vi = qn * sv;
        #pragma unroll
        for (int o = 32; o > 0; o >>= 1) { vr += __shfl_down(vr, o, 64); vi += __shfl_down(vi, o, 64); }
        if (lane == 0) { atomicAdd(&srs[j], vr); atomicAdd(&sis[j], vi); }
    }
    __syncthreads();
    if (t < 38) {
        atomicAdd(&Sr[g * NK + kbase + t], srs[t]);
        atomicAdd(&Si[g * NK + kbase + t], sis[t]);
    }
}

__global__ __launch_bounds__(512) void k_final(const float* __restrict__ k2,
    const float* __restrict__ Sr, const float* __restrict__ Si,
    const float* __restrict__ vol, const float* __restrict__ acc,
    float* __restrict__ out)
{
    __shared__ float red[512];
    const int g = blockIdx.x, t = threadIdx.x;
    float v = 0.f;
    if (t < NK) {
        const float kk = k2[g * NK + t];
        const float sr = Sr[g * NK + t], si = Si[g * NK + t];
        v = __expf(-0.5f * kk) * (sr * sr + si * si) / kk;
    }
    red[t] = v;
    __syncthreads();
    for (int s2 = 256; s2 > 0; s2 >>= 1) {
        if (t < s2) red[t] += red[t + s2];
        __syncthreads();
    }
    if (t == 0) {
        const float Ees = 6.283185307f / vol[g] * red[0];
        out[g]     = acc[g * 5 + 0] + Ees;
        out[4 + g] = acc[g * 5 + 1];
        out[8 + g * 3 + 0] = acc[g * 5 + 2];
        out[8 + g * 3 + 1] = acc[g * 5 + 3];
        out[8 + g * 3 + 2] = acc[g * 5 + 4];
    }
}

extern "C" void kernel_launch(void* const* d_in, const int* in_sizes, int n_in,
                              void* d_out, int out_size, void* d_ws, size_t ws_size,
                              hipStream_t stream)
{
    const float* na    = (const float*)d_in[0];
    const float* pos   = (const float*)d_in[1];
    const float* shif  = (const float*)d_in[2];
    const float* q     = (const float*)d_in[3];
    const float* rcell = (const float*)d_in[5];
    const float* vol   = (const float*)d_in[6];
    const int*   ei    = (const int*)d_in[7];
    const int*   batch = (const int*)d_in[8];
    const float* embW  = (const float*)d_in[9];
    const float* qcoef = (const float*)d_in[10];
    const float* rW1   = (const float*)d_in[11];
    const float* rW2   = (const float*)d_in[12];
    const float* rW3   = (const float*)d_in[13];
    const float* rW4   = (const float*)d_in[14];
    const float* lup   = (const float*)d_in[15];
    const float* lout  = (const float*)d_in[16];
    const float* Wsc   = (const float*)d_in[17];
    const float* Wp    = (const float*)d_in[18];
    const float* Wr0   = (const float*)d_in[19];
    const float* Wa    = (const float*)d_in[20];
    const float* Wb    = (const float*)d_in[21];
    const float* Wq    = (const float*)d_in[22];
    const float* aE    = (const float*)d_in[23];
    float* out = (float*)d_out;

    float* wsf  = (float*)d_ws;
    float* F    = wsf;                  // [16][N][64] fp32
    float* A    = F + 8192000;          // [16][N][64] fp32 (A result; later sc)
    float* R    = A + 8192000;          // 20,480,000-float region:
    float* H2   = R;                    //   fp32 [16][N][64] (lin_out result)
    unsigned short* Hb = (unsigned short*)R;             // bf16 [N][16][64]
    unsigned short* wb = (unsigned short*)(R + 4096000); // bf16 [E][256]
    float* s1   = R + 20480000;         // [N][64]
    float* kvec = s1 + 512000;          // [G*342][3]
    float* k2   = kvec + 4104;
    float* Sr   = k2 + 1368;
    float* Si   = Sr + 1368;
    float* acc  = Si + 1368;            // [G][5]
    int*   elem = (int*)(acc + 32);     // [N]
    int*   perm = elem + 8000;          // [8640]
    int*   counts = perm + 8640;        // [16]
    int*   cursor = counts + 16;        // [16]
    int*   offs   = cursor + 16;        // [16]
    int*   roff   = offs + 16;          // [N+1]
    int*   cnt    = roff + 8001;        // [N]
    int*   cur    = cnt + 8000;         // [N]
    int*   elist  = cur + 8000;         // [E]

    hipMemsetAsync(F, 0, 8192000 * sizeof(float), stream);
    hipMemsetAsync(Sr, 0, (1368 * 2 + 32) * sizeof(float), stream);
    hipMemsetAsync(perm, 0xFF, 8640 * sizeof(int), stream);
    hipMemsetAsync(counts, 0, 32 * sizeof(int), stream);
    hipMemsetAsync(cnt, 0, 16000 * sizeof(int), stream);

    k_init<<<32, 256, 0, stream>>>(na, q, pos, batch, aE, elem, acc);
    k_feat0<<<2000, 256, 0, stream>>>(elem, embW, F);
    k_hist<<<32, 256, 0, stream>>>(elem, counts);
    k_offs<<<1, 64, 0, stream>>>(counts, offs);
    k_scatter<<<32, 256, 0, stream>>>(elem, offs, cursor, perm);
    k_gcnt<<<500, 256, 0, stream>>>(ei, cnt);
    k_goff<<<1, 1024, 0, stream>>>(cnt, roff);
    k_gscat<<<500, 256, 0, stream>>>(ei, roff, cur, elist);
    k_kvec<<<6, 256, 0, stream>>>(rcell, kvec, k2);
    k_phase<<<dim3(9, 8, G), 256, 0, stream>>>(pos, q, kvec, Sr, Si);

    for (int t = 0; t < 2; ++t) {
        k_pre<<<2000, 256, 0, stream>>>(q, qcoef + t * 64, F);
        k_lgemm_hb<<<dim3(125, 16), 256, 0, stream>>>(F, lup + t * 4 * 4096, Hb);
        k_wgemm<<<2000, 256, 0, stream>>>(pos, shif, ei,
            rW1 + t * 512, rW2 + t * 4096, rW3 + t * 4096, rW4 + t * 16384, elist, wb);
        k_agg<<<2000, 256, 0, stream>>>(pos, shif, ei, Hb, wb, roff, elist, A);
        k_lgemm<<<dim3(125, 16), 256, 0, stream>>>(A, lout + t * 4 * 4096, H2);
        k_s1<<<2000, 256, 0, stream>>>(H2, s1);
        k_sc<<<dim3(135, 16), 256, 0, stream>>>(F, Wsc + t * NEL * 4096, perm, elem, A);
        k_out<<<dim3(125, 16), 256, 0, stream>>>(H2, s1, Wp + t * 3 * 4096, A, F);
        k_read<<<32, 256, 0, stream>>>(F, q, batch, Wr0, Wa, Wb, Wq + t * 64, acc, t == 1);
    }
    k_final<<<G, 512, 0, stream>>>(k2, Sr, Si, vol, acc, out);
}

// Round 5
// 943.780 us; speedup vs baseline: 1.7872x; 1.0382x over previous
//
#include <hip/hip_runtime.h>
#include <hip/hip_bf16.h>

constexpr int N    = 8000;
constexpr int E    = 128000;
constexpr int G    = 4;
constexpr int NEL  = 10;
constexpr int NGR  = N / G;          // 2000
constexpr int NC   = N * 64;         // 512000
constexpr int NK   = 342;            // Ewald vectors
constexpr float RMAX = 5.0f;
constexpr int XS = 68;               // padded LDS row stride (floats); 68*4B % 16B == 0

__device__ __forceinline__ int lmap_rt(int l) { return (l >= 1) + (l >= 4) + (l >= 9); }
__device__ __forceinline__ float silu(float x) { return x / (1.f + __expf(-x)); }
__device__ __forceinline__ float bf2f(unsigned short u) { return __uint_as_float(((unsigned)u) << 16); }
__device__ __forceinline__ unsigned short f2bf(float f) {
    __hip_bfloat16 h = __float2bfloat16(f);
    return *(unsigned short*)&h;
}

// 64x64 @ 64x64 inner product, X stride XS (bank-conflict-free), W stride 64
__device__ __forceinline__ void gemm64(const float* X, const float* W,
                                       int tr, int tc, float4 acc[4])
{
    #pragma unroll 2
    for (int k0 = 0; k0 < 64; k0 += 4) {
        float4 xq[4];
        #pragma unroll
        for (int j = 0; j < 4; ++j) xq[j] = *(const float4*)&X[((tr << 2) + j) * XS + k0];
        #pragma unroll
        for (int i = 0; i < 4; ++i) {
            const float4 w = *(const float4*)&W[((k0 + i) << 6) + (tc << 2)];
            #pragma unroll
            for (int j = 0; j < 4; ++j) {
                const float x = ((const float*)&xq[j])[i];
                acc[j].x += x * w.x; acc[j].y += x * w.y; acc[j].z += x * w.z; acc[j].w += x * w.w;
            }
        }
    }
}

// ---------------- init: elem, e0/charge/dipole ----------------
__global__ __launch_bounds__(256) void k_init(const float* __restrict__ na,
    const float* __restrict__ q, const float* __restrict__ pos,
    const int* __restrict__ batch, const float* __restrict__ aE,
    int* __restrict__ elem, float* __restrict__ acc)
{
    __shared__ float s[G * 5];
    if (threadIdx.x < G * 5) s[threadIdx.x] = 0.f;
    __syncthreads();
    const int n = blockIdx.x * 256 + threadIdx.x;
    if (n < N) {
        int el = 0; float best = na[n * NEL];
        #pragma unroll
        for (int j = 1; j < NEL; ++j) { float v = na[n * NEL + j]; if (v > best) { best = v; el = j; } }
        elem[n] = el;
        const int g = batch[n];
        const float qn = q[n];
        atomicAdd(&s[g * 5 + 0], aE[el]);
        atomicAdd(&s[g * 5 + 1], qn);
        atomicAdd(&s[g * 5 + 2], qn * pos[n * 3 + 0]);
        atomicAdd(&s[g * 5 + 3], qn * pos[n * 3 + 1]);
        atomicAdd(&s[g * 5 + 4], qn * pos[n * 3 + 2]);
    }
    __syncthreads();
    if (threadIdx.x < G * 5) atomicAdd(&acc[threadIdx.x], s[threadIdx.x]);
}

__global__ __launch_bounds__(256) void k_feat0(const int* __restrict__ elem,
    const float* __restrict__ embW, float* __restrict__ F)
{
    const int i = blockIdx.x * 256 + threadIdx.x;
    if (i < NC) F[i] = embW[elem[i >> 6] * 64 + (i & 63)];
}

__global__ __launch_bounds__(256) void k_pre(const float* __restrict__ q,
    const float* __restrict__ qc, float* __restrict__ F)
{
    const int i = blockIdx.x * 256 + threadIdx.x;
    if (i < NC) F[i] += q[i >> 6] * qc[i & 63];
}

// ---------------- element bucketing ----------------
__global__ __launch_bounds__(256) void k_hist(const int* __restrict__ elem, int* __restrict__ counts)
{
    const int n = blockIdx.x * 256 + threadIdx.x;
    if (n < N) atomicAdd(&counts[elem[n]], 1);
}
__global__ void k_offs(const int* __restrict__ counts, int* __restrict__ offs)
{
    if (threadIdx.x == 0 && blockIdx.x == 0) {
        int o = 0;
        for (int j = 0; j < NEL; ++j) { offs[j] = o; o += (counts[j] + 63) & ~63; }
        offs[NEL] = o;
    }
}
__global__ __launch_bounds__(256) void k_scatter(const int* __restrict__ elem,
    const int* __restrict__ offs, int* __restrict__ cursor, int* __restrict__ perm)
{
    const int n = blockIdx.x * 256 + threadIdx.x;
    if (n < N) {
        const int el = elem[n];
        const int p = atomicAdd(&cursor[el], 1);
        perm[offs[el] + p] = n;
    }
}

// ---------------- receiver CSR build ----------------
__global__ __launch_bounds__(256) void k_gcnt(const int* __restrict__ ei, int* __restrict__ cnt)
{
    const int e = blockIdx.x * 256 + threadIdx.x;
    if (e < E) atomicAdd(&cnt[ei[E + e]], 1);
}
__global__ __launch_bounds__(1024) void k_goff(const int* __restrict__ cnt, int* __restrict__ roff)
{
    __shared__ int part[1024];
    const int t = threadIdx.x;
    const int base = t * 8;
    int loc[8];
    int s = 0;
    #pragma unroll
    for (int i = 0; i < 8; ++i) { loc[i] = s; s += (base + i < N) ? cnt[base + i] : 0; }
    part[t] = s;
    __syncthreads();
    for (int d = 1; d < 1024; d <<= 1) {
        const int v = (t >= d) ? part[t - d] : 0;
        __syncthreads();
        part[t] += v;
        __syncthreads();
    }
    const int excl = (t == 0) ? 0 : part[t - 1];
    #pragma unroll
    for (int i = 0; i < 8; ++i) if (base + i < N) roff[base + i] = excl + loc[i];
    if (t == 0) roff[N] = E;
}
__global__ __launch_bounds__(256) void k_gscat(const int* __restrict__ ei,
    const int* __restrict__ roff, int* __restrict__ cur, int* __restrict__ elist)
{
    const int e = blockIdx.x * 256 + threadIdx.x;
    if (e < E) {
        const int rv = ei[E + e];
        const int p = atomicAdd(&cur[rv], 1);
        elist[roff[rv] + p] = e;
    }
}

// ---------------- lin_up GEMM -> bf16 node-major Hb[n][l][64] ----------------
__global__ __launch_bounds__(256) void k_lgemm_hb(const float* __restrict__ X,
    const float* __restrict__ Wb, unsigned short* __restrict__ Hb)
{
    __shared__ float Ws[4096];
    __shared__ float Xs[64 * XS];
    const int l  = blockIdx.y;
    const int nb = blockIdx.x << 6;
    const float* W = Wb + lmap_rt(l) * 4096;
    for (int i = threadIdx.x; i < 4096; i += 256) Ws[i] = W[i];
    const float* Xp = X + (size_t)l * NC + (size_t)nb * 64;
    for (int i = threadIdx.x; i < 4096; i += 256) Xs[(i >> 6) * XS + (i & 63)] = Xp[i];
    __syncthreads();
    const int tc = threadIdx.x & 15;
    const int tr = threadIdx.x >> 4;
    float4 acc[4];
    #pragma unroll
    for (int j = 0; j < 4; ++j) acc[j] = make_float4(0.f, 0.f, 0.f, 0.f);
    gemm64(Xs, Ws, tr, tc, acc);
    #pragma unroll
    for (int j = 0; j < 4; ++j) {
        const int n = nb + (tr << 2) + j;
        ushort4 o;
        o.x = f2bf(acc[j].x); o.y = f2bf(acc[j].y); o.z = f2bf(acc[j].z); o.w = f2bf(acc[j].w);
        *(ushort4*)&Hb[(size_t)n * 1024 + (l << 6) + (tc << 2)] = o;
    }
}

// ---------------- lin_out GEMM -> fp32 l-major ----------------
__global__ __launch_bounds__(256) void k_lgemm(const float* __restrict__ X,
    const float* __restrict__ Wb, float* __restrict__ Out)
{
    __shared__ float Ws[4096];
    __shared__ float Xs[64 * XS];
    const int l  = blockIdx.y;
    const int nb = blockIdx.x << 6;
    const float* W = Wb + lmap_rt(l) * 4096;
    for (int i = threadIdx.x; i < 4096; i += 256) Ws[i] = W[i];
    const float* Xp = X + (size_t)l * NC + (size_t)nb * 64;
    for (int i = threadIdx.x; i < 4096; i += 256) Xs[(i >> 6) * XS + (i & 63)] = Xp[i];
    __syncthreads();
    const int tc = threadIdx.x & 15;
    const int tr = threadIdx.x >> 4;
    float4 acc[4];
    #pragma unroll
    for (int j = 0; j < 4; ++j) acc[j] = make_float4(0.f, 0.f, 0.f, 0.f);
    gemm64(Xs, Ws, tr, tc, acc);
    float* Op = Out + (size_t)l * NC + (size_t)nb * 64;
    #pragma unroll
    for (int j = 0; j < 4; ++j)
        *(float4*)&Op[(((tr << 2) + j) << 6) + (tc << 2)] = acc[j];
}

// ---------------- sc GEMM over element buckets ----------------
__global__ __launch_bounds__(256) void k_sc(const float* __restrict__ F,
    const float* __restrict__ Wsc, const int* __restrict__ perm,
    const int* __restrict__ elem, float* __restrict__ Out)
{
    __shared__ float Ws[4096];
    __shared__ float Xs[64 * XS];
    __shared__ int rows[64];
    const int l  = blockIdx.y;
    const int tb = blockIdx.x << 6;
    if (threadIdx.x < 64) rows[threadIdx.x] = perm[tb + threadIdx.x];
    __syncthreads();
    if (rows[0] < 0) return;
    const float* W = Wsc + elem[rows[0]] * 4096;
    for (int i = threadIdx.x; i < 4096; i += 256) Ws[i] = W[i];
    for (int i = threadIdx.x; i < 4096; i += 256) {
        const int rr = i >> 6, cc = i & 63;
        const int n = rows[rr];
        Xs[rr * XS + cc] = (n >= 0) ? F[(size_t)l * NC + (size_t)n * 64 + cc] : 0.f;
    }
    __syncthreads();
    const int tc = threadIdx.x & 15;
    const int tr = threadIdx.x >> 4;
    float4 acc[4];
    #pragma unroll
    for (int j = 0; j < 4; ++j) acc[j] = make_float4(0.f, 0.f, 0.f, 0.f);
    gemm64(Xs, Ws, tr, tc, acc);
    #pragma unroll
    for (int j = 0; j < 4; ++j) {
        const int n = rows[(tr << 2) + j];
        if (n >= 0) *(float4*)&Out[(size_t)l * NC + (size_t)n * 64 + (tc << 2)] = acc[j];
    }
}

// ---------------- edge GEMM pipeline: rb -> h1 -> h2 -> h3 -> w(bf16) ----------------
// weights prefetched into registers one stage ahead (global latency off critical path)
__global__ __launch_bounds__(256) void k_wgemm(const float* __restrict__ pos,
    const float* __restrict__ shifts, const int* __restrict__ ei,
    const float* __restrict__ W1, const float* __restrict__ W2,
    const float* __restrict__ W3, const float* __restrict__ W4,
    const int* __restrict__ elist, unsigned short* __restrict__ wout)
{
    __shared__ float hA[64 * XS];
    __shared__ float hB[64 * XS];   // first 1024 floats double as rb(512)+W1s(512)
    __shared__ float Ws[4096];
    float* rb  = hB;        // [64][8]
    float* W1s = hB + 512;
    const int t = threadIdx.x;
    const int j0 = blockIdx.x << 6;
    const int tr = t >> 4, tc = t & 15;
    // geometry -> rb (edges j0..j0+63); E is a multiple of 64
    if (t < 64) {
        const int e = elist[j0 + t];
        const int s = ei[e], rv = ei[E + e];
        const float dx = pos[rv * 3 + 0] - pos[s * 3 + 0] + shifts[e * 3 + 0];
        const float dy = pos[rv * 3 + 1] - pos[s * 3 + 1] + shifts[e * 3 + 1];
        const float dz = pos[rv * 3 + 2] - pos[s * 3 + 2] + shifts[e * 3 + 2];
        const float r = sqrtf(dx * dx + dy * dy + dz * dz);
        const float u  = r * 0.2f;
        const float u2 = u * u, u5 = u2 * u2 * u;
        const float fc = 1.f - 21.f * u5 + 35.f * u5 * u - 15.f * u5 * u2;
        float pref = 0.63245553f * fc / (r + 1e-9f);
        if (u >= 1.f) pref = 0.f;
        const float piu = 3.14159265358979f * u;
        #pragma unroll
        for (int b = 0; b < 8; ++b) rb[t * 8 + b] = __sinf((float)(b + 1) * piu) * pref;
    }
    for (int i = t; i < 512; i += 256) W1s[i] = W1[i];
    // prefetch W2 into registers
    float wreg[16];
    #pragma unroll
    for (int c = 0; c < 4; ++c) *(float4*)&wreg[c * 4] = *(const float4*)&W2[(c << 10) + (t << 2)];
    __syncthreads();
    // stage 1: h1 = silu(rb @ W1)   (64x8 @ 8x64); also commit W2 to Ws, prefetch W3
    {
        float4 a[4];
        #pragma unroll
        for (int j = 0; j < 4; ++j) a[j] = make_float4(0.f, 0.f, 0.f, 0.f);
        #pragma unroll
        for (int k0 = 0; k0 < 8; k0 += 4) {
            float4 xq[4];
            #pragma unroll
            for (int j = 0; j < 4; ++j) xq[j] = *(const float4*)&rb[(((tr << 2) + j) << 3) + k0];
            #pragma unroll
            for (int i = 0; i < 4; ++i) {
                const float4 w = *(const float4*)&W1s[((k0 + i) << 6) + (tc << 2)];
                #pragma unroll
                for (int j = 0; j < 4; ++j) {
                    const float x = ((const float*)&xq[j])[i];
                    a[j].x += x * w.x; a[j].y += x * w.y; a[j].z += x * w.z; a[j].w += x * w.w;
                }
            }
        }
        #pragma unroll
        for (int c = 0; c < 4; ++c) *(float4*)&Ws[(c << 10) + (t << 2)] = *(const float4*)&wreg[c * 4];
        #pragma unroll
        for (int c = 0; c < 4; ++c) *(float4*)&wreg[c * 4] = *(const float4*)&W3[(c << 10) + (t << 2)];
        #pragma unroll
        for (int j = 0; j < 4; ++j) {
            float* o = &hA[((tr << 2) + j) * XS + (tc << 2)];
            o[0] = silu(a[j].x); o[1] = silu(a[j].y); o[2] = silu(a[j].z); o[3] = silu(a[j].w);
        }
    }
    __syncthreads();
    // stage 2: h2 = silu(h1 @ W2) -> hB
    {
        float4 a[4];
        #pragma unroll
        for (int j = 0; j < 4; ++j) a[j] = make_float4(0.f, 0.f, 0.f, 0.f);
        gemm64(hA, Ws, tr, tc, a);
        #pragma unroll
        for (int j = 0; j < 4; ++j) {
            float* o = &hB[((tr << 2) + j) * XS + (tc << 2)];
            o[0] = silu(a[j].x); o[1] = silu(a[j].y); o[2] = silu(a[j].z); o[3] = silu(a[j].w);
        }
    }
    __syncthreads();
    // commit W3, prefetch W4 col-chunk 0
    #pragma unroll
    for (int c = 0; c < 4; ++c) *(float4*)&Ws[(c << 10) + (t << 2)] = *(const float4*)&wreg[c * 4];
    {
        const int i = t << 2;
        #pragma unroll
        for (int c = 0; c < 4; ++c) {
            const int ii = (c << 10) + i;
            *(float4*)&wreg[c * 4] = *(const float4*)&W4[(ii >> 6) * 256 + (ii & 63)];
        }
    }
    __syncthreads();
    // stage 3: h3 = silu(h2 @ W3) -> hA
    {
        float4 a[4];
        #pragma unroll
        for (int j = 0; j < 4; ++j) a[j] = make_float4(0.f, 0.f, 0.f, 0.f);
        gemm64(hB, Ws, tr, tc, a);
        #pragma unroll
        for (int j = 0; j < 4; ++j) {
            float* o = &hA[((tr << 2) + j) * XS + (tc << 2)];
            o[0] = silu(a[j].x); o[1] = silu(a[j].y); o[2] = silu(a[j].z); o[3] = silu(a[j].w);
        }
    }
    // stage 4: w = h3 @ W4 (64x64 @ 64x256), 4 column chunks, pipelined
    for (int cc = 0; cc < 4; ++cc) {
        __syncthreads();
        #pragma unroll
        for (int c = 0; c < 4; ++c) *(float4*)&Ws[(c << 10) + (t << 2)] = *(const float4*)&wreg[c * 4];
        if (cc < 3) {
            const int i = t << 2;
            #pragma unroll
            for (int c = 0; c < 4; ++c) {
                const int ii = (c << 10) + i;
                *(float4*)&wreg[c * 4] = *(const float4*)&W4[(ii >> 6) * 256 + ((cc + 1) << 6) + (ii & 63)];
            }
        }
        __syncthreads();
        float4 a[4];
        #pragma unroll
        for (int j = 0; j < 4; ++j) a[j] = make_float4(0.f, 0.f, 0.f, 0.f);
        gemm64(hA, Ws, tr, tc, a);
        #pragma unroll
        for (int j = 0; j < 4; ++j) {
            const int p = j0 + (tr << 2) + j;
            ushort4 o;
            o.x = f2bf(a[j].x); o.y = f2bf(a[j].y); o.z = f2bf(a[j].z); o.w = f2bf(a[j].w);
            *(ushort4*)&wout[(size_t)p * 256 + (cc << 6) + (tc << 2)] = o;
        }
    }
}

// ---------------- aggregate: wave per receiver, bf16 w + bf16 Hb ----------------
__global__ __launch_bounds__(256) void k_agg(const float* __restrict__ pos,
    const float* __restrict__ shifts, const int* __restrict__ ei,
    const unsigned short* __restrict__ Hb, const unsigned short* __restrict__ wb,
    const int* __restrict__ roff, const int* __restrict__ elist,
    float* __restrict__ A)
{
    const int lane = threadIdx.x & 63;
    const int n = (blockIdx.x << 2) + (threadIdx.x >> 6);
    const int ja = roff[n], jb2 = roff[n + 1];
    float acc[16];
    #pragma unroll
    for (int l = 0; l < 16; ++l) acc[l] = 0.f;
    const float p0x = pos[n * 3], p0y = pos[n * 3 + 1], p0z = pos[n * 3 + 2];
    constexpr int LM[16] = {0,1,1,1,2,2,2,2,2,3,3,3,3,3,3,3};
    for (int j = ja; j < jb2; ++j) {
        const int e = elist[j];
        const int s = ei[e];
        const float dx = p0x - pos[s * 3 + 0] + shifts[e * 3 + 0];
        const float dy = p0y - pos[s * 3 + 1] + shifts[e * 3 + 1];
        const float dz = p0z - pos[s * 3 + 2] + shifts[e * 3 + 2];
        const float r = sqrtf(dx * dx + dy * dy + dz * dz);
        if (r >= RMAX) continue;
        const float inv = 1.f / (r + 1e-9f);
        const float x = dx * inv, y = dy * inv, z = dz * inv;
        const float xx = x * x, yy = y * y, zz = z * z;
        float Y[16];
        Y[0] = 1.f;
        Y[1] = 1.7320508f * x;  Y[2] = 1.7320508f * y;  Y[3] = 1.7320508f * z;
        Y[4] = 3.8729833f * x * y;  Y[5] = 3.8729833f * y * z;
        Y[6] = 0.5f * 2.2360680f * (3.f * zz - 1.f);
        Y[7] = 3.8729833f * x * z;  Y[8] = 0.5f * 3.8729833f * (xx - yy);
        Y[9]  = 2.0916500f * y * (3.f * xx - yy);
        Y[10] = 10.2469508f * x * y * z;
        Y[11] = 1.6201852f * y * (5.f * zz - 1.f);
        Y[12] = 0.5f * 2.6457513f * z * (5.f * zz - 3.f);
        Y[13] = 1.6201852f * x * (5.f * zz - 1.f);
        Y[14] = 0.5f * 10.2469508f * z * (xx - yy);
        Y[15] = 2.0916500f * x * (xx - 3.f * yy);
        float se = 0.f;
        const unsigned short* Hp = Hb + (size_t)s * 1024 + lane;
        #pragma unroll
        for (int l = 0; l < 16; ++l) se += bf2f(Hp[l << 6]) * Y[l];
        se *= 0.0625f;
        const ushort4 wq = *(const ushort4*)&wb[(size_t)j * 256 + (lane << 2)];
        const float wl[4] = { bf2f(wq.x) * se, bf2f(wq.y) * se, bf2f(wq.z) * se, bf2f(wq.w) * se };
        #pragma unroll
        for (int l = 0; l < 16; ++l) acc[l] += wl[LM[l]] * Y[l];
    }
    float* Ap = A + (size_t)n * 64 + lane;
    #pragma unroll
    for (int l = 0; l < 16; ++l) Ap[(size_t)l * NC] = acc[l];
}

// ---------------- s1[n][c] = sum_l H2[l][n][c]^2 ----------------
__global__ __launch_bounds__(256) void k_s1(const float* __restrict__ H, float* __restrict__ s1)
{
    const int i = blockIdx.x * 256 + threadIdx.x;
    if (i < NC) {
        float s = 0.f;
        #pragma unroll
        for (int l = 0; l < 16; ++l) { const float a = H[(size_t)l * NC + i]; s += a * a; }
        s1[i] = s;
    }
}

// ---------------- out = sum_p (A'*s1^p)@Wp_p + sc -> F ----------------
// A-tile and s1-tile live in registers across the 3 passes; Wp prefetched one pass ahead
__global__ __launch_bounds__(256) void k_out(const float* __restrict__ Ap,
    const float* __restrict__ s1, const float* __restrict__ Wp3,
    const float* __restrict__ sc, float* __restrict__ F)
{
    __shared__ float Xs[64 * XS];
    __shared__ float Ws[4096];
    const int l  = blockIdx.y;
    const int nb = blockIdx.x << 6;
    const int t  = threadIdx.x;
    const int tc = t & 15;
    const int tr = t >> 4;
    const float* Xp = Ap + (size_t)l * NC + (size_t)nb * 64;
    float av[16], sv[16];
    #pragma unroll
    for (int k = 0; k < 16; ++k) {
        const int i = t + (k << 8);
        av[k] = Xp[i];
        sv[k] = s1[nb * 64 + i];
    }
    float wreg[16];
    #pragma unroll
    for (int c = 0; c < 4; ++c) *(float4*)&wreg[c * 4] = *(const float4*)&Wp3[(c << 10) + (t << 2)];
    float4 acc[4];
    #pragma unroll
    for (int j = 0; j < 4; ++j) acc[j] = make_float4(0.f, 0.f, 0.f, 0.f);
    for (int p = 0; p < 3; ++p) {
        #pragma unroll
        for (int k = 0; k < 16; ++k) {
            const int i = t + (k << 8);
            Xs[(i >> 6) * XS + (i & 63)] = av[k];
            av[k] *= sv[k];
        }
        #pragma unroll
        for (int c = 0; c < 4; ++c) *(float4*)&Ws[(c << 10) + (t << 2)] = *(const float4*)&wreg[c * 4];
        if (p < 2) {
            #pragma unroll
            for (int c = 0; c < 4; ++c)
                *(float4*)&wreg[c * 4] = *(const float4*)&Wp3[(p + 1) * 4096 + (c << 10) + (t << 2)];
        }
        __syncthreads();
        gemm64(Xs, Ws, tr, tc, acc);
        __syncthreads();
    }
    #pragma unroll
    for (int j = 0; j < 4; ++j) {
        const int row = (tr << 2) + j;
        const size_t idx = (size_t)l * NC + (size_t)(nb + row) * 64 + (tc << 2);
        const float4 sv2 = *(const float4*)&sc[idx];
        float4 o;
        o.x = acc[j].x + sv2.x; o.y = acc[j].y + sv2.y; o.z = acc[j].z + sv2.z; o.w = acc[j].w + sv2.w;
        *(float4*)&F[idx] = o;
    }
}

// ---------------- readout ----------------
__global__ __launch_bounds__(256) void k_read(const float* __restrict__ F,
    const float* __restrict__ q, const int* __restrict__ batch,
    const float* __restrict__ Wr0, const float* __restrict__ Wa,
    const float* __restrict__ Wb, const float* __restrict__ Wq,
    float* __restrict__ acc, int last)
{
    __shared__ float sred[G];
    if (threadIdx.x < G) sred[threadIdx.x] = 0.f;
    __syncthreads();
    const int n = blockIdx.x * 256 + threadIdx.x;
    if (n < N) {
        float a16[16];
        #pragma unroll
        for (int j = 0; j < 16; ++j) a16[j] = 0.f;
        float ar = 0.f, aq = 0.f;
        const float* f = F + (size_t)n * 64;
        for (int c = 0; c < 64; ++c) {
            const float fv = f[c];
            aq += fv * Wq[c];
            if (last) {
                #pragma unroll
                for (int j = 0; j < 16; ++j) a16[j] += fv * Wa[c * 16 + j];
            } else ar += fv * Wr0[c];
        }
        float en;
        if (last) {
            en = 0.f;
            #pragma unroll
            for (int j = 0; j < 16; ++j) en += silu(a16[j]) * Wb[j];
        } else en = ar;
        en += q[n] * aq;
        atomicAdd(&sred[batch[n]], en);
    }
    __syncthreads();
    if (threadIdx.x < G) atomicAdd(&acc[threadIdx.x * 5], sred[threadIdx.x]);
}

// ---------------- Ewald ----------------
__global__ __launch_bounds__(256) void k_kvec(const float* __restrict__ rcell,
    float* __restrict__ kvec, float* __restrict__ k2)
{
    const int idx = blockIdx.x * 256 + threadIdx.x;
    if (idx >= G * NK) return;
    const int g = idx / NK, k = idx % NK;
    const int kk = k + (k >= 171 ? 1 : 0);
    const int a = kk / 49 - 3, b = (kk / 7) % 7 - 3, c = kk % 7 - 3;
    const float* rc = rcell + g * 9;
    float s = 0.f;
    #pragma unroll
    for (int i = 0; i < 3; ++i) {
        const float kv = 6.283185307f * ((float)a * rc[0 + i] + (float)b * rc[3 + i] + (float)c * rc[6 + i]);
        kvec[idx * 3 + i] = kv;
        s += kv * kv;
    }
    k2[idx] = s;
}

__global__ __launch_bounds__(256) void k_phase(const float* __restrict__ pos,
    const float* __restrict__ q, const float* __restrict__ kvec,
    float* __restrict__ Sr, float* __restrict__ Si)
{
    __shared__ float kvs[38 * 3];
    __shared__ float srs[38], sis[38];
    const int g = blockIdx.z, kc = blockIdx.x, ncb = blockIdx.y;
    const int kbase = kc * 38;
    if (threadIdx.x < 38 * 3) kvs[threadIdx.x] = kvec[((size_t)g * NK + kbase) * 3 + threadIdx.x];
    if (threadIdx.x < 38) { srs[threadIdx.x] = 0.f; sis[threadIdx.x] = 0.f; }
    __syncthreads();
    const int t = threadIdx.x;
    float px = 0.f, py = 0.f, pz = 0.f, qn = 0.f;
    if (t < 250) {
        const int n = g * NGR + ncb * 250 + t;
        px = pos[n * 3]; py = pos[n * 3 + 1]; pz = pos[n * 3 + 2]; qn = q[n];
    }
    const int lane = t & 63;
    for (int j = 0; j < 38; ++j) {
        const float ph = px * kvs[j * 3] + py * kvs[j * 3 + 1] + pz * kvs[j * 3 + 2];
        float sv, cv;
        __sincosf(ph, &sv, &cv);
        float vr = qn * cv, vi = qn * sv;
        #pragma unroll
        for (int o = 32; o > 0; o >>= 1) { vr += __shfl_down(vr, o, 64); vi += __shfl_down(vi, o, 64); }
        if (lane == 0) { atomicAdd(&srs[j], vr); atomicAdd(&sis[j], vi); }
    }
    __syncthreads();
    if (t < 38) {
        atomicAdd(&Sr[g * NK + kbase + t], srs[t]);
        atomicAdd(&Si[g * NK + kbase + t], sis[t]);
    }
}

__global__ __launch_bounds__(512) void k_final(const float* __restrict__ k2,
    const float* __restrict__ Sr, const float* __restrict__ Si,
    const float* __restrict__ vol, const float* __restrict__ acc,
    float* __restrict__ out)
{
    __shared__ float red[512];
    const int g = blockIdx.x, t = threadIdx.x;
    float v = 0.f;
    if (t < NK) {
        const float kk = k2[g * NK + t];
        const float sr = Sr[g * NK + t], si = Si[g * NK + t];
        v = __expf(-0.5f * kk) * (sr * sr + si * si) / kk;
    }
    red[t] = v;
    __syncthreads();
    for (int s2 = 256; s2 > 0; s2 >>= 1) {
        if (t < s2) red[t] += red[t + s2];
        __syncthreads();
    }
    if (t == 0) {
        const float Ees = 6.283185307f / vol[g] * red[0];
        out[g]     = acc[g * 5 + 0] + Ees;
        out[4 + g] = acc[g * 5 + 1];
        out[8 + g * 3 + 0] = acc[g * 5 + 2];
        out[8 + g * 3 + 1] = acc[g * 5 + 3];
        out[8 + g * 3 + 2] = acc[g * 5 + 4];
    }
}

extern "C" void kernel_launch(void* const* d_in, const int* in_sizes, int n_in,
                              void* d_out, int out_size, void* d_ws, size_t ws_size,
                              hipStream_t stream)
{
    const float* na    = (const float*)d_in[0];
    const float* pos   = (const float*)d_in[1];
    const float* shif  = (const float*)d_in[2];
    const float* q     = (const float*)d_in[3];
    const float* rcell = (const float*)d_in[5];
    const float* vol   = (const float*)d_in[6];
    const int*   ei    = (const int*)d_in[7];
    const int*   batch = (const int*)d_in[8];
    const float* embW  = (const float*)d_in[9];
    const float* qcoef = (const float*)d_in[10];
    const float* rW1   = (const float*)d_in[11];
    const float* rW2   = (const float*)d_in[12];
    const float* rW3   = (const float*)d_in[13];
    const float* rW4   = (const float*)d_in[14];
    const float* lup   = (const float*)d_in[15];
    const float* lout  = (const float*)d_in[16];
    const float* Wsc   = (const float*)d_in[17];
    const float* Wp    = (const float*)d_in[18];
    const float* Wr0   = (const float*)d_in[19];
    const float* Wa    = (const float*)d_in[20];
    const float* Wb    = (const float*)d_in[21];
    const float* Wq    = (const float*)d_in[22];
    const float* aE    = (const float*)d_in[23];
    float* out = (float*)d_out;

    float* wsf  = (float*)d_ws;
    float* F    = wsf;                  // [16][N][64] fp32
    float* A    = F + 8192000;          // [16][N][64] fp32 (A result; later sc)
    float* R    = A + 8192000;          // 20,480,000-float region:
    float* H2   = R;                    //   fp32 [16][N][64] (lin_out result)
    unsigned short* Hb = (unsigned short*)R;             // bf16 [N][16][64]
    unsigned short* wb = (unsigned short*)(R + 4096000); // bf16 [E][256]
    float* s1   = R + 20480000;         // [N][64]
    float* kvec = s1 + 512000;          // [G*342][3]
    float* k2   = kvec + 4104;
    float* Sr   = k2 + 1368;
    float* Si   = Sr + 1368;
    float* acc  = Si + 1368;            // [G][5]
    int*   elem = (int*)(acc + 32);     // [N]
    int*   perm = elem + 8000;          // [8640]
    int*   counts = perm + 8640;        // [16]
    int*   cursor = counts + 16;        // [16]
    int*   offs   = cursor + 16;        // [16]
    int*   roff   = offs + 16;          // [N+1]
    int*   cnt    = roff + 8001;        // [N]
    int*   cur    = cnt + 8000;         // [N]
    int*   elist  = cur + 8000;         // [E]

    hipMemsetAsync(F, 0, 8192000 * sizeof(float), stream);
    hipMemsetAsync(Sr, 0, (1368 * 2 + 32) * sizeof(float), stream);
    hipMemsetAsync(perm, 0xFF, 8640 * sizeof(int), stream);
    hipMemsetAsync(counts, 0, 32 * sizeof(int), stream);
    hipMemsetAsync(cnt, 0, 16000 * sizeof(int), stream);

    k_init<<<32, 256, 0, stream>>>(na, q, pos, batch, aE, elem, acc);
    k_feat0<<<2000, 256, 0, stream>>>(elem, embW, F);
    k_hist<<<32, 256, 0, stream>>>(elem, counts);
    k_offs<<<1, 64, 0, stream>>>(counts, offs);
    k_scatter<<<32, 256, 0, stream>>>(elem, offs, cursor, perm);
    k_gcnt<<<500, 256, 0, stream>>>(ei, cnt);
    k_goff<<<1, 1024, 0, stream>>>(cnt, roff);
    k_gscat<<<500, 256, 0, stream>>>(ei, roff, cur, elist);
    k_kvec<<<6, 256, 0, stream>>>(rcell, kvec, k2);
    k_phase<<<dim3(9, 8, G), 256, 0, stream>>>(pos, q, kvec, Sr, Si);

    for (int t = 0; t < 2; ++t) {
        k_pre<<<2000, 256, 0, stream>>>(q, qcoef + t * 64, F);
        k_lgemm_hb<<<dim3(125, 16), 256, 0, stream>>>(F, lup + t * 4 * 4096, Hb);
        k_wgemm<<<2000, 256, 0, stream>>>(pos, shif, ei,
            rW1 + t * 512, rW2 + t * 4096, rW3 + t * 4096, rW4 + t * 16384, elist, wb);
        k_agg<<<2000, 256, 0, stream>>>(pos, shif, ei, Hb, wb, roff, elist, A);
        k_lgemm<<<dim3(125, 16), 256, 0, stream>>>(A, lout + t * 4 * 4096, H2);
        k_s1<<<2000, 256, 0, stream>>>(H2, s1);
        k_sc<<<dim3(135, 16), 256, 0, stream>>>(F, Wsc + t * NEL * 4096, perm, elem, A);
        k_out<<<dim3(125, 16), 256, 0, stream>>>(H2, s1, Wp + t * 3 * 4096, A, F);
        k_read<<<32, 256, 0, stream>>>(F, q, batch, Wr0, Wa, Wb, Wq + t * 64, acc, t == 1);
    }
    k_final<<<G, 512, 0, stream>>>(k2, Sr, Si, vol, acc, out);
}

// Round 6
// 767.170 us; speedup vs baseline: 2.1987x; 1.2302x over previous
//
#include <hip/hip_runtime.h>
#include <hip/hip_bf16.h>

constexpr int N    = 8000;
constexpr int E    = 128000;
constexpr int G    = 4;
constexpr int NEL  = 10;
constexpr int NGR  = N / G;          // 2000
constexpr int NC   = N * 64;         // 512000
constexpr int NK   = 342;            // Ewald vectors
constexpr float RMAX = 5.0f;
constexpr int XS = 68;               // padded LDS row stride (floats) for fp32 GEMMs
constexpr int HS = 72;               // padded LDS row stride (bf16) for MFMA tiles; 72*2B=144B, 16B-aligned
constexpr int WT_T = 25088;          // per-t size of transposed weight block (ushorts)

typedef __bf16 bf16x8 __attribute__((ext_vector_type(8)));
typedef float  f32x4v __attribute__((ext_vector_type(4)));
typedef unsigned short u16x8 __attribute__((ext_vector_type(8)));

__device__ __forceinline__ int lmap_rt(int l) { return (l >= 1) + (l >= 4) + (l >= 9); }
__device__ __forceinline__ float silu(float x) { return x / (1.f + __expf(-x)); }
__device__ __forceinline__ float bf2f(unsigned short u) { return __uint_as_float(((unsigned)u) << 16); }
__device__ __forceinline__ unsigned short f2bf(float f) {
    __hip_bfloat16 h = __float2bfloat16(f);
    return *(unsigned short*)&h;
}

// 64x64 @ 64x64 fp32 inner product, X stride XS (bank-conflict-free), W stride 64
__device__ __forceinline__ void gemm64(const float* X, const float* W,
                                       int tr, int tc, float4 acc[4])
{
    #pragma unroll 2
    for (int k0 = 0; k0 < 64; k0 += 4) {
        float4 xq[4];
        #pragma unroll
        for (int j = 0; j < 4; ++j) xq[j] = *(const float4*)&X[((tr << 2) + j) * XS + k0];
        #pragma unroll
        for (int i = 0; i < 4; ++i) {
            const float4 w = *(const float4*)&W[((k0 + i) << 6) + (tc << 2)];
            #pragma unroll
            for (int j = 0; j < 4; ++j) {
                const float x = ((const float*)&xq[j])[i];
                acc[j].x += x * w.x; acc[j].y += x * w.y; acc[j].z += x * w.z; acc[j].w += x * w.w;
            }
        }
    }
}

// MFMA 64x64(xN) stage: hsrc rows = M (stride HS), wt rows = N (stride HS), K=64 (or 8)
__device__ __forceinline__ void mfma_stage(const unsigned short* hsrc, const unsigned short* wt,
                                           int m0, int lane, f32x4v acc[4], bool k8only)
{
    const int quad = lane >> 4;
    const int idx  = lane & 15;
    bf16x8 bz;
    #pragma unroll
    for (int i = 0; i < 8; ++i) bz[i] = (__bf16)0.f;
    bf16x8 a0 = bz, a1 = bz;
    const int mrow = m0 + idx;
    if (k8only) {
        if (quad == 0) a0 = *(const bf16x8*)&hsrc[mrow * HS];
    } else {
        a0 = *(const bf16x8*)&hsrc[mrow * HS + (quad << 3)];
        a1 = *(const bf16x8*)&hsrc[mrow * HS + 32 + (quad << 3)];
    }
    #pragma unroll
    for (int c4 = 0; c4 < 4; ++c4) {
        const int nrow = (c4 << 4) + idx;
        if (k8only) {
            bf16x8 b0 = bz;
            if (quad == 0) b0 = *(const bf16x8*)&wt[nrow * HS];
            acc[c4] = __builtin_amdgcn_mfma_f32_16x16x32_bf16(a0, b0, acc[c4], 0, 0, 0);
        } else {
            const bf16x8 b0 = *(const bf16x8*)&wt[nrow * HS + (quad << 3)];
            const bf16x8 b1 = *(const bf16x8*)&wt[nrow * HS + 32 + (quad << 3)];
            acc[c4] = __builtin_amdgcn_mfma_f32_16x16x32_bf16(a0, b0, acc[c4], 0, 0, 0);
            acc[c4] = __builtin_amdgcn_mfma_f32_16x16x32_bf16(a1, b1, acc[c4], 0, 0, 0);
        }
    }
}

// ---------------- init: elem, e0/charge/dipole ----------------
__global__ __launch_bounds__(256) void k_init(const float* __restrict__ na,
    const float* __restrict__ q, const float* __restrict__ pos,
    const int* __restrict__ batch, const float* __restrict__ aE,
    int* __restrict__ elem, float* __restrict__ acc)
{
    __shared__ float s[G * 5];
    if (threadIdx.x < G * 5) s[threadIdx.x] = 0.f;
    __syncthreads();
    const int n = blockIdx.x * 256 + threadIdx.x;
    if (n < N) {
        int el = 0; float best = na[n * NEL];
        #pragma unroll
        for (int j = 1; j < NEL; ++j) { float v = na[n * NEL + j]; if (v > best) { best = v; el = j; } }
        elem[n] = el;
        const int g = batch[n];
        const float qn = q[n];
        atomicAdd(&s[g * 5 + 0], aE[el]);
        atomicAdd(&s[g * 5 + 1], qn);
        atomicAdd(&s[g * 5 + 2], qn * pos[n * 3 + 0]);
        atomicAdd(&s[g * 5 + 3], qn * pos[n * 3 + 1]);
        atomicAdd(&s[g * 5 + 4], qn * pos[n * 3 + 2]);
    }
    __syncthreads();
    if (threadIdx.x < G * 5) atomicAdd(&acc[threadIdx.x], s[threadIdx.x]);
}

__global__ __launch_bounds__(256) void k_feat0(const int* __restrict__ elem,
    const float* __restrict__ embW, float* __restrict__ F)
{
    const int i = blockIdx.x * 256 + threadIdx.x;
    if (i < NC) F[i] = embW[elem[i >> 6] * 64 + (i & 63)];
}

__global__ __launch_bounds__(256) void k_pre(const float* __restrict__ q,
    const float* __restrict__ qc, float* __restrict__ F)
{
    const int i = blockIdx.x * 256 + threadIdx.x;
    if (i < NC) F[i] += q[i >> 6] * qc[i & 63];
}

// ---------------- element bucketing ----------------
__global__ __launch_bounds__(256) void k_hist(const int* __restrict__ elem, int* __restrict__ counts)
{
    const int n = blockIdx.x * 256 + threadIdx.x;
    if (n < N) atomicAdd(&counts[elem[n]], 1);
}
__global__ void k_offs(const int* __restrict__ counts, int* __restrict__ offs)
{
    if (threadIdx.x == 0 && blockIdx.x == 0) {
        int o = 0;
        for (int j = 0; j < NEL; ++j) { offs[j] = o; o += (counts[j] + 63) & ~63; }
        offs[NEL] = o;
    }
}
__global__ __launch_bounds__(256) void k_scatter(const int* __restrict__ elem,
    const int* __restrict__ offs, int* __restrict__ cursor, int* __restrict__ perm)
{
    const int n = blockIdx.x * 256 + threadIdx.x;
    if (n < N) {
        const int el = elem[n];
        const int p = atomicAdd(&cursor[el], 1);
        perm[offs[el] + p] = n;
    }
}

// ---------------- receiver CSR build ----------------
__global__ __launch_bounds__(256) void k_gcnt(const int* __restrict__ ei, int* __restrict__ cnt)
{
    const int e = blockIdx.x * 256 + threadIdx.x;
    if (e < E) atomicAdd(&cnt[ei[E + e]], 1);
}
__global__ __launch_bounds__(1024) void k_goff(const int* __restrict__ cnt, int* __restrict__ roff)
{
    __shared__ int part[1024];
    const int t = threadIdx.x;
    const int base = t * 8;
    int loc[8];
    int s = 0;
    #pragma unroll
    for (int i = 0; i < 8; ++i) { loc[i] = s; s += (base + i < N) ? cnt[base + i] : 0; }
    part[t] = s;
    __syncthreads();
    for (int d = 1; d < 1024; d <<= 1) {
        const int v = (t >= d) ? part[t - d] : 0;
        __syncthreads();
        part[t] += v;
        __syncthreads();
    }
    const int excl = (t == 0) ? 0 : part[t - 1];
    #pragma unroll
    for (int i = 0; i < 8; ++i) if (base + i < N) roff[base + i] = excl + loc[i];
    if (t == 0) roff[N] = E;
}
__global__ __launch_bounds__(256) void k_gscat(const int* __restrict__ ei,
    const int* __restrict__ roff, int* __restrict__ cur, int* __restrict__ elist)
{
    const int e = blockIdx.x * 256 + threadIdx.x;
    if (e < E) {
        const int rv = ei[E + e];
        const int p = atomicAdd(&cur[rv], 1);
        elist[roff[rv] + p] = e;
    }
}

// ---------------- weight transpose+bf16 prep (runs once) ----------------
// layout per t (WT_T ushorts): [0,512) W1T[64][8]; [512,4608) W2T[64][64];
// [4608,8704) W3T[64][64]; [8704,25088) W4T[256][64]
__global__ __launch_bounds__(256) void k_wprep(const float* __restrict__ rW1,
    const float* __restrict__ rW2, const float* __restrict__ rW3,
    const float* __restrict__ rW4, unsigned short* __restrict__ WT)
{
    const int idx = blockIdx.x * 256 + threadIdx.x;
    if (idx >= 2 * WT_T) return;
    const int t = idx / WT_T;
    const int r = idx % WT_T;
    float v;
    if (r < 512) {
        const int n = r >> 3, k = r & 7;
        v = rW1[t * 512 + k * 64 + n];
    } else if (r < 4608) {
        const int i = r - 512, n = i >> 6, k = i & 63;
        v = rW2[t * 4096 + k * 64 + n];
    } else if (r < 8704) {
        const int i = r - 4608, n = i >> 6, k = i & 63;
        v = rW3[t * 4096 + k * 64 + n];
    } else {
        const int i = r - 8704, n = i >> 6, k = i & 63;
        v = rW4[t * 16384 + k * 256 + n];
    }
    WT[idx] = f2bf(v);
}

// ---------------- lin_up GEMM -> bf16 node-major Hb[n][l][64] ----------------
__global__ __launch_bounds__(256) void k_lgemm_hb(const float* __restrict__ X,
    const float* __restrict__ Wb, unsigned short* __restrict__ Hb)
{
    __shared__ float Ws[4096];
    __shared__ float Xs[64 * XS];
    const int l  = blockIdx.y;
    const int nb = blockIdx.x << 6;
    const float* W = Wb + lmap_rt(l) * 4096;
    for (int i = threadIdx.x; i < 4096; i += 256) Ws[i] = W[i];
    const float* Xp = X + (size_t)l * NC + (size_t)nb * 64;
    for (int i = threadIdx.x; i < 4096; i += 256) Xs[(i >> 6) * XS + (i & 63)] = Xp[i];
    __syncthreads();
    const int tc = threadIdx.x & 15;
    const int tr = threadIdx.x >> 4;
    float4 acc[4];
    #pragma unroll
    for (int j = 0; j < 4; ++j) acc[j] = make_float4(0.f, 0.f, 0.f, 0.f);
    gemm64(Xs, Ws, tr, tc, acc);
    #pragma unroll
    for (int j = 0; j < 4; ++j) {
        const int n = nb + (tr << 2) + j;
        ushort4 o;
        o.x = f2bf(acc[j].x); o.y = f2bf(acc[j].y); o.z = f2bf(acc[j].z); o.w = f2bf(acc[j].w);
        *(ushort4*)&Hb[(size_t)n * 1024 + (l << 6) + (tc << 2)] = o;
    }
}

// ---------------- lin_out GEMM -> fp32 l-major ----------------
__global__ __launch_bounds__(256) void k_lgemm(const float* __restrict__ X,
    const float* __restrict__ Wb, float* __restrict__ Out)
{
    __shared__ float Ws[4096];
    __shared__ float Xs[64 * XS];
    const int l  = blockIdx.y;
    const int nb = blockIdx.x << 6;
    const float* W = Wb + lmap_rt(l) * 4096;
    for (int i = threadIdx.x; i < 4096; i += 256) Ws[i] = W[i];
    const float* Xp = X + (size_t)l * NC + (size_t)nb * 64;
    for (int i = threadIdx.x; i < 4096; i += 256) Xs[(i >> 6) * XS + (i & 63)] = Xp[i];
    __syncthreads();
    const int tc = threadIdx.x & 15;
    const int tr = threadIdx.x >> 4;
    float4 acc[4];
    #pragma unroll
    for (int j = 0; j < 4; ++j) acc[j] = make_float4(0.f, 0.f, 0.f, 0.f);
    gemm64(Xs, Ws, tr, tc, acc);
    float* Op = Out + (size_t)l * NC + (size_t)nb * 64;
    #pragma unroll
    for (int j = 0; j < 4; ++j)
        *(float4*)&Op[(((tr << 2) + j) << 6) + (tc << 2)] = acc[j];
}

// ---------------- sc GEMM over element buckets ----------------
__global__ __launch_bounds__(256) void k_sc(const float* __restrict__ F,
    const float* __restrict__ Wsc, const int* __restrict__ perm,
    const int* __restrict__ elem, float* __restrict__ Out)
{
    __shared__ float Ws[4096];
    __shared__ float Xs[64 * XS];
    __shared__ int rows[64];
    const int l  = blockIdx.y;
    const int tb = blockIdx.x << 6;
    if (threadIdx.x < 64) rows[threadIdx.x] = perm[tb + threadIdx.x];
    __syncthreads();
    if (rows[0] < 0) return;
    const float* W = Wsc + elem[rows[0]] * 4096;
    for (int i = threadIdx.x; i < 4096; i += 256) Ws[i] = W[i];
    for (int i = threadIdx.x; i < 4096; i += 256) {
        const int rr = i >> 6, cc = i & 63;
        const int n = rows[rr];
        Xs[rr * XS + cc] = (n >= 0) ? F[(size_t)l * NC + (size_t)n * 64 + cc] : 0.f;
    }
    __syncthreads();
    const int tc = threadIdx.x & 15;
    const int tr = threadIdx.x >> 4;
    float4 acc[4];
    #pragma unroll
    for (int j = 0; j < 4; ++j) acc[j] = make_float4(0.f, 0.f, 0.f, 0.f);
    gemm64(Xs, Ws, tr, tc, acc);
    #pragma unroll
    for (int j = 0; j < 4; ++j) {
        const int n = rows[(tr << 2) + j];
        if (n >= 0) *(float4*)&Out[(size_t)l * NC + (size_t)n * 64 + (tc << 2)] = acc[j];
    }
}

// ---------------- edge MLP pipeline via MFMA: rb -> h1 -> h2 -> h3 -> w(bf16) ----------------
__global__ __launch_bounds__(256) void k_wgemm(const float* __restrict__ pos,
    const float* __restrict__ shifts, const int* __restrict__ ei,
    const unsigned short* __restrict__ WT, const int* __restrict__ elist,
    unsigned short* __restrict__ wout)
{
    __shared__ unsigned short hbf[64 * HS];
    __shared__ unsigned short wtb[2][64 * HS];
    __shared__ unsigned short outS[64 * HS];
    const int t = threadIdx.x;
    const int lane = t & 63;
    const int wid  = t >> 6;
    const int m0   = wid << 4;
    const int quad = lane >> 4;
    const int idx  = lane & 15;
    const int j0 = blockIdx.x << 6;
    // geometry -> rb bf16 into hbf cols 0..7
    if (t < 64) {
        const int e = elist[j0 + t];
        const int s = ei[e], rv = ei[E + e];
        const float dx = pos[rv * 3 + 0] - pos[s * 3 + 0] + shifts[e * 3 + 0];
        const float dy = pos[rv * 3 + 1] - pos[s * 3 + 1] + shifts[e * 3 + 1];
        const float dz = pos[rv * 3 + 2] - pos[s * 3 + 2] + shifts[e * 3 + 2];
        const float r = sqrtf(dx * dx + dy * dy + dz * dz);
        const float u  = r * 0.2f;
        const float u2 = u * u, u5 = u2 * u2 * u;
        const float fc = 1.f - 21.f * u5 + 35.f * u5 * u - 15.f * u5 * u2;
        float pref = 0.63245553f * fc / (r + 1e-9f);
        if (u >= 1.f) pref = 0.f;
        const float piu = 3.14159265358979f * u;
        #pragma unroll
        for (int b = 0; b < 8; ++b) hbf[t * HS + b] = f2bf(__sinf((float)(b + 1) * piu) * pref);
    }
    // stage W1T (64x8) -> wtb[0]
    {
        const int n = t >> 2, k = (t & 3) << 1;
        wtb[0][n * HS + k]     = WT[n * 8 + k];
        wtb[0][n * HS + k + 1] = WT[n * 8 + k + 1];
    }
    // prefetch W2T -> regs
    const int prow = t >> 2, pkb = (t & 3) << 4;
    u16x8 pf0, pf1;
    pf0 = *(const u16x8*)&WT[512 + prow * 64 + pkb];
    pf1 = *(const u16x8*)&WT[512 + prow * 64 + pkb + 8];
    __syncthreads();
    f32x4v acc[4];
    #pragma unroll
    for (int c = 0; c < 4; ++c) { acc[c][0] = 0.f; acc[c][1] = 0.f; acc[c][2] = 0.f; acc[c][3] = 0.f; }
    // stage 1: h1 = silu(rb @ W1)
    mfma_stage(hbf, wtb[0], m0, lane, acc, true);
    __syncthreads();
    #pragma unroll
    for (int c4 = 0; c4 < 4; ++c4)
        #pragma unroll
        for (int r = 0; r < 4; ++r)
            hbf[(m0 + (quad << 2) + r) * HS + (c4 << 4) + idx] = f2bf(silu(acc[c4][r]));
    *(u16x8*)&wtb[1][prow * HS + pkb]     = pf0;
    *(u16x8*)&wtb[1][prow * HS + pkb + 8] = pf1;
    pf0 = *(const u16x8*)&WT[4608 + prow * 64 + pkb];
    pf1 = *(const u16x8*)&WT[4608 + prow * 64 + pkb + 8];
    __syncthreads();
    #pragma unroll
    for (int c = 0; c < 4; ++c) { acc[c][0] = 0.f; acc[c][1] = 0.f; acc[c][2] = 0.f; acc[c][3] = 0.f; }
    // stage 2: h2 = silu(h1 @ W2)
    mfma_stage(hbf, wtb[1], m0, lane, acc, false);
    __syncthreads();
    #pragma unroll
    for (int c4 = 0; c4 < 4; ++c4)
        #pragma unroll
        for (int r = 0; r < 4; ++r)
            hbf[(m0 + (quad << 2) + r) * HS + (c4 << 4) + idx] = f2bf(silu(acc[c4][r]));
    *(u16x8*)&wtb[0][prow * HS + pkb]     = pf0;
    *(u16x8*)&wtb[0][prow * HS + pkb + 8] = pf1;
    pf0 = *(const u16x8*)&WT[8704 + prow * 64 + pkb];
    pf1 = *(const u16x8*)&WT[8704 + prow * 64 + pkb + 8];
    __syncthreads();
    #pragma unroll
    for (int c = 0; c < 4; ++c) { acc[c][0] = 0.f; acc[c][1] = 0.f; acc[c][2] = 0.f; acc[c][3] = 0.f; }
    // stage 3: h3 = silu(h2 @ W3)
    mfma_stage(hbf, wtb[0], m0, lane, acc, false);
    __syncthreads();
    #pragma unroll
    for (int c4 = 0; c4 < 4; ++c4)
        #pragma unroll
        for (int r = 0; r < 4; ++r)
            hbf[(m0 + (quad << 2) + r) * HS + (c4 << 4) + idx] = f2bf(silu(acc[c4][r]));
    *(u16x8*)&wtb[1][prow * HS + pkb]     = pf0;
    *(u16x8*)&wtb[1][prow * HS + pkb + 8] = pf1;
    pf0 = *(const u16x8*)&WT[8704 + 4096 + prow * 64 + pkb];
    pf1 = *(const u16x8*)&WT[8704 + 4096 + prow * 64 + pkb + 8];
    __syncthreads();
    // stage 4: w = h3 @ W4 (64x256), 4 column chunks of 64
    int cur = 1;
    for (int c = 0; c < 4; ++c) {
        #pragma unroll
        for (int cc = 0; cc < 4; ++cc) { acc[cc][0] = 0.f; acc[cc][1] = 0.f; acc[cc][2] = 0.f; acc[cc][3] = 0.f; }
        mfma_stage(hbf, wtb[cur], m0, lane, acc, false);
        __syncthreads();
        #pragma unroll
        for (int c4 = 0; c4 < 4; ++c4)
            #pragma unroll
            for (int r = 0; r < 4; ++r)
                outS[(m0 + (quad << 2) + r) * HS + (c4 << 4) + idx] = f2bf(acc[c4][r]);
        if (c < 3) {
            *(u16x8*)&wtb[1 - cur][prow * HS + pkb]     = pf0;
            *(u16x8*)&wtb[1 - cur][prow * HS + pkb + 8] = pf1;
            if (c < 2) {
                pf0 = *(const u16x8*)&WT[8704 + (c + 2) * 4096 + prow * 64 + pkb];
                pf1 = *(const u16x8*)&WT[8704 + (c + 2) * 4096 + prow * 64 + pkb + 8];
            }
        }
        __syncthreads();
        *(u16x8*)&wout[(size_t)(j0 + prow) * 256 + (c << 6) + pkb]     = *(const u16x8*)&outS[prow * HS + pkb];
        *(u16x8*)&wout[(size_t)(j0 + prow) * 256 + (c << 6) + pkb + 8] = *(const u16x8*)&outS[prow * HS + pkb + 8];
        cur ^= 1;
    }
}

// ---------------- aggregate: wave per receiver, bf16 w + bf16 Hb ----------------
__global__ __launch_bounds__(256) void k_agg(const float* __restrict__ pos,
    const float* __restrict__ shifts, const int* __restrict__ ei,
    const unsigned short* __restrict__ Hb, const unsigned short* __restrict__ wb,
    const int* __restrict__ roff, const int* __restrict__ elist,
    float* __restrict__ A)
{
    const int lane = threadIdx.x & 63;
    const int n = (blockIdx.x << 2) + (threadIdx.x >> 6);
    const int ja = roff[n], jb2 = roff[n + 1];
    float acc[16];
    #pragma unroll
    for (int l = 0; l < 16; ++l) acc[l] = 0.f;
    const float p0x = pos[n * 3], p0y = pos[n * 3 + 1], p0z = pos[n * 3 + 2];
    constexpr int LM[16] = {0,1,1,1,2,2,2,2,2,3,3,3,3,3,3,3};
    for (int j = ja; j < jb2; ++j) {
        const int e = elist[j];
        const int s = ei[e];
        const float dx = p0x - pos[s * 3 + 0] + shifts[e * 3 + 0];
        const float dy = p0y - pos[s * 3 + 1] + shifts[e * 3 + 1];
        const float dz = p0z - pos[s * 3 + 2] + shifts[e * 3 + 2];
        const float r = sqrtf(dx * dx + dy * dy + dz * dz);
        if (r >= RMAX) continue;
        const float inv = 1.f / (r + 1e-9f);
        const float x = dx * inv, y = dy * inv, z = dz * inv;
        const float xx = x * x, yy = y * y, zz = z * z;
        float Y[16];
        Y[0] = 1.f;
        Y[1] = 1.7320508f * x;  Y[2] = 1.7320508f * y;  Y[3] = 1.7320508f * z;
        Y[4] = 3.8729833f * x * y;  Y[5] = 3.8729833f * y * z;
        Y[6] = 0.5f * 2.2360680f * (3.f * zz - 1.f);
        Y[7] = 3.8729833f * x * z;  Y[8] = 0.5f * 3.8729833f * (xx - yy);
        Y[9]  = 2.0916500f * y * (3.f * xx - yy);
        Y[10] = 10.2469508f * x * y * z;
        Y[11] = 1.6201852f * y * (5.f * zz - 1.f);
        Y[12] = 0.5f * 2.6457513f * z * (5.f * zz - 3.f);
        Y[13] = 1.6201852f * x * (5.f * zz - 1.f);
        Y[14] = 0.5f * 10.2469508f * z * (xx - yy);
        Y[15] = 2.0916500f * x * (xx - 3.f * yy);
        float se = 0.f;
        const unsigned short* Hp = Hb + (size_t)s * 1024 + lane;
        #pragma unroll
        for (int l = 0; l < 16; ++l) se += bf2f(Hp[l << 6]) * Y[l];
        se *= 0.0625f;
        const ushort4 wq = *(const ushort4*)&wb[(size_t)j * 256 + (lane << 2)];
        const float wl[4] = { bf2f(wq.x) * se, bf2f(wq.y) * se, bf2f(wq.z) * se, bf2f(wq.w) * se };
        #pragma unroll
        for (int l = 0; l < 16; ++l) acc[l] += wl[LM[l]] * Y[l];
    }
    float* Ap = A + (size_t)n * 64 + lane;
    #pragma unroll
    for (int l = 0; l < 16; ++l) Ap[(size_t)l * NC] = acc[l];
}

// ---------------- s1[n][c] = sum_l H2[l][n][c]^2 ----------------
__global__ __launch_bounds__(256) void k_s1(const float* __restrict__ H, float* __restrict__ s1)
{
    const int i = blockIdx.x * 256 + threadIdx.x;
    if (i < NC) {
        float s = 0.f;
        #pragma unroll
        for (int l = 0; l < 16; ++l) { const float a = H[(size_t)l * NC + i]; s += a * a; }
        s1[i] = s;
    }
}

// ---------------- out = sum_p (A'*s1^p)@Wp_p + sc -> F ----------------
__global__ __launch_bounds__(256) void k_out(const float* __restrict__ Ap,
    const float* __restrict__ s1, const float* __restrict__ Wp3,
    const float* __restrict__ sc, float* __restrict__ F)
{
    __shared__ float Xs[64 * XS];
    __shared__ float Ws[4096];
    const int l  = blockIdx.y;
    const int nb = blockIdx.x << 6;
    const int t  = threadIdx.x;
    const int tc = t & 15;
    const int tr = t >> 4;
    const float* Xp = Ap + (size_t)l * NC + (size_t)nb * 64;
    float av[16], sv[16];
    #pragma unroll
    for (int k = 0; k < 16; ++k) {
        const int i = t + (k << 8);
        av[k] = Xp[i];
        sv[k] = s1[nb * 64 + i];
    }
    float wreg[16];
    #pragma unroll
    for (int c = 0; c < 4; ++c) *(float4*)&wreg[c * 4] = *(const float4*)&Wp3[(c << 10) + (t << 2)];
    float4 acc[4];
    #pragma unroll
    for (int j = 0; j < 4; ++j) acc[j] = make_float4(0.f, 0.f, 0.f, 0.f);
    for (int p = 0; p < 3; ++p) {
        #pragma unroll
        for (int k = 0; k < 16; ++k) {
            const int i = t + (k << 8);
            Xs[(i >> 6) * XS + (i & 63)] = av[k];
            av[k] *= sv[k];
        }
        #pragma unroll
        for (int c = 0; c < 4; ++c) *(float4*)&Ws[(c << 10) + (t << 2)] = *(const float4*)&wreg[c * 4];
        if (p < 2) {
            #pragma unroll
            for (int c = 0; c < 4; ++c)
                *(float4*)&wreg[c * 4] = *(const float4*)&Wp3[(p + 1) * 4096 + (c << 10) + (t << 2)];
        }
        __syncthreads();
        gemm64(Xs, Ws, tr, tc, acc);
        __syncthreads();
    }
    #pragma unroll
    for (int j = 0; j < 4; ++j) {
        const int row = (tr << 2) + j;
        const size_t idx = (size_t)l * NC + (size_t)(nb + row) * 64 + (tc << 2);
        const float4 sv2 = *(const float4*)&sc[idx];
        float4 o;
        o.x = acc[j].x + sv2.x; o.y = acc[j].y + sv2.y; o.z = acc[j].z + sv2.z; o.w = acc[j].w + sv2.w;
        *(float4*)&F[idx] = o;
    }
}

// ---------------- readout ----------------
__global__ __launch_bounds__(256) void k_read(const float* __restrict__ F,
    const float* __restrict__ q, const int* __restrict__ batch,
    const float* __restrict__ Wr0, const float* __restrict__ Wa,
    const float* __restrict__ Wb, const float* __restrict__ Wq,
    float* __restrict__ acc, int last)
{
    __shared__ float sred[G];
    if (threadIdx.x < G) sred[threadIdx.x] = 0.f;
    __syncthreads();
    const int n = blockIdx.x * 256 + threadIdx.x;
    if (n < N) {
        float a16[16];
        #pragma unroll
        for (int j = 0; j < 16; ++j) a16[j] = 0.f;
        float ar = 0.f, aq = 0.f;
        const float* f = F + (size_t)n * 64;
        for (int c = 0; c < 64; ++c) {
            const float fv = f[c];
            aq += fv * Wq[c];
            if (last) {
                #pragma unroll
                for (int j = 0; j < 16; ++j) a16[j] += fv * Wa[c * 16 + j];
            } else ar += fv * Wr0[c];
        }
        float en;
        if (last) {
            en = 0.f;
            #pragma unroll
            for (int j = 0; j < 16; ++j) en += silu(a16[j]) * Wb[j];
        } else en = ar;
        en += q[n] * aq;
        atomicAdd(&sred[batch[n]], en);
    }
    __syncthreads();
    if (threadIdx.x < G) atomicAdd(&acc[threadIdx.x * 5], sred[threadIdx.x]);
}

// ---------------- Ewald ----------------
__global__ __launch_bounds__(256) void k_kvec(const float* __restrict__ rcell,
    float* __restrict__ kvec, float* __restrict__ k2)
{
    const int idx = blockIdx.x * 256 + threadIdx.x;
    if (idx >= G * NK) return;
    const int g = idx / NK, k = idx % NK;
    const int kk = k + (k >= 171 ? 1 : 0);
    const int a = kk / 49 - 3, b = (kk / 7) % 7 - 3, c = kk % 7 - 3;
    const float* rc = rcell + g * 9;
    float s = 0.f;
    #pragma unroll
    for (int i = 0; i < 3; ++i) {
        const float kv = 6.283185307f * ((float)a * rc[0 + i] + (float)b * rc[3 + i] + (float)c * rc[6 + i]);
        kvec[idx * 3 + i] = kv;
        s += kv * kv;
    }
    k2[idx] = s;
}

__global__ __launch_bounds__(256) void k_phase(const float* __restrict__ pos,
    const float* __restrict__ q, const float* __restrict__ kvec,
    float* __restrict__ Sr, float* __restrict__ Si)
{
    __shared__ float kvs[38 * 3];
    __shared__ float srs[38], sis[38];
    const int g = blockIdx.z, kc = blockIdx.x, ncb = blockIdx.y;
    const int kbase = kc * 38;
    if (threadIdx.x < 38 * 3) kvs[threadIdx.x] = kvec[((size_t)g * NK + kbase) * 3 + threadIdx.x];
    if (threadIdx.x < 38) { srs[threadIdx.x] = 0.f; sis[threadIdx.x] = 0.f; }
    __syncthreads();
    const int t = threadIdx.x;
    float px = 0.f, py = 0.f, pz = 0.f, qn = 0.f;
    if (t < 250) {
        const int n = g * NGR + ncb * 250 + t;
        px = pos[n * 3]; py = pos[n * 3 + 1]; pz = pos[n * 3 + 2]; qn = q[n];
    }
    const int lane = t & 63;
    for (int j = 0; j < 38; ++j) {
        const float ph = px * kvs[j * 3] + py * kvs[j * 3 + 1] + pz * kvs[j * 3 + 2];
        float sv, cv;
        __sincosf(ph, &sv, &cv);
        float vr = qn * cv, vi = qn * sv;
        #pragma unroll
        for (int o = 32; o > 0; o >>= 1) { vr += __shfl_down(vr, o, 64); vi += __shfl_down(vi, o, 64); }
        if (lane == 0) { atomicAdd(&srs[j], vr); atomicAdd(&sis[j], vi); }
    }
    __syncthreads();
    if (t < 38) {
        atomicAdd(&Sr[g * NK + kbase + t], srs[t]);
        atomicAdd(&Si[g * NK + kbase + t], sis[t]);
    }
}

__global__ __launch_bounds__(512) void k_final(const float* __restrict__ k2,
    const float* __restrict__ Sr, const float* __restrict__ Si,
    const float* __restrict__ vol, const float* __restrict__ acc,
    float* __restrict__ out)
{
    __shared__ float red[512];
    const int g = blockIdx.x, t = threadIdx.x;
    float v = 0.f;
    if (t < NK) {
        const float kk = k2[g * NK + t];
        const float sr = Sr[g * NK + t], si = Si[g * NK + t];
        v = __expf(-0.5f * kk) * (sr * sr + si * si) / kk;
    }
    red[t] = v;
    __syncthreads();
    for (int s2 = 256; s2 > 0; s2 >>= 1) {
        if (t < s2) red[t] += red[t + s2];
        __syncthreads();
    }
    if (t == 0) {
        const float Ees = 6.283185307f / vol[g] * red[0];
        out[g]     = acc[g * 5 + 0] + Ees;
        out[4 + g] = acc[g * 5 + 1];
        out[8 + g * 3 + 0] = acc[g * 5 + 2];
        out[8 + g * 3 + 1] = acc[g * 5 + 3];
        out[8 + g * 3 + 2] = acc[g * 5 + 4];
    }
}

extern "C" void kernel_launch(void* const* d_in, const int* in_sizes, int n_in,
                              void* d_out, int out_size, void* d_ws, size_t ws_size,
                              hipStream_t stream)
{
    const float* na    = (const float*)d_in[0];
    const float* pos   = (const float*)d_in[1];
    const float* shif  = (const float*)d_in[2];
    const float* q     = (const float*)d_in[3];
    const float* rcell = (const float*)d_in[5];
    const float* vol   = (const float*)d_in[6];
    const int*   ei    = (const int*)d_in[7];
    const int*   batch = (const int*)d_in[8];
    const float* embW  = (const float*)d_in[9];
    const float* qcoef = (const float*)d_in[10];
    const float* rW1   = (const float*)d_in[11];
    const float* rW2   = (const float*)d_in[12];
    const float* rW3   = (const float*)d_in[13];
    const float* rW4   = (const float*)d_in[14];
    const float* lup   = (const float*)d_in[15];
    const float* lout  = (const float*)d_in[16];
    const float* Wsc   = (const float*)d_in[17];
    const float* Wp    = (const float*)d_in[18];
    const float* Wr0   = (const float*)d_in[19];
    const float* Wa    = (const float*)d_in[20];
    const float* Wb    = (const float*)d_in[21];
    const float* Wq    = (const float*)d_in[22];
    const float* aE    = (const float*)d_in[23];
    float* out = (float*)d_out;

    float* wsf  = (float*)d_ws;
    float* F    = wsf;                  // [16][N][64] fp32
    float* A    = F + 8192000;          // [16][N][64] fp32 (A result; later sc)
    float* R    = A + 8192000;          // 20,480,000-float region:
    float* H2   = R;                    //   fp32 [16][N][64] (lin_out result)
    unsigned short* Hb = (unsigned short*)R;             // bf16 [N][16][64]
    unsigned short* wb = (unsigned short*)(R + 4096000); // bf16 [E][256]
    float* s1   = R + 20480000;         // [N][64]
    float* kvec = s1 + 512000;          // [G*342][3]
    float* k2   = kvec + 4104;
    float* Sr   = k2 + 1368;
    float* Si   = Sr + 1368;
    float* acc  = Si + 1368;            // [G][5]
    int*   elem = (int*)(acc + 32);     // [N]
    int*   perm = elem + 8000;          // [8640]
    int*   counts = perm + 8640;        // [16]
    int*   cursor = counts + 16;        // [16]
    int*   offs   = cursor + 16;        // [16]
    int*   roff   = offs + 16;          // [N+1]
    int*   cnt    = roff + 8001;        // [N]
    int*   cur    = cnt + 8000;         // [N]
    int*   elist  = cur + 8000;         // [E]
    unsigned short* WTb = (unsigned short*)(elist + E);  // [2*WT_T] transposed bf16 weights

    hipMemsetAsync(F, 0, 8192000 * sizeof(float), stream);
    hipMemsetAsync(Sr, 0, (1368 * 2 + 32) * sizeof(float), stream);
    hipMemsetAsync(perm, 0xFF, 8640 * sizeof(int), stream);
    hipMemsetAsync(counts, 0, 32 * sizeof(int), stream);
    hipMemsetAsync(cnt, 0, 16000 * sizeof(int), stream);

    k_init<<<32, 256, 0, stream>>>(na, q, pos, batch, aE, elem, acc);
    k_feat0<<<2000, 256, 0, stream>>>(elem, embW, F);
    k_hist<<<32, 256, 0, stream>>>(elem, counts);
    k_offs<<<1, 64, 0, stream>>>(counts, offs);
    k_scatter<<<32, 256, 0, stream>>>(elem, offs, cursor, perm);
    k_gcnt<<<500, 256, 0, stream>>>(ei, cnt);
    k_goff<<<1, 1024, 0, stream>>>(cnt, roff);
    k_gscat<<<500, 256, 0, stream>>>(ei, roff, cur, elist);
    k_wprep<<<196, 256, 0, stream>>>(rW1, rW2, rW3, rW4, WTb);
    k_kvec<<<6, 256, 0, stream>>>(rcell, kvec, k2);
    k_phase<<<dim3(9, 8, G), 256, 0, stream>>>(pos, q, kvec, Sr, Si);

    for (int t = 0; t < 2; ++t) {
        k_pre<<<2000, 256, 0, stream>>>(q, qcoef + t * 64, F);
        k_lgemm_hb<<<dim3(125, 16), 256, 0, stream>>>(F, lup + t * 4 * 4096, Hb);
        k_wgemm<<<2000, 256, 0, stream>>>(pos, shif, ei, WTb + t * WT_T, elist, wb);
        k_agg<<<2000, 256, 0, stream>>>(pos, shif, ei, Hb, wb, roff, elist, A);
        k_lgemm<<<dim3(125, 16), 256, 0, stream>>>(A, lout + t * 4 * 4096, H2);
        k_s1<<<2000, 256, 0, stream>>>(H2, s1);
        k_sc<<<dim3(135, 16), 256, 0, stream>>>(F, Wsc + t * NEL * 4096, perm, elem, A);
        k_out<<<dim3(125, 16), 256, 0, stream>>>(H2, s1, Wp + t * 3 * 4096, A, F);
        k_read<<<32, 256, 0, stream>>>(F, q, batch, Wr0, Wa, Wb, Wq + t * 64, acc, t == 1);
    }
    k_final<<<G, 512, 0, stream>>>(k2, Sr, Si, vol, acc, out);
}

// Round 7
// 649.454 us; speedup vs baseline: 2.5972x; 1.1813x over previous
//
#include <hip/hip_runtime.h>
#include <hip/hip_bf16.h>

constexpr int N    = 8000;
constexpr int E    = 128000;
constexpr int G    = 4;
constexpr int NEL  = 10;
constexpr int NGR  = N / G;          // 2000
constexpr int NC   = N * 64;         // 512000
constexpr int NK   = 342;            // Ewald vectors
constexpr float RMAX = 5.0f;
constexpr int XS = 68;               // padded LDS row stride (floats) for fp32 GEMMs
constexpr int HS = 72;               // padded LDS row stride (bf16) for MFMA tiles
constexpr int WT_T = 25088;          // per-t size of transposed radial-weight block (ushorts)

typedef __bf16 bf16x8 __attribute__((ext_vector_type(8)));
typedef float  f32x4v __attribute__((ext_vector_type(4)));
typedef unsigned short u16x8 __attribute__((ext_vector_type(8)));

__device__ __forceinline__ int lmap_rt(int l) { return (l >= 1) + (l >= 4) + (l >= 9); }
__device__ __forceinline__ float silu(float x) { return x / (1.f + __expf(-x)); }
__device__ __forceinline__ float bf2f(unsigned short u) { return __uint_as_float(((unsigned)u) << 16); }
__device__ __forceinline__ unsigned short f2bf(float f) {
    __hip_bfloat16 h = __float2bfloat16(f);
    return *(unsigned short*)&h;
}

// 64x64 @ 64x64 fp32 inner product, X stride XS, W stride 64
__device__ __forceinline__ void gemm64(const float* X, const float* W,
                                       int tr, int tc, float4 acc[4])
{
    #pragma unroll 2
    for (int k0 = 0; k0 < 64; k0 += 4) {
        float4 xq[4];
        #pragma unroll
        for (int j = 0; j < 4; ++j) xq[j] = *(const float4*)&X[((tr << 2) + j) * XS + k0];
        #pragma unroll
        for (int i = 0; i < 4; ++i) {
            const float4 w = *(const float4*)&W[((k0 + i) << 6) + (tc << 2)];
            #pragma unroll
            for (int j = 0; j < 4; ++j) {
                const float x = ((const float*)&xq[j])[i];
                acc[j].x += x * w.x; acc[j].y += x * w.y; acc[j].z += x * w.z; acc[j].w += x * w.w;
            }
        }
    }
}

// MFMA 64x64(xK) stage: hsrc rows = M (stride HS), wt rows = N (stride HS), K=64 (or 8)
__device__ __forceinline__ void mfma_stage(const unsigned short* hsrc, const unsigned short* wt,
                                           int m0, int lane, f32x4v acc[4], bool k8only)
{
    const int quad = lane >> 4;
    const int idx  = lane & 15;
    bf16x8 bz;
    #pragma unroll
    for (int i = 0; i < 8; ++i) bz[i] = (__bf16)0.f;
    bf16x8 a0 = bz, a1 = bz;
    const int mrow = m0 + idx;
    if (k8only) {
        if (quad == 0) a0 = *(const bf16x8*)&hsrc[mrow * HS];
    } else {
        a0 = *(const bf16x8*)&hsrc[mrow * HS + (quad << 3)];
        a1 = *(const bf16x8*)&hsrc[mrow * HS + 32 + (quad << 3)];
    }
    #pragma unroll
    for (int c4 = 0; c4 < 4; ++c4) {
        const int nrow = (c4 << 4) + idx;
        if (k8only) {
            bf16x8 b0 = bz;
            if (quad == 0) b0 = *(const bf16x8*)&wt[nrow * HS];
            acc[c4] = __builtin_amdgcn_mfma_f32_16x16x32_bf16(a0, b0, acc[c4], 0, 0, 0);
        } else {
            const bf16x8 b0 = *(const bf16x8*)&wt[nrow * HS + (quad << 3)];
            const bf16x8 b1 = *(const bf16x8*)&wt[nrow * HS + 32 + (quad << 3)];
            acc[c4] = __builtin_amdgcn_mfma_f32_16x16x32_bf16(a0, b0, acc[c4], 0, 0, 0);
            acc[c4] = __builtin_amdgcn_mfma_f32_16x16x32_bf16(a1, b1, acc[c4], 0, 0, 0);
        }
    }
}

// ---------------- init: elem, e0/charge/dipole ----------------
__global__ __launch_bounds__(256) void k_init(const float* __restrict__ na,
    const float* __restrict__ q, const float* __restrict__ pos,
    const int* __restrict__ batch, const float* __restrict__ aE,
    int* __restrict__ elem, float* __restrict__ acc)
{
    __shared__ float s[G * 5];
    if (threadIdx.x < G * 5) s[threadIdx.x] = 0.f;
    __syncthreads();
    const int n = blockIdx.x * 256 + threadIdx.x;
    if (n < N) {
        int el = 0; float best = na[n * NEL];
        #pragma unroll
        for (int j = 1; j < NEL; ++j) { float v = na[n * NEL + j]; if (v > best) { best = v; el = j; } }
        elem[n] = el;
        const int g = batch[n];
        const float qn = q[n];
        atomicAdd(&s[g * 5 + 0], aE[el]);
        atomicAdd(&s[g * 5 + 1], qn);
        atomicAdd(&s[g * 5 + 2], qn * pos[n * 3 + 0]);
        atomicAdd(&s[g * 5 + 3], qn * pos[n * 3 + 1]);
        atomicAdd(&s[g * 5 + 4], qn * pos[n * 3 + 2]);
    }
    __syncthreads();
    if (threadIdx.x < G * 5) atomicAdd(&acc[threadIdx.x], s[threadIdx.x]);
}

__global__ __launch_bounds__(256) void k_feat0(const int* __restrict__ elem,
    const float* __restrict__ embW, float* __restrict__ F)
{
    const int i = blockIdx.x * 256 + threadIdx.x;
    if (i < NC) F[i] = embW[elem[i >> 6] * 64 + (i & 63)];
}

__global__ __launch_bounds__(256) void k_pre(const float* __restrict__ q,
    const float* __restrict__ qc, float* __restrict__ F)
{
    const int i = blockIdx.x * 256 + threadIdx.x;
    if (i < NC) F[i] += q[i >> 6] * qc[i & 63];
}

// ---------------- element bucketing ----------------
__global__ __launch_bounds__(256) void k_hist(const int* __restrict__ elem, int* __restrict__ counts)
{
    const int n = blockIdx.x * 256 + threadIdx.x;
    if (n < N) atomicAdd(&counts[elem[n]], 1);
}
__global__ void k_offs(const int* __restrict__ counts, int* __restrict__ offs)
{
    if (threadIdx.x == 0 && blockIdx.x == 0) {
        int o = 0;
        for (int j = 0; j < NEL; ++j) { offs[j] = o; o += (counts[j] + 63) & ~63; }
        offs[NEL] = o;
    }
}
__global__ __launch_bounds__(256) void k_scatter(const int* __restrict__ elem,
    const int* __restrict__ offs, int* __restrict__ cursor, int* __restrict__ perm)
{
    const int n = blockIdx.x * 256 + threadIdx.x;
    if (n < N) {
        const int el = elem[n];
        const int p = atomicAdd(&cursor[el], 1);
        perm[offs[el] + p] = n;
    }
}

// ---------------- receiver CSR build ----------------
__global__ __launch_bounds__(256) void k_gcnt(const int* __restrict__ ei, int* __restrict__ cnt)
{
    const int e = blockIdx.x * 256 + threadIdx.x;
    if (e < E) atomicAdd(&cnt[ei[E + e]], 1);
}
__global__ __launch_bounds__(1024) void k_goff(const int* __restrict__ cnt, int* __restrict__ roff)
{
    __shared__ int part[1024];
    const int t = threadIdx.x;
    const int base = t * 8;
    int loc[8];
    int s = 0;
    #pragma unroll
    for (int i = 0; i < 8; ++i) { loc[i] = s; s += (base + i < N) ? cnt[base + i] : 0; }
    part[t] = s;
    __syncthreads();
    for (int d = 1; d < 1024; d <<= 1) {
        const int v = (t >= d) ? part[t - d] : 0;
        __syncthreads();
        part[t] += v;
        __syncthreads();
    }
    const int excl = (t == 0) ? 0 : part[t - 1];
    #pragma unroll
    for (int i = 0; i < 8; ++i) if (base + i < N) roff[base + i] = excl + loc[i];
    if (t == 0) roff[N] = E;
}
__global__ __launch_bounds__(256) void k_gscat(const int* __restrict__ ei,
    const int* __restrict__ roff, int* __restrict__ cur, int* __restrict__ elist)
{
    const int e = blockIdx.x * 256 + threadIdx.x;
    if (e < E) {
        const int rv = ei[E + e];
        const int p = atomicAdd(&cur[rv], 1);
        elist[roff[rv] + p] = e;
    }
}

// ---------------- per-elist-position geometry precompute ----------------
__global__ __launch_bounds__(256) void k_geom(const float* __restrict__ pos,
    const float* __restrict__ shifts, const int* __restrict__ ei,
    const int* __restrict__ elist, float4* __restrict__ geomv, int* __restrict__ spck)
{
    const int j = blockIdx.x * 256 + threadIdx.x;
    if (j >= E) return;
    const int e = elist[j];
    const int s = ei[e], rv = ei[E + e];
    const float dx = pos[rv * 3 + 0] - pos[s * 3 + 0] + shifts[e * 3 + 0];
    const float dy = pos[rv * 3 + 1] - pos[s * 3 + 1] + shifts[e * 3 + 1];
    const float dz = pos[rv * 3 + 2] - pos[s * 3 + 2] + shifts[e * 3 + 2];
    const float r = sqrtf(dx * dx + dy * dy + dz * dz);
    const float inv = 1.f / (r + 1e-9f);
    float4 g;
    g.x = dx * inv; g.y = dy * inv; g.z = dz * inv; g.w = r;
    geomv[j] = g;
    spck[j] = s;
}

// ---------------- weight transpose+bf16 prep (runs once) ----------------
__global__ __launch_bounds__(256) void k_wprep(const float* __restrict__ rW1,
    const float* __restrict__ rW2, const float* __restrict__ rW3,
    const float* __restrict__ rW4, unsigned short* __restrict__ WT)
{
    const int idx = blockIdx.x * 256 + threadIdx.x;
    if (idx >= 2 * WT_T) return;
    const int t = idx / WT_T;
    const int r = idx % WT_T;
    float v;
    if (r < 512) {
        const int n = r >> 3, k = r & 7;
        v = rW1[t * 512 + k * 64 + n];
    } else if (r < 4608) {
        const int i = r - 512, n = i >> 6, k = i & 63;
        v = rW2[t * 4096 + k * 64 + n];
    } else if (r < 8704) {
        const int i = r - 4608, n = i >> 6, k = i & 63;
        v = rW3[t * 4096 + k * 64 + n];
    } else {
        const int i = r - 8704, n = i >> 6, k = i & 63;
        v = rW4[t * 16384 + k * 256 + n];
    }
    WT[idx] = f2bf(v);
}

// WpT[t][p][d][c] = Wp[t][p][c][d], bf16
__global__ __launch_bounds__(256) void k_wprep2(const float* __restrict__ Wp,
    unsigned short* __restrict__ WpT)
{
    const int idx = blockIdx.x * 256 + threadIdx.x;
    if (idx >= 24576) return;
    const int tp = idx / 4096;        // t*3+p
    const int i  = idx % 4096;
    const int d = i >> 6, c = i & 63;
    WpT[idx] = f2bf(Wp[(size_t)tp * 4096 + c * 64 + d]);
}

// ---------------- lin_up GEMM -> bf16 node-major Hb[n][l][64] ----------------
__global__ __launch_bounds__(256) void k_lgemm_hb(const float* __restrict__ X,
    const float* __restrict__ Wb, unsigned short* __restrict__ Hb)
{
    __shared__ float Ws[4096];
    __shared__ float Xs[64 * XS];
    const int l  = blockIdx.y;
    const int nb = blockIdx.x << 6;
    const float* W = Wb + lmap_rt(l) * 4096;
    for (int i = threadIdx.x; i < 4096; i += 256) Ws[i] = W[i];
    const float* Xp = X + (size_t)l * NC + (size_t)nb * 64;
    for (int i = threadIdx.x; i < 4096; i += 256) Xs[(i >> 6) * XS + (i & 63)] = Xp[i];
    __syncthreads();
    const int tc = threadIdx.x & 15;
    const int tr = threadIdx.x >> 4;
    float4 acc[4];
    #pragma unroll
    for (int j = 0; j < 4; ++j) acc[j] = make_float4(0.f, 0.f, 0.f, 0.f);
    gemm64(Xs, Ws, tr, tc, acc);
    #pragma unroll
    for (int j = 0; j < 4; ++j) {
        const int n = nb + (tr << 2) + j;
        ushort4 o;
        o.x = f2bf(acc[j].x); o.y = f2bf(acc[j].y); o.z = f2bf(acc[j].z); o.w = f2bf(acc[j].w);
        *(ushort4*)&Hb[(size_t)n * 1024 + (l << 6) + (tc << 2)] = o;
    }
}

// ---------------- lin_out GEMM -> fp32 l-major ----------------
__global__ __launch_bounds__(256) void k_lgemm(const float* __restrict__ X,
    const float* __restrict__ Wb, float* __restrict__ Out)
{
    __shared__ float Ws[4096];
    __shared__ float Xs[64 * XS];
    const int l  = blockIdx.y;
    const int nb = blockIdx.x << 6;
    const float* W = Wb + lmap_rt(l) * 4096;
    for (int i = threadIdx.x; i < 4096; i += 256) Ws[i] = W[i];
    const float* Xp = X + (size_t)l * NC + (size_t)nb * 64;
    for (int i = threadIdx.x; i < 4096; i += 256) Xs[(i >> 6) * XS + (i & 63)] = Xp[i];
    __syncthreads();
    const int tc = threadIdx.x & 15;
    const int tr = threadIdx.x >> 4;
    float4 acc[4];
    #pragma unroll
    for (int j = 0; j < 4; ++j) acc[j] = make_float4(0.f, 0.f, 0.f, 0.f);
    gemm64(Xs, Ws, tr, tc, acc);
    float* Op = Out + (size_t)l * NC + (size_t)nb * 64;
    #pragma unroll
    for (int j = 0; j < 4; ++j)
        *(float4*)&Op[(((tr << 2) + j) << 6) + (tc << 2)] = acc[j];
}

// ---------------- sc GEMM over element buckets ----------------
__global__ __launch_bounds__(256) void k_sc(const float* __restrict__ F,
    const float* __restrict__ Wsc, const int* __restrict__ perm,
    const int* __restrict__ elem, float* __restrict__ Out)
{
    __shared__ float Ws[4096];
    __shared__ float Xs[64 * XS];
    __shared__ int rows[64];
    const int l  = blockIdx.y;
    const int tb = blockIdx.x << 6;
    if (threadIdx.x < 64) rows[threadIdx.x] = perm[tb + threadIdx.x];
    __syncthreads();
    if (rows[0] < 0) return;
    const float* W = Wsc + elem[rows[0]] * 4096;
    for (int i = threadIdx.x; i < 4096; i += 256) Ws[i] = W[i];
    for (int i = threadIdx.x; i < 4096; i += 256) {
        const int rr = i >> 6, cc = i & 63;
        const int n = rows[rr];
        Xs[rr * XS + cc] = (n >= 0) ? F[(size_t)l * NC + (size_t)n * 64 + cc] : 0.f;
    }
    __syncthreads();
    const int tc = threadIdx.x & 15;
    const int tr = threadIdx.x >> 4;
    float4 acc[4];
    #pragma unroll
    for (int j = 0; j < 4; ++j) acc[j] = make_float4(0.f, 0.f, 0.f, 0.f);
    gemm64(Xs, Ws, tr, tc, acc);
    #pragma unroll
    for (int j = 0; j < 4; ++j) {
        const int n = rows[(tr << 2) + j];
        if (n >= 0) *(float4*)&Out[(size_t)l * NC + (size_t)n * 64 + (tc << 2)] = acc[j];
    }
}

// ---------------- edge MLP pipeline via MFMA ----------------
__global__ __launch_bounds__(256) void k_wgemm(const float4* __restrict__ geomv,
    const unsigned short* __restrict__ WT, unsigned short* __restrict__ wout)
{
    __shared__ unsigned short hbf[64 * HS];
    __shared__ unsigned short wtb[2][64 * HS];
    __shared__ unsigned short outS[64 * HS];
    const int t = threadIdx.x;
    const int lane = t & 63;
    const int wid  = t >> 6;
    const int m0   = wid << 4;
    const int quad = lane >> 4;
    const int idx  = lane & 15;
    const int j0 = blockIdx.x << 6;
    if (t < 64) {
        const float r = geomv[j0 + t].w;
        const float u  = r * 0.2f;
        const float u2 = u * u, u5 = u2 * u2 * u;
        const float fc = 1.f - 21.f * u5 + 35.f * u5 * u - 15.f * u5 * u2;
        float pref = 0.63245553f * fc / (r + 1e-9f);
        if (u >= 1.f) pref = 0.f;
        const float piu = 3.14159265358979f * u;
        #pragma unroll
        for (int b = 0; b < 8; ++b) hbf[t * HS + b] = f2bf(__sinf((float)(b + 1) * piu) * pref);
    }
    {
        const int n = t >> 2, k = (t & 3) << 1;
        wtb[0][n * HS + k]     = WT[n * 8 + k];
        wtb[0][n * HS + k + 1] = WT[n * 8 + k + 1];
    }
    const int prow = t >> 2, pkb = (t & 3) << 4;
    u16x8 pf0, pf1;
    pf0 = *(const u16x8*)&WT[512 + prow * 64 + pkb];
    pf1 = *(const u16x8*)&WT[512 + prow * 64 + pkb + 8];
    __syncthreads();
    f32x4v acc[4];
    #pragma unroll
    for (int c = 0; c < 4; ++c) { acc[c][0] = 0.f; acc[c][1] = 0.f; acc[c][2] = 0.f; acc[c][3] = 0.f; }
    mfma_stage(hbf, wtb[0], m0, lane, acc, true);
    __syncthreads();
    #pragma unroll
    for (int c4 = 0; c4 < 4; ++c4)
        #pragma unroll
        for (int r = 0; r < 4; ++r)
            hbf[(m0 + (quad << 2) + r) * HS + (c4 << 4) + idx] = f2bf(silu(acc[c4][r]));
    *(u16x8*)&wtb[1][prow * HS + pkb]     = pf0;
    *(u16x8*)&wtb[1][prow * HS + pkb + 8] = pf1;
    pf0 = *(const u16x8*)&WT[4608 + prow * 64 + pkb];
    pf1 = *(const u16x8*)&WT[4608 + prow * 64 + pkb + 8];
    __syncthreads();
    #pragma unroll
    for (int c = 0; c < 4; ++c) { acc[c][0] = 0.f; acc[c][1] = 0.f; acc[c][2] = 0.f; acc[c][3] = 0.f; }
    mfma_stage(hbf, wtb[1], m0, lane, acc, false);
    __syncthreads();
    #pragma unroll
    for (int c4 = 0; c4 < 4; ++c4)
        #pragma unroll
        for (int r = 0; r < 4; ++r)
            hbf[(m0 + (quad << 2) + r) * HS + (c4 << 4) + idx] = f2bf(silu(acc[c4][r]));
    *(u16x8*)&wtb[0][prow * HS + pkb]     = pf0;
    *(u16x8*)&wtb[0][prow * HS + pkb + 8] = pf1;
    pf0 = *(const u16x8*)&WT[8704 + prow * 64 + pkb];
    pf1 = *(const u16x8*)&WT[8704 + prow * 64 + pkb + 8];
    __syncthreads();
    #pragma unroll
    for (int c = 0; c < 4; ++c) { acc[c][0] = 0.f; acc[c][1] = 0.f; acc[c][2] = 0.f; acc[c][3] = 0.f; }
    mfma_stage(hbf, wtb[0], m0, lane, acc, false);
    __syncthreads();
    #pragma unroll
    for (int c4 = 0; c4 < 4; ++c4)
        #pragma unroll
        for (int r = 0; r < 4; ++r)
            hbf[(m0 + (quad << 2) + r) * HS + (c4 << 4) + idx] = f2bf(silu(acc[c4][r]));
    *(u16x8*)&wtb[1][prow * HS + pkb]     = pf0;
    *(u16x8*)&wtb[1][prow * HS + pkb + 8] = pf1;
    pf0 = *(const u16x8*)&WT[8704 + 4096 + prow * 64 + pkb];
    pf1 = *(const u16x8*)&WT[8704 + 4096 + prow * 64 + pkb + 8];
    __syncthreads();
    int cur = 1;
    for (int c = 0; c < 4; ++c) {
        #pragma unroll
        for (int cc = 0; cc < 4; ++cc) { acc[cc][0] = 0.f; acc[cc][1] = 0.f; acc[cc][2] = 0.f; acc[cc][3] = 0.f; }
        mfma_stage(hbf, wtb[cur], m0, lane, acc, false);
        __syncthreads();
        #pragma unroll
        for (int c4 = 0; c4 < 4; ++c4)
            #pragma unroll
            for (int r = 0; r < 4; ++r)
                outS[(m0 + (quad << 2) + r) * HS + (c4 << 4) + idx] = f2bf(acc[c4][r]);
        if (c < 3) {
            *(u16x8*)&wtb[1 - cur][prow * HS + pkb]     = pf0;
            *(u16x8*)&wtb[1 - cur][prow * HS + pkb + 8] = pf1;
            if (c < 2) {
                pf0 = *(const u16x8*)&WT[8704 + (c + 2) * 4096 + prow * 64 + pkb];
                pf1 = *(const u16x8*)&WT[8704 + (c + 2) * 4096 + prow * 64 + pkb + 8];
            }
        }
        __syncthreads();
        *(u16x8*)&wout[(size_t)(j0 + prow) * 256 + (c << 6) + pkb]     = *(const u16x8*)&outS[prow * HS + pkb];
        *(u16x8*)&wout[(size_t)(j0 + prow) * 256 + (c << 6) + pkb + 8] = *(const u16x8*)&outS[prow * HS + pkb + 8];
        cur ^= 1;
    }
}

// ---------------- aggregate: wave per receiver, streamed geometry, 2-stage pipeline ----------------
__global__ __launch_bounds__(256) void k_agg(const float4* __restrict__ geomv,
    const int* __restrict__ spck,
    const unsigned short* __restrict__ Hb, const unsigned short* __restrict__ wb,
    const int* __restrict__ roff, float* __restrict__ A)
{
    const int lane = threadIdx.x & 63;
    const int n = (blockIdx.x << 2) + (threadIdx.x >> 6);
    const int ja = roff[n], jb2 = roff[n + 1];
    float acc[16];
    #pragma unroll
    for (int l = 0; l < 16; ++l) acc[l] = 0.f;
    constexpr int LM[16] = {0,1,1,1,2,2,2,2,2,3,3,3,3,3,3,3};
    // pipeline registers: stage0 = current (g0,w0,hv0), stage1 = next scalars (g1,s1_,w1)
    float4 g0, g1;
    ushort4 w0, w1;
    int s1_ = 0;
    unsigned short hv0[16];
    if (ja < jb2) {
        g0 = geomv[ja];
        const int s0 = spck[ja];
        w0 = *(const ushort4*)&wb[(size_t)ja * 256 + (lane << 2)];
        #pragma unroll
        for (int l = 0; l < 16; ++l) hv0[l] = Hb[(size_t)s0 * 1024 + (l << 6) + lane];
    }
    if (ja + 1 < jb2) {
        g1 = geomv[ja + 1];
        s1_ = spck[ja + 1];
        w1 = *(const ushort4*)&wb[(size_t)(ja + 1) * 256 + (lane << 2)];
    }
    for (int j = ja; j < jb2; ++j) {
        const float4 gc = g0;
        const ushort4 wc = w0;
        float hc[16];
        #pragma unroll
        for (int l = 0; l < 16; ++l) hc[l] = bf2f(hv0[l]);
        // rotate pipeline: prefetch Hb for j+1 (sender known), scalars for j+2
        if (j + 1 < jb2) {
            g0 = g1; w0 = w1;
            const int sN = s1_;
            #pragma unroll
            for (int l = 0; l < 16; ++l) hv0[l] = Hb[(size_t)sN * 1024 + (l << 6) + lane];
            if (j + 2 < jb2) {
                g1 = geomv[j + 2];
                s1_ = spck[j + 2];
                w1 = *(const ushort4*)&wb[(size_t)(j + 2) * 256 + (lane << 2)];
            }
        }
        if (gc.w >= RMAX) continue;
        const float x = gc.x, y = gc.y, z = gc.z;
        const float xx = x * x, yy = y * y, zz = z * z;
        float Y[16];
        Y[0] = 1.f;
        Y[1] = 1.7320508f * x;  Y[2] = 1.7320508f * y;  Y[3] = 1.7320508f * z;
        Y[4] = 3.8729833f * x * y;  Y[5] = 3.8729833f * y * z;
        Y[6] = 0.5f * 2.2360680f * (3.f * zz - 1.f);
        Y[7] = 3.8729833f * x * z;  Y[8] = 0.5f * 3.8729833f * (xx - yy);
        Y[9]  = 2.0916500f * y * (3.f * xx - yy);
        Y[10] = 10.2469508f * x * y * z;
        Y[11] = 1.6201852f * y * (5.f * zz - 1.f);
        Y[12] = 0.5f * 2.6457513f * z * (5.f * zz - 3.f);
        Y[13] = 1.6201852f * x * (5.f * zz - 1.f);
        Y[14] = 0.5f * 10.2469508f * z * (xx - yy);
        Y[15] = 2.0916500f * x * (xx - 3.f * yy);
        float se = 0.f;
        #pragma unroll
        for (int l = 0; l < 16; ++l) se += hc[l] * Y[l];
        se *= 0.0625f;
        const float wl[4] = { bf2f(wc.x) * se, bf2f(wc.y) * se, bf2f(wc.z) * se, bf2f(wc.w) * se };
        #pragma unroll
        for (int l = 0; l < 16; ++l) acc[l] += wl[LM[l]] * Y[l];
    }
    float* Ap = A + (size_t)n * 64 + lane;
    #pragma unroll
    for (int l = 0; l < 16; ++l) Ap[(size_t)l * NC] = acc[l];
}

// ---------------- s1[n][c] = sum_l H2[l][n][c]^2 ----------------
__global__ __launch_bounds__(256) void k_s1(const float* __restrict__ H, float* __restrict__ s1)
{
    const int i = blockIdx.x * 256 + threadIdx.x;
    if (i < NC) {
        float s = 0.f;
        #pragma unroll
        for (int l = 0; l < 16; ++l) { const float a = H[(size_t)l * NC + i]; s += a * a; }
        s1[i] = s;
    }
}

// ---------------- out = sum_p (A'*s1^p)@Wp_p + sc -> F  (MFMA) ----------------
__global__ __launch_bounds__(256) void k_out(const float* __restrict__ Ap,
    const float* __restrict__ s1, const unsigned short* __restrict__ WpT,
    const float* __restrict__ sc, float* __restrict__ F)
{
    __shared__ unsigned short Xb[64 * HS];
    __shared__ unsigned short Wt[64 * HS];
    const int l  = blockIdx.y;
    const int nb = blockIdx.x << 6;
    const int t  = threadIdx.x;
    const int lane = t & 63;
    const int m0   = (t >> 6) << 4;
    const int quad = lane >> 4;
    const int idx  = lane & 15;
    const int prow = t >> 2, pkb = (t & 3) << 4;
    const float* Xp = Ap + (size_t)l * NC + (size_t)nb * 64;
    float av[16], sv[16];
    #pragma unroll
    for (int k = 0; k < 16; ++k) {
        const int i = t + (k << 8);
        av[k] = Xp[i];
        sv[k] = s1[nb * 64 + i];
    }
    f32x4v acc[4];
    #pragma unroll
    for (int c = 0; c < 4; ++c) { acc[c][0] = 0.f; acc[c][1] = 0.f; acc[c][2] = 0.f; acc[c][3] = 0.f; }
    for (int p = 0; p < 3; ++p) {
        #pragma unroll
        for (int k = 0; k < 16; ++k) {
            const int i = t + (k << 8);
            Xb[(i >> 6) * HS + (i & 63)] = f2bf(av[k]);
            av[k] *= sv[k];
        }
        *(u16x8*)&Wt[prow * HS + pkb]     = *(const u16x8*)&WpT[p * 4096 + prow * 64 + pkb];
        *(u16x8*)&Wt[prow * HS + pkb + 8] = *(const u16x8*)&WpT[p * 4096 + prow * 64 + pkb + 8];
        __syncthreads();
        mfma_stage(Xb, Wt, m0, lane, acc, false);
        __syncthreads();
    }
    #pragma unroll
    for (int c4 = 0; c4 < 4; ++c4) {
        #pragma unroll
        for (int r = 0; r < 4; ++r) {
            const int row = m0 + (quad << 2) + r;
            const int col = (c4 << 4) + idx;
            const size_t id = (size_t)l * NC + (size_t)(nb + row) * 64 + col;
            F[id] = acc[c4][r] + sc[id];
        }
    }
}

// ---------------- readout ----------------
__global__ __launch_bounds__(256) void k_read(const float* __restrict__ F,
    const float* __restrict__ q, const int* __restrict__ batch,
    const float* __restrict__ Wr0, const float* __restrict__ Wa,
    const float* __restrict__ Wb, const float* __restrict__ Wq,
    float* __restrict__ acc, int last)
{
    __shared__ float sred[G];
    if (threadIdx.x < G) sred[threadIdx.x] = 0.f;
    __syncthreads();
    const int n = blockIdx.x * 256 + threadIdx.x;
    if (n < N) {
        float a16[16];
        #pragma unroll
        for (int j = 0; j < 16; ++j) a16[j] = 0.f;
        float ar = 0.f, aq = 0.f;
        const float* f = F + (size_t)n * 64;
        for (int c = 0; c < 64; ++c) {
            const float fv = f[c];
            aq += fv * Wq[c];
            if (last) {
                #pragma unroll
                for (int j = 0; j < 16; ++j) a16[j] += fv * Wa[c * 16 + j];
            } else ar += fv * Wr0[c];
        }
        float en;
        if (last) {
            en = 0.f;
            #pragma unroll
            for (int j = 0; j < 16; ++j) en += silu(a16[j]) * Wb[j];
        } else en = ar;
        en += q[n] * aq;
        atomicAdd(&sred[batch[n]], en);
    }
    __syncthreads();
    if (threadIdx.x < G) atomicAdd(&acc[threadIdx.x * 5], sred[threadIdx.x]);
}

// ---------------- Ewald ----------------
__global__ __launch_bounds__(256) void k_kvec(const float* __restrict__ rcell,
    float* __restrict__ kvec, float* __restrict__ k2)
{
    const int idx = blockIdx.x * 256 + threadIdx.x;
    if (idx >= G * NK) return;
    const int g = idx / NK, k = idx % NK;
    const int kk = k + (k >= 171 ? 1 : 0);
    const int a = kk / 49 - 3, b = (kk / 7) % 7 - 3, c = kk % 7 - 3;
    const float* rc = rcell + g * 9;
    float s = 0.f;
    #pragma unroll
    for (int i = 0; i < 3; ++i) {
        const float kv = 6.283185307f * ((float)a * rc[0 + i] + (float)b * rc[3 + i] + (float)c * rc[6 + i]);
        kvec[idx * 3 + i] = kv;
        s += kv * kv;
    }
    k2[idx] = s;
}

__global__ __launch_bounds__(256) void k_phase(const float* __restrict__ pos,
    const float* __restrict__ q, const float* __restrict__ kvec,
    float* __restrict__ Sr, float* __restrict__ Si)
{
    __shared__ float kvs[38 * 3];
    __shared__ float srs[38], sis[38];
    const int g = blockIdx.z, kc = blockIdx.x, ncb = blockIdx.y;
    const int kbase = kc * 38;
    if (threadIdx.x < 38 * 3) kvs[threadIdx.x] = kvec[((size_t)g * NK + kbase) * 3 + threadIdx.x];
    if (threadIdx.x < 38) { srs[threadIdx.x] = 0.f; sis[threadIdx.x] = 0.f; }
    __syncthreads();
    const int t = threadIdx.x;
    float px = 0.f, py = 0.f, pz = 0.f, qn = 0.f;
    if (t < 250) {
        const int n = g * NGR + ncb * 250 + t;
        px = pos[n * 3]; py = pos[n * 3 + 1]; pz = pos[n * 3 + 2]; qn = q[n];
    }
    const int lane = t & 63;
    for (int j = 0; j < 38; ++j) {
        const float ph = px * kvs[j * 3] + py * kvs[j * 3 + 1] + pz * kvs[j * 3 + 2];
        float sv, cv;
        __sincosf(ph, &sv, &cv);
        float vr = qn * cv, vi = qn * sv;
        #pragma unroll
        for (int o = 32; o > 0; o >>= 1) { vr += __shfl_down(vr, o, 64); vi += __shfl_down(vi, o, 64); }
        if (lane == 0) { atomicAdd(&srs[j], vr); atomicAdd(&sis[j], vi); }
    }
    __syncthreads();
    if (t < 38) {
        atomicAdd(&Sr[g * NK + kbase + t], srs[t]);
        atomicAdd(&Si[g * NK + kbase + t], sis[t]);
    }
}

__global__ __launch_bounds__(512) void k_final(const float* __restrict__ k2,
    const float* __restrict__ Sr, const float* __restrict__ Si,
    const float* __restrict__ vol, const float* __restrict__ acc,
    float* __restrict__ out)
{
    __shared__ float red[512];
    const int g = blockIdx.x, t = threadIdx.x;
    float v = 0.f;
    if (t < NK) {
        const float kk = k2[g * NK + t];
        const float sr = Sr[g * NK + t], si = Si[g * NK + t];
        v = __expf(-0.5f * kk) * (sr * sr + si * si) / kk;
    }
    red[t] = v;
    __syncthreads();
    for (int s2 = 256; s2 > 0; s2 >>= 1) {
        if (t < s2) red[t] += red[t + s2];
        __syncthreads();
    }
    if (t == 0) {
        const float Ees = 6.283185307f / vol[g] * red[0];
        out[g]     = acc[g * 5 + 0] + Ees;
        out[4 + g] = acc[g * 5 + 1];
        out[8 + g * 3 + 0] = acc[g * 5 + 2];
        out[8 + g * 3 + 1] = acc[g * 5 + 3];
        out[8 + g * 3 + 2] = acc[g * 5 + 4];
    }
}

extern "C" void kernel_launch(void* const* d_in, const int* in_sizes, int n_in,
                              void* d_out, int out_size, void* d_ws, size_t ws_size,
                              hipStream_t stream)
{
    const float* na    = (const float*)d_in[0];
    const float* pos   = (const float*)d_in[1];
    const float* shif  = (const float*)d_in[2];
    const float* q     = (const float*)d_in[3];
    const float* rcell = (const float*)d_in[5];
    const float* vol   = (const float*)d_in[6];
    const int*   ei    = (const int*)d_in[7];
    const int*   batch = (const int*)d_in[8];
    const float* embW  = (const float*)d_in[9];
    const float* qcoef = (const float*)d_in[10];
    const float* rW1   = (const float*)d_in[11];
    const float* rW2   = (const float*)d_in[12];
    const float* rW3   = (const float*)d_in[13];
    const float* rW4   = (const float*)d_in[14];
    const float* lup   = (const float*)d_in[15];
    const float* lout  = (const float*)d_in[16];
    const float* Wsc   = (const float*)d_in[17];
    const float* Wp    = (const float*)d_in[18];
    const float* Wr0   = (const float*)d_in[19];
    const float* Wa    = (const float*)d_in[20];
    const float* Wb    = (const float*)d_in[21];
    const float* Wq    = (const float*)d_in[22];
    const float* aE    = (const float*)d_in[23];
    float* out = (float*)d_out;

    float* wsf  = (float*)d_ws;
    float* F    = wsf;                  // [16][N][64] fp32
    float* A    = F + 8192000;          // [16][N][64] fp32 (A result; later sc)
    float* R    = A + 8192000;          // 20,480,000-float region:
    float* H2   = R;                    //   fp32 [16][N][64] (lin_out result)
    unsigned short* Hb = (unsigned short*)R;             // bf16 [N][16][64]
    unsigned short* wb = (unsigned short*)(R + 4096000); // bf16 [E][256]
    float* s1   = R + 20480000;         // [N][64]
    float* kvec = s1 + 512000;          // [G*342][3]
    float* k2   = kvec + 4104;
    float* Sr   = k2 + 1368;
    float* Si   = Sr + 1368;
    float* acc  = Si + 1368;            // [G][5]
    int*   elem = (int*)(acc + 32);     // [N]
    int*   perm = elem + 8000;          // [8640]
    int*   counts = perm + 8640;        // [16]
    int*   cursor = counts + 16;        // [16]
    int*   offs   = cursor + 16;        // [16]
    int*   roff   = offs + 16;          // [N+1]
    int*   cnt    = roff + 8001;        // [N]
    int*   cur    = cnt + 8000;         // [N]
    int*   elist  = cur + 8000;         // [E]
    unsigned short* WTb = (unsigned short*)(((uintptr_t)(elist + E) + 31) & ~(uintptr_t)31); // [2*WT_T]
    unsigned short* WpT = WTb + 2 * WT_T;                // [24576]
    float4* geomv = (float4*)(WpT + 24576);              // [E]
    int*    spck  = (int*)(geomv + E);                   // [E]

    hipMemsetAsync(F, 0, 8192000 * sizeof(float), stream);
    hipMemsetAsync(Sr, 0, (1368 * 2 + 32) * sizeof(float), stream);
    hipMemsetAsync(perm, 0xFF, 8640 * sizeof(int), stream);
    hipMemsetAsync(counts, 0, 32 * sizeof(int), stream);
    hipMemsetAsync(cnt, 0, 16000 * sizeof(int), stream);

    k_init<<<32, 256, 0, stream>>>(na, q, pos, batch, aE, elem, acc);
    k_feat0<<<2000, 256, 0, stream>>>(elem, embW, F);
    k_hist<<<32, 256, 0, stream>>>(elem, counts);
    k_offs<<<1, 64, 0, stream>>>(counts, offs);
    k_scatter<<<32, 256, 0, stream>>>(elem, offs, cursor, perm);
    k_gcnt<<<500, 256, 0, stream>>>(ei, cnt);
    k_goff<<<1, 1024, 0, stream>>>(cnt, roff);
    k_gscat<<<500, 256, 0, stream>>>(ei, roff, cur, elist);
    k_geom<<<500, 256, 0, stream>>>(pos, shif, ei, elist, geomv, spck);
    k_wprep<<<196, 256, 0, stream>>>(rW1, rW2, rW3, rW4, WTb);
    k_wprep2<<<96, 256, 0, stream>>>(Wp, WpT);
    k_kvec<<<6, 256, 0, stream>>>(rcell, kvec, k2);
    k_phase<<<dim3(9, 8, G), 256, 0, stream>>>(pos, q, kvec, Sr, Si);

    for (int t = 0; t < 2; ++t) {
        k_pre<<<2000, 256, 0, stream>>>(q, qcoef + t * 64, F);
        k_lgemm_hb<<<dim3(125, 16), 256, 0, stream>>>(F, lup + t * 4 * 4096, Hb);
        k_wgemm<<<2000, 256, 0, stream>>>(geomv, WTb + t * WT_T, wb);
        k_agg<<<2000, 256, 0, stream>>>(geomv, spck, Hb, wb, roff, A);
        k_lgemm<<<dim3(125, 16), 256, 0, stream>>>(A, lout + t * 4 * 4096, H2);
        k_s1<<<2000, 256, 0, stream>>>(H2, s1);
        k_sc<<<dim3(135, 16), 256, 0, stream>>>(F, Wsc + t * NEL * 4096, perm, elem, A);
        k_out<<<dim3(125, 16), 256, 0, stream>>>(H2, s1, WpT + t * 12288, A, F);
        k_read<<<32, 256, 0, stream>>>(F, q, batch, Wr0, Wa, Wb, Wq + t * 64, acc, t == 1);
    }
    k_final<<<G, 512, 0, stream>>>(k2, Sr, Si, vol, acc, out);
}

// Round 8
// 564.351 us; speedup vs baseline: 2.9889x; 1.1508x over previous
//
#include <hip/hip_runtime.h>
#include <hip/hip_bf16.h>

constexpr int N    = 8000;
constexpr int E    = 128000;
constexpr int G    = 4;
constexpr int NEL  = 10;
constexpr int NGR  = N / G;          // 2000
constexpr int NC   = N * 64;         // 512000
constexpr int NK   = 342;            // Ewald vectors
constexpr float RMAX = 5.0f;
constexpr int HS = 72;               // padded LDS row stride (bf16) for MFMA tiles
constexpr int WT_T = 25088;          // per-t size of transposed radial-weight block (ushorts)

typedef __bf16 bf16x8 __attribute__((ext_vector_type(8)));
typedef float  f32x4v __attribute__((ext_vector_type(4)));
typedef unsigned short u16x8 __attribute__((ext_vector_type(8)));

__device__ __forceinline__ int lmap_rt(int l) { return (l >= 1) + (l >= 4) + (l >= 9); }
__device__ __forceinline__ float silu(float x) { return x / (1.f + __expf(-x)); }
__device__ __forceinline__ float bf2f(unsigned short u) { return __uint_as_float(((unsigned)u) << 16); }
__device__ __forceinline__ unsigned short f2bf(float f) {
    __hip_bfloat16 h = __float2bfloat16(f);
    return *(unsigned short*)&h;
}

// MFMA 64x64(xK) stage: hsrc rows = M (stride HS), wt rows = N (stride HS), K=64 (or 8)
__device__ __forceinline__ void mfma_stage(const unsigned short* hsrc, const unsigned short* wt,
                                           int m0, int lane, f32x4v acc[4], bool k8only)
{
    const int quad = lane >> 4;
    const int idx  = lane & 15;
    bf16x8 bz;
    #pragma unroll
    for (int i = 0; i < 8; ++i) bz[i] = (__bf16)0.f;
    bf16x8 a0 = bz, a1 = bz;
    const int mrow = m0 + idx;
    if (k8only) {
        if (quad == 0) a0 = *(const bf16x8*)&hsrc[mrow * HS];
    } else {
        a0 = *(const bf16x8*)&hsrc[mrow * HS + (quad << 3)];
        a1 = *(const bf16x8*)&hsrc[mrow * HS + 32 + (quad << 3)];
    }
    #pragma unroll
    for (int c4 = 0; c4 < 4; ++c4) {
        const int nrow = (c4 << 4) + idx;
        if (k8only) {
            bf16x8 b0 = bz;
            if (quad == 0) b0 = *(const bf16x8*)&wt[nrow * HS];
            acc[c4] = __builtin_amdgcn_mfma_f32_16x16x32_bf16(a0, b0, acc[c4], 0, 0, 0);
        } else {
            const bf16x8 b0 = *(const bf16x8*)&wt[nrow * HS + (quad << 3)];
            const bf16x8 b1 = *(const bf16x8*)&wt[nrow * HS + 32 + (quad << 3)];
            acc[c4] = __builtin_amdgcn_mfma_f32_16x16x32_bf16(a0, b0, acc[c4], 0, 0, 0);
            acc[c4] = __builtin_amdgcn_mfma_f32_16x16x32_bf16(a1, b1, acc[c4], 0, 0, 0);
        }
    }
}

// ---------------- init: elem, e0/charge/dipole ----------------
__global__ __launch_bounds__(256) void k_init(const float* __restrict__ na,
    const float* __restrict__ q, const float* __restrict__ pos,
    const int* __restrict__ batch, const float* __restrict__ aE,
    int* __restrict__ elem, float* __restrict__ acc)
{
    __shared__ float s[G * 5];
    if (threadIdx.x < G * 5) s[threadIdx.x] = 0.f;
    __syncthreads();
    const int n = blockIdx.x * 256 + threadIdx.x;
    if (n < N) {
        int el = 0; float best = na[n * NEL];
        #pragma unroll
        for (int j = 1; j < NEL; ++j) { float v = na[n * NEL + j]; if (v > best) { best = v; el = j; } }
        elem[n] = el;
        const int g = batch[n];
        const float qn = q[n];
        atomicAdd(&s[g * 5 + 0], aE[el]);
        atomicAdd(&s[g * 5 + 1], qn);
        atomicAdd(&s[g * 5 + 2], qn * pos[n * 3 + 0]);
        atomicAdd(&s[g * 5 + 3], qn * pos[n * 3 + 1]);
        atomicAdd(&s[g * 5 + 4], qn * pos[n * 3 + 2]);
    }
    __syncthreads();
    if (threadIdx.x < G * 5) atomicAdd(&acc[threadIdx.x], s[threadIdx.x]);
}

__global__ __launch_bounds__(256) void k_feat0(const int* __restrict__ elem,
    const float* __restrict__ embW, float* __restrict__ F)
{
    const int i = blockIdx.x * 256 + threadIdx.x;
    if (i < NC) F[i] = embW[elem[i >> 6] * 64 + (i & 63)];
}

__global__ __launch_bounds__(256) void k_pre(const float* __restrict__ q,
    const float* __restrict__ qc, float* __restrict__ F)
{
    const int i = blockIdx.x * 256 + threadIdx.x;
    if (i < NC) F[i] += q[i >> 6] * qc[i & 63];
}

// ---------------- element bucketing ----------------
__global__ __launch_bounds__(256) void k_hist(const int* __restrict__ elem, int* __restrict__ counts)
{
    const int n = blockIdx.x * 256 + threadIdx.x;
    if (n < N) atomicAdd(&counts[elem[n]], 1);
}
__global__ void k_offs(const int* __restrict__ counts, int* __restrict__ offs)
{
    if (threadIdx.x == 0 && blockIdx.x == 0) {
        int o = 0;
        for (int j = 0; j < NEL; ++j) { offs[j] = o; o += (counts[j] + 63) & ~63; }
        offs[NEL] = o;
    }
}
__global__ __launch_bounds__(256) void k_scatter(const int* __restrict__ elem,
    const int* __restrict__ offs, int* __restrict__ cursor, int* __restrict__ perm)
{
    const int n = blockIdx.x * 256 + threadIdx.x;
    if (n < N) {
        const int el = elem[n];
        const int p = atomicAdd(&cursor[el], 1);
        perm[offs[el] + p] = n;
    }
}

// ---------------- receiver CSR build ----------------
__global__ __launch_bounds__(256) void k_gcnt(const int* __restrict__ ei, int* __restrict__ cnt)
{
    const int e = blockIdx.x * 256 + threadIdx.x;
    if (e < E) atomicAdd(&cnt[ei[E + e]], 1);
}
__global__ __launch_bounds__(1024) void k_goff(const int* __restrict__ cnt, int* __restrict__ roff)
{
    __shared__ int part[1024];
    const int t = threadIdx.x;
    const int base = t * 8;
    int loc[8];
    int s = 0;
    #pragma unroll
    for (int i = 0; i < 8; ++i) { loc[i] = s; s += (base + i < N) ? cnt[base + i] : 0; }
    part[t] = s;
    __syncthreads();
    for (int d = 1; d < 1024; d <<= 1) {
        const int v = (t >= d) ? part[t - d] : 0;
        __syncthreads();
        part[t] += v;
        __syncthreads();
    }
    const int excl = (t == 0) ? 0 : part[t - 1];
    #pragma unroll
    for (int i = 0; i < 8; ++i) if (base + i < N) roff[base + i] = excl + loc[i];
    if (t == 0) roff[N] = E;
}
__global__ __launch_bounds__(256) void k_gscat(const int* __restrict__ ei,
    const int* __restrict__ roff, int* __restrict__ cur, int* __restrict__ elist)
{
    const int e = blockIdx.x * 256 + threadIdx.x;
    if (e < E) {
        const int rv = ei[E + e];
        const int p = atomicAdd(&cur[rv], 1);
        elist[roff[rv] + p] = e;
    }
}

// ---------------- per-elist-position geometry precompute ----------------
__global__ __launch_bounds__(256) void k_geom(const float* __restrict__ pos,
    const float* __restrict__ shifts, const int* __restrict__ ei,
    const int* __restrict__ elist, float4* __restrict__ geomv, int* __restrict__ spck)
{
    const int j = blockIdx.x * 256 + threadIdx.x;
    if (j >= E) return;
    const int e = elist[j];
    const int s = ei[e], rv = ei[E + e];
    const float dx = pos[rv * 3 + 0] - pos[s * 3 + 0] + shifts[e * 3 + 0];
    const float dy = pos[rv * 3 + 1] - pos[s * 3 + 1] + shifts[e * 3 + 1];
    const float dz = pos[rv * 3 + 2] - pos[s * 3 + 2] + shifts[e * 3 + 2];
    const float r = sqrtf(dx * dx + dy * dy + dz * dz);
    const float inv = 1.f / (r + 1e-9f);
    float4 g;
    g.x = dx * inv; g.y = dy * inv; g.z = dz * inv; g.w = r;
    geomv[j] = g;
    spck[j] = s;
}

// ---------------- weight transpose+bf16 prep (runs once) ----------------
__global__ __launch_bounds__(256) void k_wprep(const float* __restrict__ rW1,
    const float* __restrict__ rW2, const float* __restrict__ rW3,
    const float* __restrict__ rW4, unsigned short* __restrict__ WT)
{
    const int idx = blockIdx.x * 256 + threadIdx.x;
    if (idx >= 2 * WT_T) return;
    const int t = idx / WT_T;
    const int r = idx % WT_T;
    float v;
    if (r < 512) {
        const int n = r >> 3, k = r & 7;
        v = rW1[t * 512 + k * 64 + n];
    } else if (r < 4608) {
        const int i = r - 512, n = i >> 6, k = i & 63;
        v = rW2[t * 4096 + k * 64 + n];
    } else if (r < 8704) {
        const int i = r - 4608, n = i >> 6, k = i & 63;
        v = rW3[t * 4096 + k * 64 + n];
    } else {
        const int i = r - 8704, n = i >> 6, k = i & 63;
        v = rW4[t * 16384 + k * 256 + n];
    }
    WT[idx] = f2bf(v);
}

// WpT[t][p][d][c] = Wp[t][p][c][d], bf16
__global__ __launch_bounds__(256) void k_wprep2(const float* __restrict__ Wp,
    unsigned short* __restrict__ WpT)
{
    const int idx = blockIdx.x * 256 + threadIdx.x;
    if (idx >= 24576) return;
    const int tp = idx / 4096;
    const int i  = idx % 4096;
    const int d = i >> 6, c = i & 63;
    WpT[idx] = f2bf(Wp[(size_t)tp * 4096 + c * 64 + d]);
}

// transposed bf16 copies of lin_up, lin_out, W_sc
// WlupT[t][lm][d][c], WloutT[t][lm][d][c], WscT[t][el][d][c]
__global__ __launch_bounds__(256) void k_wprep3(const float* __restrict__ lup,
    const float* __restrict__ lout, const float* __restrict__ Wsc,
    unsigned short* __restrict__ WlupT, unsigned short* __restrict__ WloutT,
    unsigned short* __restrict__ WscT)
{
    const int idx = blockIdx.x * 256 + threadIdx.x;
    if (idx < 32768) {
        const int i = idx & 4095, d = i >> 6, c = i & 63;
        WlupT[idx] = f2bf(lup[(idx >> 12) * 4096 + c * 64 + d]);
    } else if (idx < 65536) {
        const int r = idx - 32768;
        const int i = r & 4095, d = i >> 6, c = i & 63;
        WloutT[r] = f2bf(lout[(r >> 12) * 4096 + c * 64 + d]);
    } else if (idx < 147456) {
        const int r = idx - 65536;
        const int i = r & 4095, d = i >> 6, c = i & 63;
        WscT[r] = f2bf(Wsc[(r >> 12) * 4096 + c * 64 + d]);
    }
}

// ---------------- lin_up GEMM (MFMA) -> bf16 node-major Hb[n][l][64] ----------------
__global__ __launch_bounds__(256) void k_lgemm_hb(const float* __restrict__ X,
    const unsigned short* __restrict__ WT, unsigned short* __restrict__ Hb)
{
    __shared__ unsigned short Xb[64 * HS];
    __shared__ unsigned short Wt[64 * HS];
    const int l  = blockIdx.y;
    const int nb = blockIdx.x << 6;
    const int t  = threadIdx.x;
    const int lane = t & 63;
    const int m0   = (t >> 6) << 4;
    const int quad = lane >> 4;
    const int idx  = lane & 15;
    const int prow = t >> 2, pkb = (t & 3) << 4;
    const float* Xp = X + (size_t)l * NC + (size_t)nb * 64;
    #pragma unroll
    for (int k = 0; k < 16; ++k) {
        const int i = t + (k << 8);
        Xb[(i >> 6) * HS + (i & 63)] = f2bf(Xp[i]);
    }
    const unsigned short* W = WT + lmap_rt(l) * 4096;
    *(u16x8*)&Wt[prow * HS + pkb]     = *(const u16x8*)&W[prow * 64 + pkb];
    *(u16x8*)&Wt[prow * HS + pkb + 8] = *(const u16x8*)&W[prow * 64 + pkb + 8];
    __syncthreads();
    f32x4v acc[4];
    #pragma unroll
    for (int c = 0; c < 4; ++c) { acc[c][0] = 0.f; acc[c][1] = 0.f; acc[c][2] = 0.f; acc[c][3] = 0.f; }
    mfma_stage(Xb, Wt, m0, lane, acc, false);
    #pragma unroll
    for (int c4 = 0; c4 < 4; ++c4) {
        #pragma unroll
        for (int r = 0; r < 4; ++r) {
            const int n = nb + m0 + (quad << 2) + r;
            const int col = (c4 << 4) + idx;
            Hb[(size_t)n * 1024 + (l << 6) + col] = f2bf(acc[c4][r]);
        }
    }
}

// ---------------- lin_out GEMM (MFMA) -> fp32 l-major ----------------
__global__ __launch_bounds__(256) void k_lgemm(const float* __restrict__ X,
    const unsigned short* __restrict__ WT, float* __restrict__ Out)
{
    __shared__ unsigned short Xb[64 * HS];
    __shared__ unsigned short Wt[64 * HS];
    const int l  = blockIdx.y;
    const int nb = blockIdx.x << 6;
    const int t  = threadIdx.x;
    const int lane = t & 63;
    const int m0   = (t >> 6) << 4;
    const int quad = lane >> 4;
    const int idx  = lane & 15;
    const int prow = t >> 2, pkb = (t & 3) << 4;
    const float* Xp = X + (size_t)l * NC + (size_t)nb * 64;
    #pragma unroll
    for (int k = 0; k < 16; ++k) {
        const int i = t + (k << 8);
        Xb[(i >> 6) * HS + (i & 63)] = f2bf(Xp[i]);
    }
    const unsigned short* W = WT + lmap_rt(l) * 4096;
    *(u16x8*)&Wt[prow * HS + pkb]     = *(const u16x8*)&W[prow * 64 + pkb];
    *(u16x8*)&Wt[prow * HS + pkb + 8] = *(const u16x8*)&W[prow * 64 + pkb + 8];
    __syncthreads();
    f32x4v acc[4];
    #pragma unroll
    for (int c = 0; c < 4; ++c) { acc[c][0] = 0.f; acc[c][1] = 0.f; acc[c][2] = 0.f; acc[c][3] = 0.f; }
    mfma_stage(Xb, Wt, m0, lane, acc, false);
    float* Op = Out + (size_t)l * NC + (size_t)nb * 64;
    #pragma unroll
    for (int c4 = 0; c4 < 4; ++c4) {
        #pragma unroll
        for (int r = 0; r < 4; ++r) {
            const int row = m0 + (quad << 2) + r;
            Op[(row << 6) + (c4 << 4) + idx] = acc[c4][r];
        }
    }
}

// ---------------- sc GEMM over element buckets (MFMA) ----------------
__global__ __launch_bounds__(256) void k_sc(const float* __restrict__ F,
    const unsigned short* __restrict__ WscT, const int* __restrict__ perm,
    const int* __restrict__ elem, float* __restrict__ Out)
{
    __shared__ unsigned short Xb[64 * HS];
    __shared__ unsigned short Wt[64 * HS];
    __shared__ int rows[64];
    const int l  = blockIdx.y;
    const int tb = blockIdx.x << 6;
    const int t  = threadIdx.x;
    if (t < 64) rows[t] = perm[tb + t];
    __syncthreads();
    if (rows[0] < 0) return;
    const int lane = t & 63;
    const int m0   = (t >> 6) << 4;
    const int quad = lane >> 4;
    const int idx  = lane & 15;
    const int prow = t >> 2, pkb = (t & 3) << 4;
    const unsigned short* W = WscT + elem[rows[0]] * 4096;
    *(u16x8*)&Wt[prow * HS + pkb]     = *(const u16x8*)&W[prow * 64 + pkb];
    *(u16x8*)&Wt[prow * HS + pkb + 8] = *(const u16x8*)&W[prow * 64 + pkb + 8];
    #pragma unroll
    for (int k = 0; k < 16; ++k) {
        const int i = t + (k << 8);
        const int rr = i >> 6, cc = i & 63;
        const int n = rows[rr];
        Xb[rr * HS + cc] = (n >= 0) ? f2bf(F[(size_t)l * NC + (size_t)n * 64 + cc]) : (unsigned short)0;
    }
    __syncthreads();
    f32x4v acc[4];
    #pragma unroll
    for (int c = 0; c < 4; ++c) { acc[c][0] = 0.f; acc[c][1] = 0.f; acc[c][2] = 0.f; acc[c][3] = 0.f; }
    mfma_stage(Xb, Wt, m0, lane, acc, false);
    #pragma unroll
    for (int c4 = 0; c4 < 4; ++c4) {
        #pragma unroll
        for (int r = 0; r < 4; ++r) {
            const int n = rows[m0 + (quad << 2) + r];
            if (n >= 0) Out[(size_t)l * NC + (size_t)n * 64 + (c4 << 4) + idx] = acc[c4][r];
        }
    }
}

// ---------------- edge MLP pipeline via MFMA ----------------
__global__ __launch_bounds__(256) void k_wgemm(const float4* __restrict__ geomv,
    const unsigned short* __restrict__ WT, unsigned short* __restrict__ wout)
{
    __shared__ unsigned short hbf[64 * HS];
    __shared__ unsigned short wtb[2][64 * HS];
    __shared__ unsigned short outS[64 * HS];
    const int t = threadIdx.x;
    const int lane = t & 63;
    const int wid  = t >> 6;
    const int m0   = wid << 4;
    const int quad = lane >> 4;
    const int idx  = lane & 15;
    const int j0 = blockIdx.x << 6;
    if (t < 64) {
        const float r = geomv[j0 + t].w;
        const float u  = r * 0.2f;
        const float u2 = u * u, u5 = u2 * u2 * u;
        const float fc = 1.f - 21.f * u5 + 35.f * u5 * u - 15.f * u5 * u2;
        float pref = 0.63245553f * fc / (r + 1e-9f);
        if (u >= 1.f) pref = 0.f;
        const float piu = 3.14159265358979f * u;
        #pragma unroll
        for (int b = 0; b < 8; ++b) hbf[t * HS + b] = f2bf(__sinf((float)(b + 1) * piu) * pref);
    }
    {
        const int n = t >> 2, k = (t & 3) << 1;
        wtb[0][n * HS + k]     = WT[n * 8 + k];
        wtb[0][n * HS + k + 1] = WT[n * 8 + k + 1];
    }
    const int prow = t >> 2, pkb = (t & 3) << 4;
    u16x8 pf0, pf1;
    pf0 = *(const u16x8*)&WT[512 + prow * 64 + pkb];
    pf1 = *(const u16x8*)&WT[512 + prow * 64 + pkb + 8];
    __syncthreads();
    f32x4v acc[4];
    #pragma unroll
    for (int c = 0; c < 4; ++c) { acc[c][0] = 0.f; acc[c][1] = 0.f; acc[c][2] = 0.f; acc[c][3] = 0.f; }
    mfma_stage(hbf, wtb[0], m0, lane, acc, true);
    __syncthreads();
    #pragma unroll
    for (int c4 = 0; c4 < 4; ++c4)
        #pragma unroll
        for (int r = 0; r < 4; ++r)
            hbf[(m0 + (quad << 2) + r) * HS + (c4 << 4) + idx] = f2bf(silu(acc[c4][r]));
    *(u16x8*)&wtb[1][prow * HS + pkb]     = pf0;
    *(u16x8*)&wtb[1][prow * HS + pkb + 8] = pf1;
    pf0 = *(const u16x8*)&WT[4608 + prow * 64 + pkb];
    pf1 = *(const u16x8*)&WT[4608 + prow * 64 + pkb + 8];
    __syncthreads();
    #pragma unroll
    for (int c = 0; c < 4; ++c) { acc[c][0] = 0.f; acc[c][1] = 0.f; acc[c][2] = 0.f; acc[c][3] = 0.f; }
    mfma_stage(hbf, wtb[1], m0, lane, acc, false);
    __syncthreads();
    #pragma unroll
    for (int c4 = 0; c4 < 4; ++c4)
        #pragma unroll
        for (int r = 0; r < 4; ++r)
            hbf[(m0 + (quad << 2) + r) * HS + (c4 << 4) + idx] = f2bf(silu(acc[c4][r]));
    *(u16x8*)&wtb[0][prow * HS + pkb]     = pf0;
    *(u16x8*)&wtb[0][prow * HS + pkb + 8] = pf1;
    pf0 = *(const u16x8*)&WT[8704 + prow * 64 + pkb];
    pf1 = *(const u16x8*)&WT[8704 + prow * 64 + pkb + 8];
    __syncthreads();
    #pragma unroll
    for (int c = 0; c < 4; ++c) { acc[c][0] = 0.f; acc[c][1] = 0.f; acc[c][2] = 0.f; acc[c][3] = 0.f; }
    mfma_stage(hbf, wtb[0], m0, lane, acc, false);
    __syncthreads();
    #pragma unroll
    for (int c4 = 0; c4 < 4; ++c4)
        #pragma unroll
        for (int r = 0; r < 4; ++r)
            hbf[(m0 + (quad << 2) + r) * HS + (c4 << 4) + idx] = f2bf(silu(acc[c4][r]));
    *(u16x8*)&wtb[1][prow * HS + pkb]     = pf0;
    *(u16x8*)&wtb[1][prow * HS + pkb + 8] = pf1;
    pf0 = *(const u16x8*)&WT[8704 + 4096 + prow * 64 + pkb];
    pf1 = *(const u16x8*)&WT[8704 + 4096 + prow * 64 + pkb + 8];
    __syncthreads();
    int cur = 1;
    for (int c = 0; c < 4; ++c) {
        #pragma unroll
        for (int cc = 0; cc < 4; ++cc) { acc[cc][0] = 0.f; acc[cc][1] = 0.f; acc[cc][2] = 0.f; acc[cc][3] = 0.f; }
        mfma_stage(hbf, wtb[cur], m0, lane, acc, false);
        __syncthreads();
        #pragma unroll
        for (int c4 = 0; c4 < 4; ++c4)
            #pragma unroll
            for (int r = 0; r < 4; ++r)
                outS[(m0 + (quad << 2) + r) * HS + (c4 << 4) + idx] = f2bf(acc[c4][r]);
        if (c < 3) {
            *(u16x8*)&wtb[1 - cur][prow * HS + pkb]     = pf0;
            *(u16x8*)&wtb[1 - cur][prow * HS + pkb + 8] = pf1;
            if (c < 2) {
                pf0 = *(const u16x8*)&WT[8704 + (c + 2) * 4096 + prow * 64 + pkb];
                pf1 = *(const u16x8*)&WT[8704 + (c + 2) * 4096 + prow * 64 + pkb + 8];
            }
        }
        __syncthreads();
        *(u16x8*)&wout[(size_t)(j0 + prow) * 256 + (c << 6) + pkb]     = *(const u16x8*)&outS[prow * HS + pkb];
        *(u16x8*)&wout[(size_t)(j0 + prow) * 256 + (c << 6) + pkb + 8] = *(const u16x8*)&outS[prow * HS + pkb + 8];
        cur ^= 1;
    }
}

// ---------------- aggregate: wave per receiver, depth-3 stream prefetch ----------------
__global__ __launch_bounds__(256) void k_agg(const float4* __restrict__ geomv,
    const int* __restrict__ spck,
    const unsigned short* __restrict__ Hb, const unsigned short* __restrict__ wb,
    const int* __restrict__ roff, float* __restrict__ A)
{
    const int lane = threadIdx.x & 63;
    const int n = (blockIdx.x << 2) + (threadIdx.x >> 6);
    const int ja = roff[n], jb2 = roff[n + 1];
    float accv[16];
    #pragma unroll
    for (int l = 0; l < 16; ++l) accv[l] = 0.f;
    constexpr int LM[16] = {0,1,1,1,2,2,2,2,2,3,3,3,3,3,3,3};
    if (ja < jb2) {
        const int jlast = jb2 - 1;
        // scalar streams: depth 3 (g,w for j, j+1, j+2); Hb: depth 2 (sender pipeline)
        int j1c = ja + 1 < jlast ? ja + 1 : jlast;
        int j2c = ja + 2 < jlast ? ja + 2 : jlast;
        float4 g0 = geomv[ja],  g1 = geomv[j1c],  g2 = geomv[j2c];
        ushort4 w0 = *(const ushort4*)&wb[(size_t)ja * 256 + (lane << 2)];
        ushort4 w1 = *(const ushort4*)&wb[(size_t)j1c * 256 + (lane << 2)];
        ushort4 w2 = *(const ushort4*)&wb[(size_t)j2c * 256 + (lane << 2)];
        int sB = spck[j1c], sC = spck[j2c];
        unsigned short hv[16];
        {
            const int s0 = spck[ja];
            #pragma unroll
            for (int l = 0; l < 16; ++l) hv[l] = Hb[(size_t)s0 * 1024 + (l << 6) + lane];
        }
        for (int j = ja; j < jb2; ++j) {
            const float4 gc = g0;
            const ushort4 wc = w0;
            float hc[16];
            #pragma unroll
            for (int l = 0; l < 16; ++l) hc[l] = bf2f(hv[l]);
            // rotate pipeline + issue next loads
            g0 = g1; g1 = g2; w0 = w1; w1 = w2;
            const int sA = sB; sB = sC;
            #pragma unroll
            for (int l = 0; l < 16; ++l) hv[l] = Hb[(size_t)sA * 1024 + (l << 6) + lane];
            const int j3 = j + 3 < jlast ? j + 3 : jlast;
            g2 = geomv[j3];
            w2 = *(const ushort4*)&wb[(size_t)j3 * 256 + (lane << 2)];
            sC = spck[j3];
            if (gc.w < RMAX) {
                const float x = gc.x, y = gc.y, z = gc.z;
                const float xx = x * x, yy = y * y, zz = z * z;
                float Y[16];
                Y[0] = 1.f;
                Y[1] = 1.7320508f * x;  Y[2] = 1.7320508f * y;  Y[3] = 1.7320508f * z;
                Y[4] = 3.8729833f * x * y;  Y[5] = 3.8729833f * y * z;
                Y[6] = 0.5f * 2.2360680f * (3.f * zz - 1.f);
                Y[7] = 3.8729833f * x * z;  Y[8] = 0.5f * 3.8729833f * (xx - yy);
                Y[9]  = 2.0916500f * y * (3.f * xx - yy);
                Y[10] = 10.2469508f * x * y * z;
                Y[11] = 1.6201852f * y * (5.f * zz - 1.f);
                Y[12] = 0.5f * 2.6457513f * z * (5.f * zz - 3.f);
                Y[13] = 1.6201852f * x * (5.f * zz - 1.f);
                Y[14] = 0.5f * 10.2469508f * z * (xx - yy);
                Y[15] = 2.0916500f * x * (xx - 3.f * yy);
                float se = 0.f;
                #pragma unroll
                for (int l = 0; l < 16; ++l) se += hc[l] * Y[l];
                se *= 0.0625f;
                const float wl[4] = { bf2f(wc.x) * se, bf2f(wc.y) * se, bf2f(wc.z) * se, bf2f(wc.w) * se };
                #pragma unroll
                for (int l = 0; l < 16; ++l) accv[l] += wl[LM[l]] * Y[l];
            }
        }
    }
    float* Ap = A + (size_t)n * 64 + lane;
    #pragma unroll
    for (int l = 0; l < 16; ++l) Ap[(size_t)l * NC] = accv[l];
}

// ---------------- s1[n][c] = sum_l H2[l][n][c]^2 ----------------
__global__ __launch_bounds__(256) void k_s1(const float* __restrict__ H, float* __restrict__ s1)
{
    const int i = blockIdx.x * 256 + threadIdx.x;
    if (i < NC) {
        float s = 0.f;
        #pragma unroll
        for (int l = 0; l < 16; ++l) { const float a = H[(size_t)l * NC + i]; s += a * a; }
        s1[i] = s;
    }
}

// ---------------- out = sum_p (A'*s1^p)@Wp_p + sc -> F  (MFMA) ----------------
__global__ __launch_bounds__(256) void k_out(const float* __restrict__ Ap,
    const float* __restrict__ s1, const unsigned short* __restrict__ WpT,
    const float* __restrict__ sc, float* __restrict__ F)
{
    __shared__ unsigned short Xb[64 * HS];
    __shared__ unsigned short Wt[64 * HS];
    const int l  = blockIdx.y;
    const int nb = blockIdx.x << 6;
    const int t  = threadIdx.x;
    const int lane = t & 63;
    const int m0   = (t >> 6) << 4;
    const int quad = lane >> 4;
    const int idx  = lane & 15;
    const int prow = t >> 2, pkb = (t & 3) << 4;
    const float* Xp = Ap + (size_t)l * NC + (size_t)nb * 64;
    float av[16], sv[16];
    #pragma unroll
    for (int k = 0; k < 16; ++k) {
        const int i = t + (k << 8);
        av[k] = Xp[i];
        sv[k] = s1[nb * 64 + i];
    }
    f32x4v acc[4];
    #pragma unroll
    for (int c = 0; c < 4; ++c) { acc[c][0] = 0.f; acc[c][1] = 0.f; acc[c][2] = 0.f; acc[c][3] = 0.f; }
    for (int p = 0; p < 3; ++p) {
        #pragma unroll
        for (int k = 0; k < 16; ++k) {
            const int i = t + (k << 8);
            Xb[(i >> 6) * HS + (i & 63)] = f2bf(av[k]);
            av[k] *= sv[k];
        }
        *(u16x8*)&Wt[prow * HS + pkb]     = *(const u16x8*)&WpT[p * 4096 + prow * 64 + pkb];
        *(u16x8*)&Wt[prow * HS + pkb + 8] = *(const u16x8*)&WpT[p * 4096 + prow * 64 + pkb + 8];
        __syncthreads();
        mfma_stage(Xb, Wt, m0, lane, acc, false);
        __syncthreads();
    }
    #pragma unroll
    for (int c4 = 0; c4 < 4; ++c4) {
        #pragma unroll
        for (int r = 0; r < 4; ++r) {
            const int row = m0 + (quad << 2) + r;
            const int col = (c4 << 4) + idx;
            const size_t id = (size_t)l * NC + (size_t)(nb + row) * 64 + col;
            F[id] = acc[c4][r] + sc[id];
        }
    }
}

// ---------------- readout ----------------
__global__ __launch_bounds__(256) void k_read(const float* __restrict__ F,
    const float* __restrict__ q, const int* __restrict__ batch,
    const float* __restrict__ Wr0, const float* __restrict__ Wa,
    const float* __restrict__ Wb, const float* __restrict__ Wq,
    float* __restrict__ acc, int last)
{
    __shared__ float sred[G];
    if (threadIdx.x < G) sred[threadIdx.x] = 0.f;
    __syncthreads();
    const int n = blockIdx.x * 256 + threadIdx.x;
    if (n < N) {
        float a16[16];
        #pragma unroll
        for (int j = 0; j < 16; ++j) a16[j] = 0.f;
        float ar = 0.f, aq = 0.f;
        const float* f = F + (size_t)n * 64;
        for (int c = 0; c < 64; ++c) {
            const float fv = f[c];
            aq += fv * Wq[c];
            if (last) {
                #pragma unroll
                for (int j = 0; j < 16; ++j) a16[j] += fv * Wa[c * 16 + j];
            } else ar += fv * Wr0[c];
        }
        float en;
        if (last) {
            en = 0.f;
            #pragma unroll
            for (int j = 0; j < 16; ++j) en += silu(a16[j]) * Wb[j];
        } else en = ar;
        en += q[n] * aq;
        atomicAdd(&sred[batch[n]], en);
    }
    __syncthreads();
    if (threadIdx.x < G) atomicAdd(&acc[threadIdx.x * 5], sred[threadIdx.x]);
}

// ---------------- Ewald ----------------
__global__ __launch_bounds__(256) void k_kvec(const float* __restrict__ rcell,
    float* __restrict__ kvec, float* __restrict__ k2)
{
    const int idx = blockIdx.x * 256 + threadIdx.x;
    if (idx >= G * NK) return;
    const int g = idx / NK, k = idx % NK;
    const int kk = k + (k >= 171 ? 1 : 0);
    const int a = kk / 49 - 3, b = (kk / 7) % 7 - 3, c = kk % 7 - 3;
    const float* rc = rcell + g * 9;
    float s = 0.f;
    #pragma unroll
    for (int i = 0; i < 3; ++i) {
        const float kv = 6.283185307f * ((float)a * rc[0 + i] + (float)b * rc[3 + i] + (float)c * rc[6 + i]);
        kvec[idx * 3 + i] = kv;
        s += kv * kv;
    }
    k2[idx] = s;
}

__global__ __launch_bounds__(256) void k_phase(const float* __restrict__ pos,
    const float* __restrict__ q, const float* __restrict__ kvec,
    float* __restrict__ Sr, float* __restrict__ Si)
{
    __shared__ float kvs[38 * 3];
    __shared__ float srs[38], sis[38];
    const int g = blockIdx.z, kc = blockIdx.x, ncb = blockIdx.y;
    const int kbase = kc * 38;
    if (threadIdx.x < 38 * 3) kvs[threadIdx.x] = kvec[((size_t)g * NK + kbase) * 3 + threadIdx.x];
    if (threadIdx.x < 38) { srs[threadIdx.x] = 0.f; sis[threadIdx.x] = 0.f; }
    __syncthreads();
    const int t = threadIdx.x;
    float px = 0.f, py = 0.f, pz = 0.f, qn = 0.f;
    if (t < 250) {
        const int n = g * NGR + ncb * 250 + t;
        px = pos[n * 3]; py = pos[n * 3 + 1]; pz = pos[n * 3 + 2]; qn = q[n];
    }
    const int lane = t & 63;
    for (int j = 0; j < 38; ++j) {
        const float ph = px * kvs[j * 3] + py * kvs[j * 3 + 1] + pz * kvs[j * 3 + 2];
        float sv, cv;
        __sincosf(ph, &sv, &cv);
        float vr = qn * cv, vi = qn * sv;
        #pragma unroll
        for (int o = 32; o > 0; o >>= 1) { vr += __shfl_down(vr, o, 64); vi += __shfl_down(vi, o, 64); }
        if (lane == 0) { atomicAdd(&srs[j], vr); atomicAdd(&sis[j], vi); }
    }
    __syncthreads();
    if (t < 38) {
        atomicAdd(&Sr[g * NK + kbase + t], srs[t]);
        atomicAdd(&Si[g * NK + kbase + t], sis[t]);
    }
}

__global__ __launch_bounds__(512) void k_final(const float* __restrict__ k2,
    const float* __restrict__ Sr, const float* __restrict__ Si,
    const float* __restrict__ vol, const float* __restrict__ acc,
    float* __restrict__ out)
{
    __shared__ float red[512];
    const int g = blockIdx.x, t = threadIdx.x;
    float v = 0.f;
    if (t < NK) {
        const float kk = k2[g * NK + t];
        const float sr = Sr[g * NK + t], si = Si[g * NK + t];
        v = __expf(-0.5f * kk) * (sr * sr + si * si) / kk;
    }
    red[t] = v;
    __syncthreads();
    for (int s2 = 256; s2 > 0; s2 >>= 1) {
        if (t < s2) red[t] += red[t + s2];
        __syncthreads();
    }
    if (t == 0) {
        const float Ees = 6.283185307f / vol[g] * red[0];
        out[g]     = acc[g * 5 + 0] + Ees;
        out[4 + g] = acc[g * 5 + 1];
        out[8 + g * 3 + 0] = acc[g * 5 + 2];
        out[8 + g * 3 + 1] = acc[g * 5 + 3];
        out[8 + g * 3 + 2] = acc[g * 5 + 4];
    }
}

extern "C" void kernel_launch(void* const* d_in, const int* in_sizes, int n_in,
                              void* d_out, int out_size, void* d_ws, size_t ws_size,
                              hipStream_t stream)
{
    const float* na    = (const float*)d_in[0];
    const float* pos   = (const float*)d_in[1];
    const float* shif  = (const float*)d_in[2];
    const float* q     = (const float*)d_in[3];
    const float* rcell = (const float*)d_in[5];
    const float* vol   = (const float*)d_in[6];
    const int*   ei    = (const int*)d_in[7];
    const int*   batch = (const int*)d_in[8];
    const float* embW  = (const float*)d_in[9];
    const float* qcoef = (const float*)d_in[10];
    const float* rW1   = (const float*)d_in[11];
    const float* rW2   = (const float*)d_in[12];
    const float* rW3   = (const float*)d_in[13];
    const float* rW4   = (const float*)d_in[14];
    const float* lup   = (const float*)d_in[15];
    const float* lout  = (const float*)d_in[16];
    const float* Wsc   = (const float*)d_in[17];
    const float* Wp    = (const float*)d_in[18];
    const float* Wr0   = (const float*)d_in[19];
    const float* Wa    = (const float*)d_in[20];
    const float* Wb    = (const float*)d_in[21];
    const float* Wq    = (const float*)d_in[22];
    const float* aE    = (const float*)d_in[23];
    float* out = (float*)d_out;

    float* wsf  = (float*)d_ws;
    float* F    = wsf;                  // [16][N][64] fp32
    float* A    = F + 8192000;          // [16][N][64] fp32 (A result; later sc)
    float* R    = A + 8192000;          // 20,480,000-float region:
    float* H2   = R;                    //   fp32 [16][N][64] (lin_out result)
    unsigned short* Hb = (unsigned short*)R;             // bf16 [N][16][64]
    unsigned short* wb = (unsigned short*)(R + 4096000); // bf16 [E][256]
    float* s1   = R + 20480000;         // [N][64]
    float* kvec = s1 + 512000;          // [G*342][3]
    float* k2   = kvec + 4104;
    float* Sr   = k2 + 1368;
    float* Si   = Sr + 1368;
    float* acc  = Si + 1368;            // [G][5]
    int*   elem = (int*)(acc + 32);     // [N]
    int*   perm = elem + 8000;          // [8640]
    int*   counts = perm + 8640;        // [16]
    int*   cursor = counts + 16;        // [16]
    int*   offs   = cursor + 16;        // [16]
    int*   roff   = offs + 16;          // [N+1]
    int*   cnt    = roff + 8001;        // [N]
    int*   cur    = cnt + 8000;         // [N]
    int*   elist  = cur + 8000;         // [E]
    unsigned short* WTb = (unsigned short*)(((uintptr_t)(elist + E) + 31) & ~(uintptr_t)31); // [2*WT_T]
    unsigned short* WpT = WTb + 2 * WT_T;                // [24576]
    float4* geomv = (float4*)(WpT + 24576);              // [E]
    int*    spck  = (int*)(geomv + E);                   // [E]
    unsigned short* WlupT  = (unsigned short*)(spck + E); // [32768]
    unsigned short* WloutT = WlupT + 32768;               // [32768]
    unsigned short* WscT   = WloutT + 32768;              // [81920]

    hipMemsetAsync(F, 0, 8192000 * sizeof(float), stream);
    hipMemsetAsync(Sr, 0, (1368 * 2 + 32) * sizeof(float), stream);
    hipMemsetAsync(perm, 0xFF, 8640 * sizeof(int), stream);
    hipMemsetAsync(counts, 0, 32 * sizeof(int), stream);
    hipMemsetAsync(cnt, 0, 16000 * sizeof(int), stream);

    k_init<<<32, 256, 0, stream>>>(na, q, pos, batch, aE, elem, acc);
    k_feat0<<<2000, 256, 0, stream>>>(elem, embW, F);
    k_hist<<<32, 256, 0, stream>>>(elem, counts);
    k_offs<<<1, 64, 0, stream>>>(counts, offs);
    k_scatter<<<32, 256, 0, stream>>>(elem, offs, cursor, perm);
    k_gcnt<<<500, 256, 0, stream>>>(ei, cnt);
    k_goff<<<1, 1024, 0, stream>>>(cnt, roff);
    k_gscat<<<500, 256, 0, stream>>>(ei, roff, cur, elist);
    k_geom<<<500, 256, 0, stream>>>(pos, shif, ei, elist, geomv, spck);
    k_wprep<<<196, 256, 0, stream>>>(rW1, rW2, rW3, rW4, WTb);
    k_wprep2<<<96, 256, 0, stream>>>(Wp, WpT);
    k_wprep3<<<576, 256, 0, stream>>>(lup, lout, Wsc, WlupT, WloutT, WscT);
    k_kvec<<<6, 256, 0, stream>>>(rcell, kvec, k2);
    k_phase<<<dim3(9, 8, G), 256, 0, stream>>>(pos, q, kvec, Sr, Si);

    for (int t = 0; t < 2; ++t) {
        k_pre<<<2000, 256, 0, stream>>>(q, qcoef + t * 64, F);
        k_lgemm_hb<<<dim3(125, 16), 256, 0, stream>>>(F, WlupT + t * 16384, Hb);
        k_wgemm<<<2000, 256, 0, stream>>>(geomv, WTb + t * WT_T, wb);
        k_agg<<<2000, 256, 0, stream>>>(geomv, spck, Hb, wb, roff, A);
        k_lgemm<<<dim3(125, 16), 256, 0, stream>>>(A, WloutT + t * 16384, H2);
        k_s1<<<2000, 256, 0, stream>>>(H2, s1);
        k_sc<<<dim3(135, 16), 256, 0, stream>>>(F, WscT + t * 40960, perm, elem, A);
        k_out<<<dim3(125, 16), 256, 0, stream>>>(H2, s1, WpT + t * 12288, A, F);
        k_read<<<32, 256, 0, stream>>>(F, q, batch, Wr0, Wa, Wb, Wq + t * 64, acc, t == 1);
    }
    k_final<<<G, 512, 0, stream>>>(k2, Sr, Si, vol, acc, out);
}